// Round 1
// 2654.197 us; speedup vs baseline: 1.0478x; 1.0478x over previous
//
#include <hip/hip_runtime.h>
#include <hip/hip_bf16.h>

typedef __hip_bfloat16 bf16;
typedef __bf16 v8bf __attribute__((ext_vector_type(8)));
typedef float v4f __attribute__((ext_vector_type(4)));
typedef unsigned short u16x8 __attribute__((ext_vector_type(8)));

// ---------------------------------------------------------------------------
//   x: (8,4096,80) -> conv1(1->128,s2) -> (8,2048,40,128)   [channel-last]
//   -> conv2(128->256,s2) -> halo (8,1026,22,256)           [channel-last+halo]
//   -> conv3(256->512,s1) -> tokens (8,1024,10240)          [token-major]
//   -> embed GEMM (split-K) -> 4 RWKV blocks -> final LN
// GEMM core: bf16 MFMA 16x16x32, TM x 128 tile, BK=32.
// Staging: __builtin_amdgcn_global_load_lds width=16 into LINEAR (unpadded)
// [rows][32] bf16 LDS tiles (m97 ladder step: +69% over reg-staged). LDS dest
// is wave-uniform base + lane*16; the per-lane GLOBAL address supplies the
// gather (conv im2col) / row stride. conv2 OOB taps read a zeroed 4KB page
// (passed via Bw). Linear stride-32 rows make the b128 fragment reads 8-way
// bank-conflicted; measured acceptable in the 2-barrier structure (m97/m98).
// ---------------------------------------------------------------------------

constexpr int B_T = 0, B_CONV = 1;
constexpr int EP_CONV_CL = 0, EP_CONV_T = 1, EP_ATOMIC = 2, EP_KVR = 3,
              EP_ADD = 4, EP_FFN = 5, EP_ADDMUL = 6;

static __device__ __forceinline__ unsigned short f2b(float f) {
    return __builtin_bit_cast(unsigned short, __float2bfloat16(f));
}

// global -> LDS async copy, 16B per lane. LDS dest must be the wave-uniform
// base; HW writes lane i at base + i*16.
static __device__ __forceinline__ void gld16(const unsigned short* g,
                                             unsigned short* l) {
    __builtin_amdgcn_global_load_lds(
        (__attribute__((address_space(1))) void*)g,
        (__attribute__((address_space(3))) void*)l, 16, 0, 0);
}

// ---------------------------------------------------------------------------
// MFMA GEMM: C[M,N] = A[M,K] * B[K,N]. A bf16 [M][K]; B bf16 [N][K] (B_T) or
// channel-last im2col gather (B_CONV; HALO=1 -> unconditional loads from the
// zero-padded (b,1026,22,256) buffer; HALO=0 -> OOB lanes read zero page Bw).
// ASH>0: A += (n0>>ASH)*M*K (fused ops).
// ---------------------------------------------------------------------------
template <int TM, int BL, int EPM, int ASH, int TIN, int FIN, int STRIDE,
          int ICN, int HALO>
__global__ __launch_bounds__(256) void gemm_k(
    const bf16* __restrict__ A, const bf16* __restrict__ Bw,
    const bf16* __restrict__ Bact,
    float* __restrict__ C, bf16* __restrict__ Cb,
    const float* __restrict__ bias, const float* __restrict__ mul,
    int M, int N, int K, int KLEN)
{
    constexpr int MI = TM / 32;
    __shared__ __align__(16) unsigned short As[TM * 32];
    __shared__ __align__(16) unsigned short Bs[128 * 32];
    const int tid = threadIdx.x;
    const int n0 = blockIdx.x * 128;
    const int m0 = blockIdx.y * TM;
    const int kbase = blockIdx.z * KLEN;
    const int wave = tid >> 6, lane = tid & 63;
    const int wr = wave >> 1, wc = wave & 1;
    const int lq = lane >> 4, lr = lane & 15;

    if constexpr (ASH > 0) A += (size_t)(n0 >> ASH) * M * K;

    v4f acc[MI][4];
#pragma unroll
    for (int i = 0; i < MI; i++)
#pragma unroll
        for (int j = 0; j < 4; j++) acc[i][j] = v4f{0.f, 0.f, 0.f, 0.f};

    // staging geometry: chunk = c*256 + tid -> row c*64 + (tid>>2), col (tid&3)*8
    const int sr = tid >> 2;
    const int sc = (tid & 3) * 8;

    // hoisted per-lane source pointers
    const unsigned short* aPtr[TM / 64];
#pragma unroll
    for (int c = 0; c < TM / 64; c++)
        aPtr[c] = (const unsigned short*)A + (size_t)(m0 + c * 64 + sr) * K + sc;

    const unsigned short* bPtr[2];
    int cb0 = 0, cb1 = 0, cto0 = 0, cto1 = 0, cfo0 = 0, cfo1 = 0;
    if constexpr (BL == B_T) {
#pragma unroll
        for (int c = 0; c < 2; c++)
            bPtr[c] = (const unsigned short*)Bw + (size_t)(n0 + c * 64 + sr) * K + sc;
    } else {
        {
            int n = n0 + sr;
            cb0 = n / 20480;
            int s = n - cb0 * 20480;
            cto0 = s / 20;
            cfo0 = s - cto0 * 20;
        }
        {
            int n = n0 + 64 + sr;
            cb1 = n / 20480;
            int s = n - cb1 * 20480;
            cto1 = s / 20;
            cfo1 = s - cto1 * 20;
        }
        if constexpr (HALO) {
            bPtr[0] = (const unsigned short*)Bact +
                      (((size_t)cb0 * 1026 + cto0) * 22 + cfo0) * 256 + sc;
            bPtr[1] = (const unsigned short*)Bact +
                      (((size_t)cb1 * 1026 + cto1) * 22 + cfo1) * 256 + sc;
        }
    }

    for (int k0 = kbase; k0 < kbase + KLEN; k0 += 32) {
        // ---- stage A: TM x 32 bf16 via global_load_lds (linear LDS)
#pragma unroll
        for (int c = 0; c < TM / 64; c++)
            gld16(aPtr[c] + k0, &As[c * 2048 + wave * 512]);
        // ---- stage B
        if constexpr (BL == B_T) {
#pragma unroll
            for (int c = 0; c < 2; c++)
                gld16(bPtr[c] + k0, &Bs[c * 2048 + wave * 512]);
        } else {
            int kg = k0 / ICN;             // kt*3+kf
            int ic = k0 - kg * ICN + sc;
            int kt = kg / 3, kf = kg - kt * 3;
            if constexpr (HALO) {          // conv3: zero-padded input
                gld16(bPtr[0] + (kt * 22 + kf) * 256 + ic, &Bs[wave * 512]);
                gld16(bPtr[1] + (kt * 22 + kf) * 256 + ic, &Bs[2048 + wave * 512]);
            } else {                       // conv2: clamp OOB to zero page (Bw)
                int ti0 = cto0 * STRIDE - 1 + kt, fi0 = cfo0 * STRIDE - 1 + kf;
                const unsigned short* s0 =
                    ((unsigned)ti0 < (unsigned)TIN && (unsigned)fi0 < (unsigned)FIN)
                    ? (const unsigned short*)Bact +
                      (((size_t)cb0 * TIN + ti0) * FIN + fi0) * ICN + ic
                    : (const unsigned short*)Bw;
                gld16(s0, &Bs[wave * 512]);
                int ti1 = cto1 * STRIDE - 1 + kt, fi1 = cfo1 * STRIDE - 1 + kf;
                const unsigned short* s1 =
                    ((unsigned)ti1 < (unsigned)TIN && (unsigned)fi1 < (unsigned)FIN)
                    ? (const unsigned short*)Bact +
                      (((size_t)cb1 * TIN + ti1) * FIN + fi1) * ICN + ic
                    : (const unsigned short*)Bw;
                gld16(s1, &Bs[2048 + wave * 512]);
            }
        }
        __syncthreads();   // compiler drains vmcnt before s_barrier

        v8bf fa[MI], fb[4];
#pragma unroll
        for (int mi = 0; mi < MI; mi++)
            fa[mi] = *(const v8bf*)&As[(wr * (TM / 2) + mi * 16 + lr) * 32 + lq * 8];
#pragma unroll
        for (int ni = 0; ni < 4; ni++)
            fb[ni] = *(const v8bf*)&Bs[(wc * 64 + ni * 16 + lr) * 32 + lq * 8];
#pragma unroll
        for (int mi = 0; mi < MI; mi++)
#pragma unroll
            for (int ni = 0; ni < 4; ni++)
                acc[mi][ni] = __builtin_amdgcn_mfma_f32_16x16x32_bf16(
                    fa[mi], fb[ni], acc[mi][ni], 0, 0, 0);
        __syncthreads();
    }

    // ---- epilogue
#pragma unroll
    for (int mi = 0; mi < MI; mi++) {
#pragma unroll
        for (int ni = 0; ni < 4; ni++) {
#pragma unroll
            for (int reg = 0; reg < 4; reg++) {
                int row = m0 + wr * (TM / 2) + mi * 16 + lq * 4 + reg;
                int col = n0 + wc * 64 + ni * 16 + lr;
                float v = acc[mi][ni][reg];
                if constexpr (EPM == EP_CONV_CL) {
                    v += bias[row];
                    v = v > 0.f ? v : 0.f;
                    int b = col / 20480;
                    int s = col - b * 20480;
                    int t = s / 20, fo = s - t * 20;
                    Cb[(((size_t)b * 1026 + t + 1) * 22 + fo + 1) * 256 + row] =
                        __float2bfloat16(v);
                } else if constexpr (EPM == EP_CONV_T) {
                    v += bias[row];
                    v = v > 0.f ? v : 0.f;
                    int b = col / 20480;
                    int s = col - b * 20480;
                    int t = s / 20, fo = s - t * 20;
                    Cb[(size_t)(b * 1024 + t) * 10240 + row * 20 + fo] = __float2bfloat16(v);
                } else if constexpr (EPM == EP_ATOMIC) {
                    float add = (blockIdx.z == 0) ? bias[col] : 0.f;
                    atomicAdd(&C[(size_t)row * N + col], v + add);
                } else if constexpr (EPM == EP_KVR) {
                    int seg = col >> 9;     // 0=k,1=v,2=r (uniform per block)
                    if (seg == 2) v = 1.f / (1.f + __expf(-v));
                    C[(size_t)seg * M * 512 + (size_t)row * 512 + (col & 511)] = v;
                } else if constexpr (EPM == EP_ADD) {
                    C[(size_t)row * N + col] += v;
                } else if constexpr (EPM == EP_FFN) {
                    if (col < 2048) {       // wk branch: sqrelu -> bf16 kkb
                        float t = v > 0.f ? v : 0.f;
                        Cb[(size_t)row * 2048 + col] = __float2bfloat16(t * t);
                    } else {                // wr branch: sigmoid -> f32 rb
                        C[(size_t)row * 512 + (col - 2048)] = 1.f / (1.f + __expf(-v));
                    }
                } else if constexpr (EPM == EP_ADDMUL) {
                    size_t idx = (size_t)row * N + col;
                    C[idx] += mul[idx] * v;
                }
            }
        }
    }
}

// ---------------------------------------------------------------------------
// Prep: conv weight OIHW f32 -> bf16 [oc][(kt*3+kf)*IC + ic]
// ---------------------------------------------------------------------------
__global__ __launch_bounds__(256) void reorder_w_k(const float* __restrict__ in,
                                                   bf16* __restrict__ out,
                                                   int OC, int IC)
{
    int idx = blockIdx.x * 256 + threadIdx.x;
    if (idx >= OC * IC * 9) return;
    int oc = idx / (IC * 9);
    int r = idx - oc * (IC * 9);
    int g = r / IC;
    int ic = r - g * IC;
    out[idx] = __float2bfloat16(in[((size_t)oc * IC + ic) * 9 + g]);
}

// ---------------------------------------------------------------------------
// Prep: f32 [K][N] -> bf16 [N][K]; z: in stride K*N, out stride ozs
// ---------------------------------------------------------------------------
__global__ __launch_bounds__(256) void transpose_k(const float* __restrict__ in,
                                                   bf16* __restrict__ out,
                                                   int K, int N, size_t ozs)
{
    __shared__ float t[32][33];
    const float* pin = in + (size_t)blockIdx.z * K * N;
    bf16* pout = out + (size_t)blockIdx.z * ozs;
    int n0 = blockIdx.x * 32, k0 = blockIdx.y * 32;
    int tx = threadIdx.x & 31, ty = threadIdx.x >> 5;
#pragma unroll
    for (int i = 0; i < 32; i += 8)
        t[ty + i][tx] = pin[(size_t)(k0 + ty + i) * N + n0 + tx];
    __syncthreads();
#pragma unroll
    for (int i = 0; i < 32; i += 8)
        pout[(size_t)(n0 + ty + i) * K + k0 + tx] = __float2bfloat16(t[tx][ty + i]);
}

// ---------------------------------------------------------------------------
// conv1 for a 2-batch chunk: 1 input channel, direct, channel-last output.
// ---------------------------------------------------------------------------
__global__ __launch_bounds__(256) void conv1_k(
    const float* __restrict__ x, const float* __restrict__ w,
    const float* __restrict__ bias, bf16* __restrict__ out)
{
    __shared__ float ws_[128 * 9];
    __shared__ float bs_[128];
    const int tid = threadIdx.x;
    for (int i = tid; i < 128 * 9; i += 256) ws_[i] = w[i];
    if (tid < 128) bs_[tid] = bias[tid];
    __syncthreads();

    int idx = blockIdx.x * 256 + tid;  // 2*2048*40
    int f = idx % 40;
    int t = (idx / 40) & 2047;
    int b = idx / 81920;

    float xin[9];
#pragma unroll
    for (int kt = 0; kt < 3; kt++)
#pragma unroll
        for (int kf = 0; kf < 3; kf++) {
            int ti = 2 * t - 1 + kt, fi = 2 * f - 1 + kf;
            float v = 0.f;
            if ((unsigned)ti < 4096u && (unsigned)fi < 80u)
                v = x[(size_t)b * 327680 + (size_t)ti * 80 + fi];
            xin[kt * 3 + kf] = v;
        }
    unsigned short* outu = (unsigned short*)out + (size_t)idx * 128;
#pragma unroll
    for (int oc8 = 0; oc8 < 16; oc8++) {
        unsigned short pk[8];
#pragma unroll
        for (int j = 0; j < 8; j++) {
            int oc = oc8 * 8 + j;
            float a = bs_[oc];
#pragma unroll
            for (int q = 0; q < 9; q++) a += ws_[oc * 9 + q] * xin[q];
            a = a > 0.f ? a : 0.f;
            pk[j] = f2b(a);
        }
        *(u16x8*)&outu[oc8 * 8] = *(u16x8*)pk;
    }
}

// ---------------------------------------------------------------------------
// LayerNorm over D=512, one wave per row (4 rows / block)
// ---------------------------------------------------------------------------
__global__ __launch_bounds__(256) void ln_k(
    const float* __restrict__ in, float* __restrict__ out,
    const float* __restrict__ g, const float* __restrict__ b, int M)
{
    int wave = threadIdx.x >> 6;
    int lane = threadIdx.x & 63;
    int row = blockIdx.x * 4 + wave;
    if (row >= M) return;
    const float* p = in + (size_t)row * 512;
    float v[8], s = 0.f, sq = 0.f;
#pragma unroll
    for (int i = 0; i < 8; i++) {
        v[i] = p[lane + i * 64];
        s += v[i];
        sq += v[i] * v[i];
    }
#pragma unroll
    for (int o = 32; o > 0; o >>= 1) {
        s += __shfl_xor(s, o, 64);
        sq += __shfl_xor(sq, o, 64);
    }
    float mean = s * (1.f / 512.f);
    float var = sq * (1.f / 512.f) - mean * mean;
    float r = rsqrtf(var + 1e-5f);
    float* q = out + (size_t)row * 512;
#pragma unroll
    for (int i = 0; i < 8; i++) {
        int d = lane + i * 64;
        q[d] = (v[i] - mean) * r * g[d] + b[d];
    }
}

// ---------------------------------------------------------------------------
// Fused LN + token-shift mix -> bf16 operands. One wave per row; the wave
// also recomputes the predecessor row's LN (exact same f32 math). Lane owns
// 8 contiguous dims (16-B loads/stores). NOUT=3 (att) or 2 (ffn).
// ---------------------------------------------------------------------------
template <int NOUT>
__global__ __launch_bounds__(256) void lnmix_k(
    const float* __restrict__ hb, const float* __restrict__ g,
    const float* __restrict__ b, const float* __restrict__ mk,
    const float* __restrict__ mv, const float* __restrict__ mr,
    bf16* __restrict__ ok, bf16* __restrict__ ov, bf16* __restrict__ orr)
{
    int wave = threadIdx.x >> 6, lane = threadIdx.x & 63;
    int row = blockIdx.x * 4 + wave;     // 8192 rows
    int u = row & 1023;
    int d0 = lane * 8;
    const float* pc = hb + (size_t)row * 512 + d0;

    float vc[8], vp[8];
    *(float4*)&vc[0] = *(const float4*)pc;
    *(float4*)&vc[4] = *(const float4*)(pc + 4);
    float s = 0.f, sq = 0.f, sp = 0.f, sqp = 0.f;
#pragma unroll
    for (int i = 0; i < 8; i++) { s += vc[i]; sq += vc[i] * vc[i]; }
    if (u) {
        *(float4*)&vp[0] = *(const float4*)(pc - 512);
        *(float4*)&vp[4] = *(const float4*)(pc - 508);
#pragma unroll
        for (int i = 0; i < 8; i++) { sp += vp[i]; sqp += vp[i] * vp[i]; }
    } else {
#pragma unroll
        for (int i = 0; i < 8; i++) vp[i] = 0.f;
    }
#pragma unroll
    for (int o = 32; o > 0; o >>= 1) {
        s += __shfl_xor(s, o, 64);
        sq += __shfl_xor(sq, o, 64);
        sp += __shfl_xor(sp, o, 64);
        sqp += __shfl_xor(sqp, o, 64);
    }
    float mc = s * (1.f / 512.f);
    float rc = rsqrtf(sq * (1.f / 512.f) - mc * mc + 1e-5f);
    float mp = sp * (1.f / 512.f);
    float rp = rsqrtf(sqp * (1.f / 512.f) - mp * mp + 1e-5f);

    float gv[8], bv[8], xc[8], xp[8];
    *(float4*)&gv[0] = *(const float4*)(g + d0);
    *(float4*)&gv[4] = *(const float4*)(g + d0 + 4);
    *(float4*)&bv[0] = *(const float4*)(b + d0);
    *(float4*)&bv[4] = *(const float4*)(b + d0 + 4);
#pragma unroll
    for (int i = 0; i < 8; i++) {
        xc[i] = (vc[i] - mc) * rc * gv[i] + bv[i];
        xp[i] = u ? (vp[i] - mp) * rp * gv[i] + bv[i] : 0.f;
    }

    size_t ob = (size_t)row * 512 + d0;
    float a[8];
    unsigned short o16[8];
    *(float4*)&a[0] = *(const float4*)(mk + d0);
    *(float4*)&a[4] = *(const float4*)(mk + d0 + 4);
#pragma unroll
    for (int i = 0; i < 8; i++) o16[i] = f2b(xc[i] * a[i] + xp[i] * (1.f - a[i]));
    *(u16x8*)((unsigned short*)ok + ob) = *(u16x8*)o16;
    if constexpr (NOUT == 3) {
        *(float4*)&a[0] = *(const float4*)(mv + d0);
        *(float4*)&a[4] = *(const float4*)(mv + d0 + 4);
#pragma unroll
        for (int i = 0; i < 8; i++) o16[i] = f2b(xc[i] * a[i] + xp[i] * (1.f - a[i]));
        *(u16x8*)((unsigned short*)ov + ob) = *(u16x8*)o16;
    }
    *(float4*)&a[0] = *(const float4*)(mr + d0);
    *(float4*)&a[4] = *(const float4*)(mr + d0 + 4);
#pragma unroll
    for (int i = 0; i < 8; i++) o16[i] = f2b(xc[i] * a[i] + xp[i] * (1.f - a[i]));
    *(u16x8*)((unsigned short*)orr + ob) = *(u16x8*)o16;
}

// ---------------------------------------------------------------------------
// WKV sequential scan; one thread per (b,d); 4-step software pipeline
// (12 independent loads in flight per 4 compute steps). out = bf16(r*wkv).
// ---------------------------------------------------------------------------
__global__ __launch_bounds__(64) void wkv_k(
    const float* __restrict__ kbuf, const float* __restrict__ vbuf,
    const float* __restrict__ rbuf, bf16* __restrict__ outbuf,
    const float* __restrict__ decay, const float* __restrict__ first)
{
    int idx = blockIdx.x * 64 + threadIdx.x;
    int d = idx & 511;
    int b = idx >> 9;
    float w = -__expf(decay[d]);
    float u = first[d];
    float aa = 0.f, bb = 0.f, pp = -1e38f;
    size_t base = (size_t)b * 1024 * 512 + d;
    float kc[4], vc[4], rc[4];
#pragma unroll
    for (int j = 0; j < 4; j++) {
        kc[j] = kbuf[base + (size_t)j * 512];
        vc[j] = vbuf[base + (size_t)j * 512];
        rc[j] = rbuf[base + (size_t)j * 512];
    }
    for (int t = 0; t < 1024; t += 4) {
        float kn[4] = {0, 0, 0, 0}, vn[4] = {0, 0, 0, 0}, rn[4] = {0, 0, 0, 0};
        if (t + 4 < 1024) {
            size_t nb = base + (size_t)(t + 4) * 512;
#pragma unroll
            for (int j = 0; j < 4; j++) {
                kn[j] = kbuf[nb + (size_t)j * 512];
                vn[j] = vbuf[nb + (size_t)j * 512];
                rn[j] = rbuf[nb + (size_t)j * 512];
            }
        }
#pragma unroll
        for (int j = 0; j < 4; j++) {
            float kt = kc[j], vt = vc[j], rt = rc[j];
            float ww = u + kt;
            float p = pp > ww ? pp : ww;
            float e1 = __expf(pp - p), e2 = __expf(ww - p);
            float out = (e1 * aa + e2 * vt) / (e1 * bb + e2);
            outbuf[base + (size_t)(t + j) * 512] = __float2bfloat16(rt * out);
            float ww2 = pp + w;
            float p2 = ww2 > kt ? ww2 : kt;
            e1 = __expf(ww2 - p2);
            e2 = __expf(kt - p2);
            aa = e1 * aa + e2 * vt;
            bb = e1 * bb + e2;
            pp = p2;
        }
#pragma unroll
        for (int j = 0; j < 4; j++) { kc[j] = kn[j]; vc[j] = vn[j]; rc[j] = rn[j]; }
    }
}

__global__ void olens_k(const int* __restrict__ x_len, float* __restrict__ out)
{
    int i = threadIdx.x;
    if (i < 8) {
        int l1 = (x_len[i] - 1) / 2 + 1;
        int ol = (l1 - 1) / 2 + 1;
        out[i] = (float)ol;
    }
}

// ---------------------------------------------------------------------------
extern "C" void kernel_launch(void* const* d_in, const int* in_sizes, int n_in,
                              void* d_out, int out_size, void* d_ws, size_t ws_size,
                              hipStream_t stream)
{
    (void)in_sizes; (void)n_in; (void)out_size; (void)ws_size;
    const float* x         = (const float*)d_in[0];
    const int*   x_len     = (const int*)d_in[1];
    const float* conv1_w   = (const float*)d_in[2];
    const float* conv1_b   = (const float*)d_in[3];
    const float* conv2_w   = (const float*)d_in[4];
    const float* conv2_b   = (const float*)d_in[5];
    const float* conv3_w   = (const float*)d_in[6];
    const float* conv3_b   = (const float*)d_in[7];
    const float* embed_w   = (const float*)d_in[8];
    const float* embed_b   = (const float*)d_in[9];
    const float* embed_ln_g= (const float*)d_in[10];
    const float* embed_ln_b= (const float*)d_in[11];
    const float* ln_att_g  = (const float*)d_in[12];
    const float* ln_att_b  = (const float*)d_in[13];
    const float* att_decay = (const float*)d_in[14];
    const float* att_first = (const float*)d_in[15];
    const float* att_mix_k = (const float*)d_in[16];
    const float* att_mix_v = (const float*)d_in[17];
    const float* att_mix_r = (const float*)d_in[18];
    const float* att_wk    = (const float*)d_in[19];
    const float* att_wv    = (const float*)d_in[20];
    const float* att_wr    = (const float*)d_in[21];
    const float* att_wo    = (const float*)d_in[22];
    const float* ln_ffn_g  = (const float*)d_in[23];
    const float* ln_ffn_b  = (const float*)d_in[24];
    const float* ffn_mix_k = (const float*)d_in[25];
    const float* ffn_mix_r = (const float*)d_in[26];
    const float* ffn_wk    = (const float*)d_in[27];
    const float* ffn_wv    = (const float*)d_in[28];
    const float* ffn_wr    = (const float*)d_in[29];
    const float* final_ln_g= (const float*)d_in[30];
    const float* final_ln_b= (const float*)d_in[31];

    // ---- workspace layout (MiB offsets, ~183 MiB) ----
    // 0..16 h | 16..32 xn | 32..40 rwkvb | 40..64 xkvr (xf aliases 40..56)
    // 64..112 kvrb | 112..144 kkb
    // conv overlay: c1b 40..80 | c2b(halo) 80..102.1 | zpg 103..103.004 |
    //               c3b 104..144
    // weights: attT 144..150 | attTo 150..152 | ffnT 152..162 | ffnTv 162..170
    //          embT 170..180 | c2wb 180..180.6 | c3wb 180.6..182.9
    char* wsb = (char*)d_ws;
    float* h     = (float*)(wsb);
    float* xn    = (float*)(wsb + (16LL << 20));
    bf16*  rwkvb = (bf16*) (wsb + (32LL << 20));
    bf16*  xkvr  = (bf16*) (wsb + (40LL << 20));   // [3][8192][512] bf16
    bf16*  xf    = xkvr;                           // [2][8192][512] bf16 (ffn)
    float* kvrb  = (float*)(wsb + (64LL << 20));   // [3][8192][512] f32
    bf16*  kkb   = (bf16*) (wsb + (112LL << 20));  // [8192][2048] bf16
    bf16*  c1b   = (bf16*) (wsb + (40LL << 20));   // (2,2048,40,128)
    bf16*  c2b   = (bf16*) (wsb + (80LL << 20));   // (2,1026,22,256) halo
    bf16*  zpg   = (bf16*) (wsb + (103LL << 20));  // 4KB zero page (conv2 OOB)
    bf16*  c3b   = (bf16*) (wsb + (104LL << 20));  // (2048,10240)
    bf16*  attT  = (bf16*) (wsb + (144LL << 20));  // 4 x [1536][512] (k,v,r)
    bf16*  attTo = (bf16*) (wsb + (150LL << 20));  // 4 x [512][512]  (wo)
    bf16*  ffnT  = (bf16*) (wsb + (152LL << 20));  // 4 x [2560][512] (wk|wr)
    bf16*  ffnTv = (bf16*) (wsb + (162LL << 20));  // 4 x [512][2048]
    bf16*  embT  = (bf16*) (wsb + (170LL << 20));  // [512][10240]
    bf16*  c2wb  = (bf16*) (wsb + (180LL << 20));  // 256 x 1152
    bf16*  c3wb  = (bf16*) (wsb + (180LL << 20) + 589824);  // 512 x 2304

    const size_t MD = 8192LL * 512;

    // ---- weight prep: packed transposed bf16
    transpose_k<<<dim3(16, 16, 4), 256, 0, stream>>>(att_wk, attT, 512, 512, 786432);
    transpose_k<<<dim3(16, 16, 4), 256, 0, stream>>>(att_wv, attT + 262144, 512, 512, 786432);
    transpose_k<<<dim3(16, 16, 4), 256, 0, stream>>>(att_wr, attT + 524288, 512, 512, 786432);
    transpose_k<<<dim3(16, 16, 4), 256, 0, stream>>>(att_wo, attTo, 512, 512, 262144);
    transpose_k<<<dim3(64, 16, 4), 256, 0, stream>>>(ffn_wk, ffnT, 512, 2048, 1310720);
    transpose_k<<<dim3(16, 16, 4), 256, 0, stream>>>(ffn_wr, ffnT + 1048576, 512, 512, 1310720);
    transpose_k<<<dim3(16, 64, 4), 256, 0, stream>>>(ffn_wv, ffnTv, 2048, 512, 1048576);
    transpose_k<<<dim3(16, 320, 1), 256, 0, stream>>>(embed_w, embT, 10240, 512, 0);
    reorder_w_k<<<1152, 256, 0, stream>>>(conv2_w, c2wb, 256, 128);
    reorder_w_k<<<4608, 256, 0, stream>>>(conv3_w, c3wb, 512, 256);
    hipMemsetAsync(xn, 0, 16LL << 20, stream);
    hipMemsetAsync(c2b, 0, 2LL * 1026 * 22 * 256 * 2, stream);
    hipMemsetAsync(zpg, 0, 4096, stream);

    // ---- conv frontend + embed (split-K x4, atomic), 2 batches per chunk
    for (int chunk = 0; chunk < 4; chunk++) {
        int b0 = chunk * 2;
        conv1_k<<<640, 256, 0, stream>>>(x + (size_t)b0 * 327680, conv1_w, conv1_b, c1b);
        gemm_k<128, B_CONV, EP_CONV_CL, 0, 2048, 40, 2, 128, 0><<<dim3(320, 2), 256, 0, stream>>>(
            c2wb, zpg, c1b, nullptr, c2b, conv2_b, nullptr, 256, 40960, 1152, 1152);
        gemm_k<128, B_CONV, EP_CONV_T, 0, 1024, 20, 1, 256, 1><<<dim3(320, 4), 256, 0, stream>>>(
            c3wb, nullptr, c2b, nullptr, c3b, conv3_b, nullptr, 512, 40960, 2304, 2304);
        gemm_k<64, B_T, EP_ATOMIC, 0, 0, 0, 0, 0, 0><<<dim3(4, 32, 4), 256, 0, stream>>>(
            c3b, embT, nullptr, xn + (size_t)b0 * 1024 * 512, nullptr, embed_b, nullptr,
            2048, 512, 10240, 2560);
    }
    ln_k<<<2048, 256, 0, stream>>>(xn, h, embed_ln_g, embed_ln_b, 8192);

    // ---- 4 RWKV blocks
    for (int i = 0; i < 4; i++) {
        // time mixing (LN fused into mix)
        lnmix_k<3><<<2048, 256, 0, stream>>>(h, ln_att_g + i * 512, ln_att_b + i * 512,
                                             att_mix_k + i * 512, att_mix_v + i * 512,
                                             att_mix_r + i * 512,
                                             xkvr, xkvr + MD, xkvr + 2 * MD);
        gemm_k<64, B_T, EP_KVR, 9, 0, 0, 0, 0, 0><<<dim3(12, 128), 256, 0, stream>>>(
            xkvr, attT + (size_t)i * 786432, nullptr, kvrb, nullptr, nullptr, nullptr,
            8192, 1536, 512, 512);
        wkv_k<<<64, 64, 0, stream>>>(kvrb, kvrb + MD, kvrb + 2 * MD, rwkvb,
                                     att_decay + i * 512, att_first + i * 512);
        gemm_k<64, B_T, EP_ADD, 0, 0, 0, 0, 0, 0><<<dim3(4, 128), 256, 0, stream>>>(
            rwkvb, attTo + (size_t)i * 262144, nullptr, h, nullptr, nullptr, nullptr,
            8192, 512, 512, 512);
        // channel mixing (LN fused into mix)
        lnmix_k<2><<<2048, 256, 0, stream>>>(h, ln_ffn_g + i * 512, ln_ffn_b + i * 512,
                                             ffn_mix_k + i * 512, nullptr,
                                             ffn_mix_r + i * 512,
                                             xf, nullptr, xf + MD);
        gemm_k<64, B_T, EP_FFN, 11, 0, 0, 0, 0, 0><<<dim3(20, 128), 256, 0, stream>>>(
            xf, ffnT + (size_t)i * 1310720, nullptr, kvrb + 2 * MD, kkb, nullptr, nullptr,
            8192, 2560, 512, 512);
        gemm_k<64, B_T, EP_ADDMUL, 0, 0, 0, 0, 0, 0><<<dim3(4, 128), 256, 0, stream>>>(
            kkb, ffnTv + (size_t)i * 1048576, nullptr, h, nullptr, nullptr, kvrb + 2 * MD,
            8192, 512, 2048, 2048);
    }

    // ---- final LN straight into d_out, then olens
    ln_k<<<2048, 256, 0, stream>>>(h, (float*)d_out, final_ln_g, final_ln_b, 8192);
    olens_k<<<1, 64, 0, stream>>>(x_len, (float*)d_out + 4194304);
}

// Round 2
// 2576.167 us; speedup vs baseline: 1.0795x; 1.0303x over previous
//
#include <hip/hip_runtime.h>
#include <hip/hip_bf16.h>

typedef __hip_bfloat16 bf16;
typedef __bf16 v8bf __attribute__((ext_vector_type(8)));
typedef float v4f __attribute__((ext_vector_type(4)));
typedef unsigned short u16x8 __attribute__((ext_vector_type(8)));

// ---------------------------------------------------------------------------
//   x: (8,4096,80) -> conv1(1->128,s2) -> (8,2048,40,128)   [channel-last]
//   -> conv2(128->256,s2) -> halo (8,1026,22,256)           [channel-last+halo]
//   -> conv3(256->512,s1) -> tokens (8,1024,10240)          [token-major]
//   -> embed GEMM (split-K) -> 4 RWKV blocks -> final LN
// GEMM core: bf16 MFMA 16x16x32, TM x 128 tile, BK=32.
// Staging: __builtin_amdgcn_global_load_lds width=16 into LINEAR (unpadded)
// [rows][32] bf16 LDS tiles, DOUBLE-BUFFERED 2-phase schedule (T3 minimum
// recipe): issue STAGE(t+1) before ds_read+MFMA of t; ONE
// __syncthreads() (vmcnt0+lgkm0+barrier) per K-step. Loads for t+1 are in
// flight across the whole compute phase of t.
// conv2 OOB taps read a zeroed 4KB page (passed via Bw).
// ---------------------------------------------------------------------------

constexpr int B_T = 0, B_CONV = 1;
constexpr int EP_CONV_CL = 0, EP_CONV_T = 1, EP_ATOMIC = 2, EP_KVR = 3,
              EP_ADD = 4, EP_FFN = 5, EP_ADDMUL = 6;

static __device__ __forceinline__ unsigned short f2b(float f) {
    return __builtin_bit_cast(unsigned short, __float2bfloat16(f));
}

// global -> LDS async copy, 16B per lane. LDS dest must be the wave-uniform
// base; HW writes lane i at base + i*16.
static __device__ __forceinline__ void gld16(const unsigned short* g,
                                             unsigned short* l) {
    __builtin_amdgcn_global_load_lds(
        (__attribute__((address_space(1))) void*)g,
        (__attribute__((address_space(3))) void*)l, 16, 0, 0);
}

// ---------------------------------------------------------------------------
// MFMA GEMM: C[M,N] = A[M,K] * B[K,N]. A bf16 [M][K]; B bf16 [N][K] (B_T) or
// channel-last im2col gather (B_CONV; HALO=1 -> unconditional loads from the
// zero-padded (b,1026,22,256) buffer; HALO=0 -> OOB lanes read zero page Bw).
// ASH>0: A += (n0>>ASH)*M*K (fused ops).
// ---------------------------------------------------------------------------
template <int TM, int BL, int EPM, int ASH, int TIN, int FIN, int STRIDE,
          int ICN, int HALO>
__global__ __launch_bounds__(256) void gemm_k(
    const bf16* __restrict__ A, const bf16* __restrict__ Bw,
    const bf16* __restrict__ Bact,
    float* __restrict__ C, bf16* __restrict__ Cb,
    const float* __restrict__ bias, const float* __restrict__ mul,
    int M, int N, int K, int KLEN)
{
    constexpr int MI = TM / 32;
    __shared__ __align__(16) unsigned short As[2][TM * 32];
    __shared__ __align__(16) unsigned short Bs[2][128 * 32];
    const int tid = threadIdx.x;
    const int n0 = blockIdx.x * 128;
    const int m0 = blockIdx.y * TM;
    const int kbase = blockIdx.z * KLEN;
    const int kend = kbase + KLEN;
    const int wave = tid >> 6, lane = tid & 63;
    const int wr = wave >> 1, wc = wave & 1;
    const int lq = lane >> 4, lr = lane & 15;

    if constexpr (ASH > 0) A += (size_t)(n0 >> ASH) * M * K;

    v4f acc[MI][4];
#pragma unroll
    for (int i = 0; i < MI; i++)
#pragma unroll
        for (int j = 0; j < 4; j++) acc[i][j] = v4f{0.f, 0.f, 0.f, 0.f};

    // staging geometry: chunk = c*256 + tid -> row c*64 + (tid>>2), col (tid&3)*8
    const int sr = tid >> 2;
    const int sc = (tid & 3) * 8;

    // hoisted per-lane source pointers
    const unsigned short* aPtr[TM / 64];
#pragma unroll
    for (int c = 0; c < TM / 64; c++)
        aPtr[c] = (const unsigned short*)A + (size_t)(m0 + c * 64 + sr) * K + sc;

    const unsigned short* bPtr[2];
    int cb0 = 0, cb1 = 0, cto0 = 0, cto1 = 0, cfo0 = 0, cfo1 = 0;
    if constexpr (BL == B_T) {
#pragma unroll
        for (int c = 0; c < 2; c++)
            bPtr[c] = (const unsigned short*)Bw + (size_t)(n0 + c * 64 + sr) * K + sc;
    } else {
        {
            int n = n0 + sr;
            cb0 = n / 20480;
            int s = n - cb0 * 20480;
            cto0 = s / 20;
            cfo0 = s - cto0 * 20;
        }
        {
            int n = n0 + 64 + sr;
            cb1 = n / 20480;
            int s = n - cb1 * 20480;
            cto1 = s / 20;
            cfo1 = s - cto1 * 20;
        }
        if constexpr (HALO) {
            bPtr[0] = (const unsigned short*)Bact +
                      (((size_t)cb0 * 1026 + cto0) * 22 + cfo0) * 256 + sc;
            bPtr[1] = (const unsigned short*)Bact +
                      (((size_t)cb1 * 1026 + cto1) * 22 + cfo1) * 256 + sc;
        }
    }

    auto stageA = [&](int k0, int sel) {
#pragma unroll
        for (int c = 0; c < TM / 64; c++)
            gld16(aPtr[c] + k0, &As[sel][c * 2048 + wave * 512]);
    };
    auto stageB = [&](int k0, int sel) {
        if constexpr (BL == B_T) {
#pragma unroll
            for (int c = 0; c < 2; c++)
                gld16(bPtr[c] + k0, &Bs[sel][c * 2048 + wave * 512]);
        } else {
            int kg = k0 / ICN;             // kt*3+kf
            int ic = k0 - kg * ICN + sc;
            int kt = kg / 3, kf = kg - kt * 3;
            if constexpr (HALO) {          // conv3: zero-padded input
                gld16(bPtr[0] + (kt * 22 + kf) * 256 + ic, &Bs[sel][wave * 512]);
                gld16(bPtr[1] + (kt * 22 + kf) * 256 + ic, &Bs[sel][2048 + wave * 512]);
            } else {                       // conv2: clamp OOB to zero page (Bw)
                int ti0 = cto0 * STRIDE - 1 + kt, fi0 = cfo0 * STRIDE - 1 + kf;
                const unsigned short* s0 =
                    ((unsigned)ti0 < (unsigned)TIN && (unsigned)fi0 < (unsigned)FIN)
                    ? (const unsigned short*)Bact +
                      (((size_t)cb0 * TIN + ti0) * FIN + fi0) * ICN + ic
                    : (const unsigned short*)Bw;
                gld16(s0, &Bs[sel][wave * 512]);
                int ti1 = cto1 * STRIDE - 1 + kt, fi1 = cfo1 * STRIDE - 1 + kf;
                const unsigned short* s1 =
                    ((unsigned)ti1 < (unsigned)TIN && (unsigned)fi1 < (unsigned)FIN)
                    ? (const unsigned short*)Bact +
                      (((size_t)cb1 * TIN + ti1) * FIN + fi1) * ICN + ic
                    : (const unsigned short*)Bw;
                gld16(s1, &Bs[sel][2048 + wave * 512]);
            }
        }
    };

    // ---- 2-phase pipelined K-loop: prologue stage buf0, then per step:
    //      issue STAGE(t+1 -> other buf), compute t, single barrier (drains
    //      vmcnt so buf[t+1] is ready and all reads of buf[t] are done).
    stageA(kbase, 0);
    stageB(kbase, 0);
    __syncthreads();
    int cur = 0;
    for (int k0 = kbase; k0 < kend; k0 += 32) {
        const int nxt = cur ^ 1;
        if (k0 + 32 < kend) {
            stageA(k0 + 32, nxt);
            stageB(k0 + 32, nxt);
        }
        v8bf fa[MI], fb[4];
#pragma unroll
        for (int mi = 0; mi < MI; mi++)
            fa[mi] = *(const v8bf*)&As[cur][(wr * (TM / 2) + mi * 16 + lr) * 32 + lq * 8];
#pragma unroll
        for (int ni = 0; ni < 4; ni++)
            fb[ni] = *(const v8bf*)&Bs[cur][(wc * 64 + ni * 16 + lr) * 32 + lq * 8];
#pragma unroll
        for (int mi = 0; mi < MI; mi++)
#pragma unroll
            for (int ni = 0; ni < 4; ni++)
                acc[mi][ni] = __builtin_amdgcn_mfma_f32_16x16x32_bf16(
                    fa[mi], fb[ni], acc[mi][ni], 0, 0, 0);
        __syncthreads();   // drains vmcnt(0)+lgkmcnt(0): next buffer ready
        cur = nxt;
    }

    // ---- epilogue
#pragma unroll
    for (int mi = 0; mi < MI; mi++) {
#pragma unroll
        for (int ni = 0; ni < 4; ni++) {
#pragma unroll
            for (int reg = 0; reg < 4; reg++) {
                int row = m0 + wr * (TM / 2) + mi * 16 + lq * 4 + reg;
                int col = n0 + wc * 64 + ni * 16 + lr;
                float v = acc[mi][ni][reg];
                if constexpr (EPM == EP_CONV_CL) {
                    v += bias[row];
                    v = v > 0.f ? v : 0.f;
                    int b = col / 20480;
                    int s = col - b * 20480;
                    int t = s / 20, fo = s - t * 20;
                    Cb[(((size_t)b * 1026 + t + 1) * 22 + fo + 1) * 256 + row] =
                        __float2bfloat16(v);
                } else if constexpr (EPM == EP_CONV_T) {
                    v += bias[row];
                    v = v > 0.f ? v : 0.f;
                    int b = col / 20480;
                    int s = col - b * 20480;
                    int t = s / 20, fo = s - t * 20;
                    Cb[(size_t)(b * 1024 + t) * 10240 + row * 20 + fo] = __float2bfloat16(v);
                } else if constexpr (EPM == EP_ATOMIC) {
                    float add = (blockIdx.z == 0) ? bias[col] : 0.f;
                    atomicAdd(&C[(size_t)row * N + col], v + add);
                } else if constexpr (EPM == EP_KVR) {
                    int seg = col >> 9;     // 0=k,1=v,2=r (uniform per block)
                    if (seg == 2) v = 1.f / (1.f + __expf(-v));
                    C[(size_t)seg * M * 512 + (size_t)row * 512 + (col & 511)] = v;
                } else if constexpr (EPM == EP_ADD) {
                    C[(size_t)row * N + col] += v;
                } else if constexpr (EPM == EP_FFN) {
                    if (col < 2048) {       // wk branch: sqrelu -> bf16 kkb
                        float t = v > 0.f ? v : 0.f;
                        Cb[(size_t)row * 2048 + col] = __float2bfloat16(t * t);
                    } else {                // wr branch: sigmoid -> f32 rb
                        C[(size_t)row * 512 + (col - 2048)] = 1.f / (1.f + __expf(-v));
                    }
                } else if constexpr (EPM == EP_ADDMUL) {
                    size_t idx = (size_t)row * N + col;
                    C[idx] += mul[idx] * v;
                }
            }
        }
    }
}

// ---------------------------------------------------------------------------
// Prep: conv weight OIHW f32 -> bf16 [oc][(kt*3+kf)*IC + ic]
// ---------------------------------------------------------------------------
__global__ __launch_bounds__(256) void reorder_w_k(const float* __restrict__ in,
                                                   bf16* __restrict__ out,
                                                   int OC, int IC)
{
    int idx = blockIdx.x * 256 + threadIdx.x;
    if (idx >= OC * IC * 9) return;
    int oc = idx / (IC * 9);
    int r = idx - oc * (IC * 9);
    int g = r / IC;
    int ic = r - g * IC;
    out[idx] = __float2bfloat16(in[((size_t)oc * IC + ic) * 9 + g]);
}

// ---------------------------------------------------------------------------
// Prep: f32 [K][N] -> bf16 [N][K]; z: in stride K*N, out stride ozs
// ---------------------------------------------------------------------------
__global__ __launch_bounds__(256) void transpose_k(const float* __restrict__ in,
                                                   bf16* __restrict__ out,
                                                   int K, int N, size_t ozs)
{
    __shared__ float t[32][33];
    const float* pin = in + (size_t)blockIdx.z * K * N;
    bf16* pout = out + (size_t)blockIdx.z * ozs;
    int n0 = blockIdx.x * 32, k0 = blockIdx.y * 32;
    int tx = threadIdx.x & 31, ty = threadIdx.x >> 5;
#pragma unroll
    for (int i = 0; i < 32; i += 8)
        t[ty + i][tx] = pin[(size_t)(k0 + ty + i) * N + n0 + tx];
    __syncthreads();
#pragma unroll
    for (int i = 0; i < 32; i += 8)
        pout[(size_t)(n0 + ty + i) * K + k0 + tx] = __float2bfloat16(t[tx][ty + i]);
}

// ---------------------------------------------------------------------------
// conv1 for a 2-batch chunk: 1 input channel, direct, channel-last output.
// ---------------------------------------------------------------------------
__global__ __launch_bounds__(256) void conv1_k(
    const float* __restrict__ x, const float* __restrict__ w,
    const float* __restrict__ bias, bf16* __restrict__ out)
{
    __shared__ float ws_[128 * 9];
    __shared__ float bs_[128];
    const int tid = threadIdx.x;
    for (int i = tid; i < 128 * 9; i += 256) ws_[i] = w[i];
    if (tid < 128) bs_[tid] = bias[tid];
    __syncthreads();

    int idx = blockIdx.x * 256 + tid;  // 2*2048*40
    int f = idx % 40;
    int t = (idx / 40) & 2047;
    int b = idx / 81920;

    float xin[9];
#pragma unroll
    for (int kt = 0; kt < 3; kt++)
#pragma unroll
        for (int kf = 0; kf < 3; kf++) {
            int ti = 2 * t - 1 + kt, fi = 2 * f - 1 + kf;
            float v = 0.f;
            if ((unsigned)ti < 4096u && (unsigned)fi < 80u)
                v = x[(size_t)b * 327680 + (size_t)ti * 80 + fi];
            xin[kt * 3 + kf] = v;
        }
    unsigned short* outu = (unsigned short*)out + (size_t)idx * 128;
#pragma unroll
    for (int oc8 = 0; oc8 < 16; oc8++) {
        unsigned short pk[8];
#pragma unroll
        for (int j = 0; j < 8; j++) {
            int oc = oc8 * 8 + j;
            float a = bs_[oc];
#pragma unroll
            for (int q = 0; q < 9; q++) a += ws_[oc * 9 + q] * xin[q];
            a = a > 0.f ? a : 0.f;
            pk[j] = f2b(a);
        }
        *(u16x8*)&outu[oc8 * 8] = *(u16x8*)pk;
    }
}

// ---------------------------------------------------------------------------
// LayerNorm over D=512, one wave per row (4 rows / block)
// ---------------------------------------------------------------------------
__global__ __launch_bounds__(256) void ln_k(
    const float* __restrict__ in, float* __restrict__ out,
    const float* __restrict__ g, const float* __restrict__ b, int M)
{
    int wave = threadIdx.x >> 6;
    int lane = threadIdx.x & 63;
    int row = blockIdx.x * 4 + wave;
    if (row >= M) return;
    const float* p = in + (size_t)row * 512;
    float v[8], s = 0.f, sq = 0.f;
#pragma unroll
    for (int i = 0; i < 8; i++) {
        v[i] = p[lane + i * 64];
        s += v[i];
        sq += v[i] * v[i];
    }
#pragma unroll
    for (int o = 32; o > 0; o >>= 1) {
        s += __shfl_xor(s, o, 64);
        sq += __shfl_xor(sq, o, 64);
    }
    float mean = s * (1.f / 512.f);
    float var = sq * (1.f / 512.f) - mean * mean;
    float r = rsqrtf(var + 1e-5f);
    float* q = out + (size_t)row * 512;
#pragma unroll
    for (int i = 0; i < 8; i++) {
        int d = lane + i * 64;
        q[d] = (v[i] - mean) * r * g[d] + b[d];
    }
}

// ---------------------------------------------------------------------------
// Fused LN + token-shift mix -> bf16 operands. One wave per row; the wave
// also recomputes the predecessor row's LN (exact same f32 math). Lane owns
// 8 contiguous dims (16-B loads/stores). NOUT=3 (att) or 2 (ffn).
// ---------------------------------------------------------------------------
template <int NOUT>
__global__ __launch_bounds__(256) void lnmix_k(
    const float* __restrict__ hb, const float* __restrict__ g,
    const float* __restrict__ b, const float* __restrict__ mk,
    const float* __restrict__ mv, const float* __restrict__ mr,
    bf16* __restrict__ ok, bf16* __restrict__ ov, bf16* __restrict__ orr)
{
    int wave = threadIdx.x >> 6, lane = threadIdx.x & 63;
    int row = blockIdx.x * 4 + wave;     // 8192 rows
    int u = row & 1023;
    int d0 = lane * 8;
    const float* pc = hb + (size_t)row * 512 + d0;

    float vc[8], vp[8];
    *(float4*)&vc[0] = *(const float4*)pc;
    *(float4*)&vc[4] = *(const float4*)(pc + 4);
    float s = 0.f, sq = 0.f, sp = 0.f, sqp = 0.f;
#pragma unroll
    for (int i = 0; i < 8; i++) { s += vc[i]; sq += vc[i] * vc[i]; }
    if (u) {
        *(float4*)&vp[0] = *(const float4*)(pc - 512);
        *(float4*)&vp[4] = *(const float4*)(pc - 508);
#pragma unroll
        for (int i = 0; i < 8; i++) { sp += vp[i]; sqp += vp[i] * vp[i]; }
    } else {
#pragma unroll
        for (int i = 0; i < 8; i++) vp[i] = 0.f;
    }
#pragma unroll
    for (int o = 32; o > 0; o >>= 1) {
        s += __shfl_xor(s, o, 64);
        sq += __shfl_xor(sq, o, 64);
        sp += __shfl_xor(sp, o, 64);
        sqp += __shfl_xor(sqp, o, 64);
    }
    float mc = s * (1.f / 512.f);
    float rc = rsqrtf(sq * (1.f / 512.f) - mc * mc + 1e-5f);
    float mp = sp * (1.f / 512.f);
    float rp = rsqrtf(sqp * (1.f / 512.f) - mp * mp + 1e-5f);

    float gv[8], bv[8], xc[8], xp[8];
    *(float4*)&gv[0] = *(const float4*)(g + d0);
    *(float4*)&gv[4] = *(const float4*)(g + d0 + 4);
    *(float4*)&bv[0] = *(const float4*)(b + d0);
    *(float4*)&bv[4] = *(const float4*)(b + d0 + 4);
#pragma unroll
    for (int i = 0; i < 8; i++) {
        xc[i] = (vc[i] - mc) * rc * gv[i] + bv[i];
        xp[i] = u ? (vp[i] - mp) * rp * gv[i] + bv[i] : 0.f;
    }

    size_t ob = (size_t)row * 512 + d0;
    float a[8];
    unsigned short o16[8];
    *(float4*)&a[0] = *(const float4*)(mk + d0);
    *(float4*)&a[4] = *(const float4*)(mk + d0 + 4);
#pragma unroll
    for (int i = 0; i < 8; i++) o16[i] = f2b(xc[i] * a[i] + xp[i] * (1.f - a[i]));
    *(u16x8*)((unsigned short*)ok + ob) = *(u16x8*)o16;
    if constexpr (NOUT == 3) {
        *(float4*)&a[0] = *(const float4*)(mv + d0);
        *(float4*)&a[4] = *(const float4*)(mv + d0 + 4);
#pragma unroll
        for (int i = 0; i < 8; i++) o16[i] = f2b(xc[i] * a[i] + xp[i] * (1.f - a[i]));
        *(u16x8*)((unsigned short*)ov + ob) = *(u16x8*)o16;
    }
    *(float4*)&a[0] = *(const float4*)(mr + d0);
    *(float4*)&a[4] = *(const float4*)(mr + d0 + 4);
#pragma unroll
    for (int i = 0; i < 8; i++) o16[i] = f2b(xc[i] * a[i] + xp[i] * (1.f - a[i]));
    *(u16x8*)((unsigned short*)orr + ob) = *(u16x8*)o16;
}

// ---------------------------------------------------------------------------
// WKV sequential scan; one thread per (b,d); 4-step software pipeline
// (12 independent loads in flight per 4 compute steps). out = bf16(r*wkv).
// ---------------------------------------------------------------------------
__global__ __launch_bounds__(64) void wkv_k(
    const float* __restrict__ kbuf, const float* __restrict__ vbuf,
    const float* __restrict__ rbuf, bf16* __restrict__ outbuf,
    const float* __restrict__ decay, const float* __restrict__ first)
{
    int idx = blockIdx.x * 64 + threadIdx.x;
    int d = idx & 511;
    int b = idx >> 9;
    float w = -__expf(decay[d]);
    float u = first[d];
    float aa = 0.f, bb = 0.f, pp = -1e38f;
    size_t base = (size_t)b * 1024 * 512 + d;
    float kc[4], vc[4], rc[4];
#pragma unroll
    for (int j = 0; j < 4; j++) {
        kc[j] = kbuf[base + (size_t)j * 512];
        vc[j] = vbuf[base + (size_t)j * 512];
        rc[j] = rbuf[base + (size_t)j * 512];
    }
    for (int t = 0; t < 1024; t += 4) {
        float kn[4] = {0, 0, 0, 0}, vn[4] = {0, 0, 0, 0}, rn[4] = {0, 0, 0, 0};
        if (t + 4 < 1024) {
            size_t nb = base + (size_t)(t + 4) * 512;
#pragma unroll
            for (int j = 0; j < 4; j++) {
                kn[j] = kbuf[nb + (size_t)j * 512];
                vn[j] = vbuf[nb + (size_t)j * 512];
                rn[j] = rbuf[nb + (size_t)j * 512];
            }
        }
#pragma unroll
        for (int j = 0; j < 4; j++) {
            float kt = kc[j], vt = vc[j], rt = rc[j];
            float ww = u + kt;
            float p = pp > ww ? pp : ww;
            float e1 = __expf(pp - p), e2 = __expf(ww - p);
            float out = (e1 * aa + e2 * vt) / (e1 * bb + e2);
            outbuf[base + (size_t)(t + j) * 512] = __float2bfloat16(rt * out);
            float ww2 = pp + w;
            float p2 = ww2 > kt ? ww2 : kt;
            e1 = __expf(ww2 - p2);
            e2 = __expf(kt - p2);
            aa = e1 * aa + e2 * vt;
            bb = e1 * bb + e2;
            pp = p2;
        }
#pragma unroll
        for (int j = 0; j < 4; j++) { kc[j] = kn[j]; vc[j] = vn[j]; rc[j] = rn[j]; }
    }
}

__global__ void olens_k(const int* __restrict__ x_len, float* __restrict__ out)
{
    int i = threadIdx.x;
    if (i < 8) {
        int l1 = (x_len[i] - 1) / 2 + 1;
        int ol = (l1 - 1) / 2 + 1;
        out[i] = (float)ol;
    }
}

// ---------------------------------------------------------------------------
extern "C" void kernel_launch(void* const* d_in, const int* in_sizes, int n_in,
                              void* d_out, int out_size, void* d_ws, size_t ws_size,
                              hipStream_t stream)
{
    (void)in_sizes; (void)n_in; (void)out_size; (void)ws_size;
    const float* x         = (const float*)d_in[0];
    const int*   x_len     = (const int*)d_in[1];
    const float* conv1_w   = (const float*)d_in[2];
    const float* conv1_b   = (const float*)d_in[3];
    const float* conv2_w   = (const float*)d_in[4];
    const float* conv2_b   = (const float*)d_in[5];
    const float* conv3_w   = (const float*)d_in[6];
    const float* conv3_b   = (const float*)d_in[7];
    const float* embed_w   = (const float*)d_in[8];
    const float* embed_b   = (const float*)d_in[9];
    const float* embed_ln_g= (const float*)d_in[10];
    const float* embed_ln_b= (const float*)d_in[11];
    const float* ln_att_g  = (const float*)d_in[12];
    const float* ln_att_b  = (const float*)d_in[13];
    const float* att_decay = (const float*)d_in[14];
    const float* att_first = (const float*)d_in[15];
    const float* att_mix_k = (const float*)d_in[16];
    const float* att_mix_v = (const float*)d_in[17];
    const float* att_mix_r = (const float*)d_in[18];
    const float* att_wk    = (const float*)d_in[19];
    const float* att_wv    = (const float*)d_in[20];
    const float* att_wr    = (const float*)d_in[21];
    const float* att_wo    = (const float*)d_in[22];
    const float* ln_ffn_g  = (const float*)d_in[23];
    const float* ln_ffn_b  = (const float*)d_in[24];
    const float* ffn_mix_k = (const float*)d_in[25];
    const float* ffn_mix_r = (const float*)d_in[26];
    const float* ffn_wk    = (const float*)d_in[27];
    const float* ffn_wv    = (const float*)d_in[28];
    const float* ffn_wr    = (const float*)d_in[29];
    const float* final_ln_g= (const float*)d_in[30];
    const float* final_ln_b= (const float*)d_in[31];

    // ---- workspace layout (MiB offsets, ~183 MiB) ----
    // 0..16 h | 16..32 xn | 32..40 rwkvb | 40..64 xkvr (xf aliases 40..56)
    // 64..112 kvrb | 112..144 kkb
    // conv overlay: c1b 40..80 | c2b(halo) 80..102.1 | zpg 103..103.004 |
    //               c3b 104..144
    // weights: attT 144..150 | attTo 150..152 | ffnT 152..162 | ffnTv 162..170
    //          embT 170..180 | c2wb 180..180.6 | c3wb 180.6..182.9
    char* wsb = (char*)d_ws;
    float* h     = (float*)(wsb);
    float* xn    = (float*)(wsb + (16LL << 20));
    bf16*  rwkvb = (bf16*) (wsb + (32LL << 20));
    bf16*  xkvr  = (bf16*) (wsb + (40LL << 20));   // [3][8192][512] bf16
    bf16*  xf    = xkvr;                           // [2][8192][512] bf16 (ffn)
    float* kvrb  = (float*)(wsb + (64LL << 20));   // [3][8192][512] f32
    bf16*  kkb   = (bf16*) (wsb + (112LL << 20));  // [8192][2048] bf16
    bf16*  c1b   = (bf16*) (wsb + (40LL << 20));   // (2,2048,40,128)
    bf16*  c2b   = (bf16*) (wsb + (80LL << 20));   // (2,1026,22,256) halo
    bf16*  zpg   = (bf16*) (wsb + (103LL << 20));  // 4KB zero page (conv2 OOB)
    bf16*  c3b   = (bf16*) (wsb + (104LL << 20));  // (2048,10240)
    bf16*  attT  = (bf16*) (wsb + (144LL << 20));  // 4 x [1536][512] (k,v,r)
    bf16*  attTo = (bf16*) (wsb + (150LL << 20));  // 4 x [512][512]  (wo)
    bf16*  ffnT  = (bf16*) (wsb + (152LL << 20));  // 4 x [2560][512] (wk|wr)
    bf16*  ffnTv = (bf16*) (wsb + (162LL << 20));  // 4 x [512][2048]
    bf16*  embT  = (bf16*) (wsb + (170LL << 20));  // [512][10240]
    bf16*  c2wb  = (bf16*) (wsb + (180LL << 20));  // 256 x 1152
    bf16*  c3wb  = (bf16*) (wsb + (180LL << 20) + 589824);  // 512 x 2304

    const size_t MD = 8192LL * 512;

    // ---- weight prep: packed transposed bf16
    transpose_k<<<dim3(16, 16, 4), 256, 0, stream>>>(att_wk, attT, 512, 512, 786432);
    transpose_k<<<dim3(16, 16, 4), 256, 0, stream>>>(att_wv, attT + 262144, 512, 512, 786432);
    transpose_k<<<dim3(16, 16, 4), 256, 0, stream>>>(att_wr, attT + 524288, 512, 512, 786432);
    transpose_k<<<dim3(16, 16, 4), 256, 0, stream>>>(att_wo, attTo, 512, 512, 262144);
    transpose_k<<<dim3(64, 16, 4), 256, 0, stream>>>(ffn_wk, ffnT, 512, 2048, 1310720);
    transpose_k<<<dim3(16, 16, 4), 256, 0, stream>>>(ffn_wr, ffnT + 1048576, 512, 512, 1310720);
    transpose_k<<<dim3(16, 64, 4), 256, 0, stream>>>(ffn_wv, ffnTv, 2048, 512, 1048576);
    transpose_k<<<dim3(16, 320, 1), 256, 0, stream>>>(embed_w, embT, 10240, 512, 0);
    reorder_w_k<<<1152, 256, 0, stream>>>(conv2_w, c2wb, 256, 128);
    reorder_w_k<<<4608, 256, 0, stream>>>(conv3_w, c3wb, 512, 256);
    hipMemsetAsync(xn, 0, 16LL << 20, stream);
    hipMemsetAsync(c2b, 0, 2LL * 1026 * 22 * 256 * 2, stream);
    hipMemsetAsync(zpg, 0, 4096, stream);

    // ---- conv frontend + embed (split-K x4, atomic), 2 batches per chunk
    for (int chunk = 0; chunk < 4; chunk++) {
        int b0 = chunk * 2;
        conv1_k<<<640, 256, 0, stream>>>(x + (size_t)b0 * 327680, conv1_w, conv1_b, c1b);
        gemm_k<128, B_CONV, EP_CONV_CL, 0, 2048, 40, 2, 128, 0><<<dim3(320, 2), 256, 0, stream>>>(
            c2wb, zpg, c1b, nullptr, c2b, conv2_b, nullptr, 256, 40960, 1152, 1152);
        gemm_k<128, B_CONV, EP_CONV_T, 0, 1024, 20, 1, 256, 1><<<dim3(320, 4), 256, 0, stream>>>(
            c3wb, nullptr, c2b, nullptr, c3b, conv3_b, nullptr, 512, 40960, 2304, 2304);
        gemm_k<64, B_T, EP_ATOMIC, 0, 0, 0, 0, 0, 0><<<dim3(4, 32, 4), 256, 0, stream>>>(
            c3b, embT, nullptr, xn + (size_t)b0 * 1024 * 512, nullptr, embed_b, nullptr,
            2048, 512, 10240, 2560);
    }
    ln_k<<<2048, 256, 0, stream>>>(xn, h, embed_ln_g, embed_ln_b, 8192);

    // ---- 4 RWKV blocks
    for (int i = 0; i < 4; i++) {
        // time mixing (LN fused into mix)
        lnmix_k<3><<<2048, 256, 0, stream>>>(h, ln_att_g + i * 512, ln_att_b + i * 512,
                                             att_mix_k + i * 512, att_mix_v + i * 512,
                                             att_mix_r + i * 512,
                                             xkvr, xkvr + MD, xkvr + 2 * MD);
        gemm_k<64, B_T, EP_KVR, 9, 0, 0, 0, 0, 0><<<dim3(12, 128), 256, 0, stream>>>(
            xkvr, attT + (size_t)i * 786432, nullptr, kvrb, nullptr, nullptr, nullptr,
            8192, 1536, 512, 512);
        wkv_k<<<64, 64, 0, stream>>>(kvrb, kvrb + MD, kvrb + 2 * MD, rwkvb,
                                     att_decay + i * 512, att_first + i * 512);
        gemm_k<64, B_T, EP_ADD, 0, 0, 0, 0, 0, 0><<<dim3(4, 128), 256, 0, stream>>>(
            rwkvb, attTo + (size_t)i * 262144, nullptr, h, nullptr, nullptr, nullptr,
            8192, 512, 512, 512);
        // channel mixing (LN fused into mix)
        lnmix_k<2><<<2048, 256, 0, stream>>>(h, ln_ffn_g + i * 512, ln_ffn_b + i * 512,
                                             ffn_mix_k + i * 512, nullptr,
                                             ffn_mix_r + i * 512,
                                             xf, nullptr, xf + MD);
        gemm_k<64, B_T, EP_FFN, 11, 0, 0, 0, 0, 0><<<dim3(20, 128), 256, 0, stream>>>(
            xf, ffnT + (size_t)i * 1310720, nullptr, kvrb + 2 * MD, kkb, nullptr, nullptr,
            8192, 2560, 512, 512);
        gemm_k<64, B_T, EP_ADDMUL, 0, 0, 0, 0, 0, 0><<<dim3(4, 128), 256, 0, stream>>>(
            kkb, ffnTv + (size_t)i * 1048576, nullptr, h, nullptr, nullptr, kvrb + 2 * MD,
            8192, 512, 2048, 2048);
    }

    // ---- final LN straight into d_out, then olens
    ln_k<<<2048, 256, 0, stream>>>(h, (float*)d_out, final_ln_g, final_ln_b, 8192);
    olens_k<<<1, 64, 0, stream>>>(x_len, (float*)d_out + 4194304);
}

// Round 3
// 2029.321 us; speedup vs baseline: 1.3704x; 1.2695x over previous
//
#include <hip/hip_runtime.h>
#include <hip/hip_bf16.h>

typedef __hip_bfloat16 bf16;
typedef __bf16 v8bf __attribute__((ext_vector_type(8)));
typedef float v4f __attribute__((ext_vector_type(4)));
typedef unsigned short u16x8 __attribute__((ext_vector_type(8)));

// ---------------------------------------------------------------------------
//   x: (8,4096,80) -> conv1(1->128,s2) -> (8,2048,40,128)   [channel-last]
//   -> conv2(128->256,s2) -> halo (8,1026,22,256)           [channel-last+halo]
//   -> conv3(256->512,s1) -> tokens (8,1024,10240)          [token-major]
//   -> embed GEMM (split-K) -> 4 RWKV blocks -> final LN
// GEMM core: bf16 MFMA 16x16x32, TM x 128 tile, BK=32.
// Staging: __builtin_amdgcn_global_load_lds width=16 into LINEAR (unpadded)
// [rows][32] bf16 LDS tiles, DOUBLE-BUFFERED 2-phase schedule.
// WKV: 3-pass chunked associative scan (C=64 chunks of T=16) replacing the
// 1024-deep serial scan (was 0.7% occupancy, 166us/dispatch).
// ---------------------------------------------------------------------------

constexpr int B_T = 0, B_CONV = 1;
constexpr int EP_CONV_CL = 0, EP_CONV_T = 1, EP_ATOMIC = 2, EP_KVR = 3,
              EP_ADD = 4, EP_FFN = 5, EP_ADDMUL = 6;

constexpr int WC = 64;          // wkv chunks per sequence
constexpr int WT = 1024 / WC;   // 16 steps per chunk
constexpr int WPLANE = WC * 4096;  // 262144 states per plane

static __device__ __forceinline__ unsigned short f2b(float f) {
    return __builtin_bit_cast(unsigned short, __float2bfloat16(f));
}

// global -> LDS async copy, 16B per lane. LDS dest must be the wave-uniform
// base; HW writes lane i at base + i*16.
static __device__ __forceinline__ void gld16(const unsigned short* g,
                                             unsigned short* l) {
    __builtin_amdgcn_global_load_lds(
        (__attribute__((address_space(1))) void*)g,
        (__attribute__((address_space(3))) void*)l, 16, 0, 0);
}

// ---------------------------------------------------------------------------
// MFMA GEMM: C[M,N] = A[M,K] * B[K,N]. A bf16 [M][K]; B bf16 [N][K] (B_T) or
// channel-last im2col gather (B_CONV; HALO=1 -> unconditional loads from the
// zero-padded (b,1026,22,256) buffer; HALO=0 -> OOB lanes read zero page Bw).
// ASH>0: A += (n0>>ASH)*M*K (fused ops).
// ---------------------------------------------------------------------------
template <int TM, int BL, int EPM, int ASH, int TIN, int FIN, int STRIDE,
          int ICN, int HALO>
__global__ __launch_bounds__(256) void gemm_k(
    const bf16* __restrict__ A, const bf16* __restrict__ Bw,
    const bf16* __restrict__ Bact,
    float* __restrict__ C, bf16* __restrict__ Cb,
    const float* __restrict__ bias, const float* __restrict__ mul,
    int M, int N, int K, int KLEN)
{
    constexpr int MI = TM / 32;
    __shared__ __align__(16) unsigned short As[2][TM * 32];
    __shared__ __align__(16) unsigned short Bs[2][128 * 32];
    const int tid = threadIdx.x;
    const int n0 = blockIdx.x * 128;
    const int m0 = blockIdx.y * TM;
    const int kbase = blockIdx.z * KLEN;
    const int kend = kbase + KLEN;
    const int wave = tid >> 6, lane = tid & 63;
    const int wr = wave >> 1, wc = wave & 1;
    const int lq = lane >> 4, lr = lane & 15;

    if constexpr (ASH > 0) A += (size_t)(n0 >> ASH) * M * K;

    v4f acc[MI][4];
#pragma unroll
    for (int i = 0; i < MI; i++)
#pragma unroll
        for (int j = 0; j < 4; j++) acc[i][j] = v4f{0.f, 0.f, 0.f, 0.f};

    // staging geometry: chunk = c*256 + tid -> row c*64 + (tid>>2), col (tid&3)*8
    const int sr = tid >> 2;
    const int sc = (tid & 3) * 8;

    // hoisted per-lane source pointers
    const unsigned short* aPtr[TM / 64];
#pragma unroll
    for (int c = 0; c < TM / 64; c++)
        aPtr[c] = (const unsigned short*)A + (size_t)(m0 + c * 64 + sr) * K + sc;

    const unsigned short* bPtr[2];
    int cb0 = 0, cb1 = 0, cto0 = 0, cto1 = 0, cfo0 = 0, cfo1 = 0;
    if constexpr (BL == B_T) {
#pragma unroll
        for (int c = 0; c < 2; c++)
            bPtr[c] = (const unsigned short*)Bw + (size_t)(n0 + c * 64 + sr) * K + sc;
    } else {
        {
            int n = n0 + sr;
            cb0 = n / 20480;
            int s = n - cb0 * 20480;
            cto0 = s / 20;
            cfo0 = s - cto0 * 20;
        }
        {
            int n = n0 + 64 + sr;
            cb1 = n / 20480;
            int s = n - cb1 * 20480;
            cto1 = s / 20;
            cfo1 = s - cto1 * 20;
        }
        if constexpr (HALO) {
            bPtr[0] = (const unsigned short*)Bact +
                      (((size_t)cb0 * 1026 + cto0) * 22 + cfo0) * 256 + sc;
            bPtr[1] = (const unsigned short*)Bact +
                      (((size_t)cb1 * 1026 + cto1) * 22 + cfo1) * 256 + sc;
        }
    }

    auto stageA = [&](int k0, int sel) {
#pragma unroll
        for (int c = 0; c < TM / 64; c++)
            gld16(aPtr[c] + k0, &As[sel][c * 2048 + wave * 512]);
    };
    auto stageB = [&](int k0, int sel) {
        if constexpr (BL == B_T) {
#pragma unroll
            for (int c = 0; c < 2; c++)
                gld16(bPtr[c] + k0, &Bs[sel][c * 2048 + wave * 512]);
        } else {
            int kg = k0 / ICN;             // kt*3+kf
            int ic = k0 - kg * ICN + sc;
            int kt = kg / 3, kf = kg - kt * 3;
            if constexpr (HALO) {          // conv3: zero-padded input
                gld16(bPtr[0] + (kt * 22 + kf) * 256 + ic, &Bs[sel][wave * 512]);
                gld16(bPtr[1] + (kt * 22 + kf) * 256 + ic, &Bs[sel][2048 + wave * 512]);
            } else {                       // conv2: clamp OOB to zero page (Bw)
                int ti0 = cto0 * STRIDE - 1 + kt, fi0 = cfo0 * STRIDE - 1 + kf;
                const unsigned short* s0 =
                    ((unsigned)ti0 < (unsigned)TIN && (unsigned)fi0 < (unsigned)FIN)
                    ? (const unsigned short*)Bact +
                      (((size_t)cb0 * TIN + ti0) * FIN + fi0) * ICN + ic
                    : (const unsigned short*)Bw;
                gld16(s0, &Bs[sel][wave * 512]);
                int ti1 = cto1 * STRIDE - 1 + kt, fi1 = cfo1 * STRIDE - 1 + kf;
                const unsigned short* s1 =
                    ((unsigned)ti1 < (unsigned)TIN && (unsigned)fi1 < (unsigned)FIN)
                    ? (const unsigned short*)Bact +
                      (((size_t)cb1 * TIN + ti1) * FIN + fi1) * ICN + ic
                    : (const unsigned short*)Bw;
                gld16(s1, &Bs[sel][2048 + wave * 512]);
            }
        }
    };

    // ---- 2-phase pipelined K-loop: prologue stage buf0, then per step:
    //      issue STAGE(t+1 -> other buf), compute t, single barrier (drains
    //      vmcnt so buf[t+1] is ready and all reads of buf[t] are done).
    stageA(kbase, 0);
    stageB(kbase, 0);
    __syncthreads();
    int cur = 0;
    for (int k0 = kbase; k0 < kend; k0 += 32) {
        const int nxt = cur ^ 1;
        if (k0 + 32 < kend) {
            stageA(k0 + 32, nxt);
            stageB(k0 + 32, nxt);
        }
        v8bf fa[MI], fb[4];
#pragma unroll
        for (int mi = 0; mi < MI; mi++)
            fa[mi] = *(const v8bf*)&As[cur][(wr * (TM / 2) + mi * 16 + lr) * 32 + lq * 8];
#pragma unroll
        for (int ni = 0; ni < 4; ni++)
            fb[ni] = *(const v8bf*)&Bs[cur][(wc * 64 + ni * 16 + lr) * 32 + lq * 8];
#pragma unroll
        for (int mi = 0; mi < MI; mi++)
#pragma unroll
            for (int ni = 0; ni < 4; ni++)
                acc[mi][ni] = __builtin_amdgcn_mfma_f32_16x16x32_bf16(
                    fa[mi], fb[ni], acc[mi][ni], 0, 0, 0);
        __syncthreads();   // drains vmcnt(0)+lgkmcnt(0): next buffer ready
        cur = nxt;
    }

    // ---- epilogue
#pragma unroll
    for (int mi = 0; mi < MI; mi++) {
#pragma unroll
        for (int ni = 0; ni < 4; ni++) {
#pragma unroll
            for (int reg = 0; reg < 4; reg++) {
                int row = m0 + wr * (TM / 2) + mi * 16 + lq * 4 + reg;
                int col = n0 + wc * 64 + ni * 16 + lr;
                float v = acc[mi][ni][reg];
                if constexpr (EPM == EP_CONV_CL) {
                    v += bias[row];
                    v = v > 0.f ? v : 0.f;
                    int b = col / 20480;
                    int s = col - b * 20480;
                    int t = s / 20, fo = s - t * 20;
                    Cb[(((size_t)b * 1026 + t + 1) * 22 + fo + 1) * 256 + row] =
                        __float2bfloat16(v);
                } else if constexpr (EPM == EP_CONV_T) {
                    v += bias[row];
                    v = v > 0.f ? v : 0.f;
                    int b = col / 20480;
                    int s = col - b * 20480;
                    int t = s / 20, fo = s - t * 20;
                    Cb[(size_t)(b * 1024 + t) * 10240 + row * 20 + fo] = __float2bfloat16(v);
                } else if constexpr (EPM == EP_ATOMIC) {
                    float add = (blockIdx.z == 0) ? bias[col] : 0.f;
                    atomicAdd(&C[(size_t)row * N + col], v + add);
                } else if constexpr (EPM == EP_KVR) {
                    int seg = col >> 9;     // 0=k,1=v,2=r (uniform per block)
                    if (seg == 2) v = 1.f / (1.f + __expf(-v));
                    C[(size_t)seg * M * 512 + (size_t)row * 512 + (col & 511)] = v;
                } else if constexpr (EPM == EP_ADD) {
                    C[(size_t)row * N + col] += v;
                } else if constexpr (EPM == EP_FFN) {
                    if (col < 2048) {       // wk branch: sqrelu -> bf16 kkb
                        float t = v > 0.f ? v : 0.f;
                        Cb[(size_t)row * 2048 + col] = __float2bfloat16(t * t);
                    } else {                // wr branch: sigmoid -> f32 rb
                        C[(size_t)row * 512 + (col - 2048)] = 1.f / (1.f + __expf(-v));
                    }
                } else if constexpr (EPM == EP_ADDMUL) {
                    size_t idx = (size_t)row * N + col;
                    C[idx] += mul[idx] * v;
                }
            }
        }
    }
}

// ---------------------------------------------------------------------------
// Prep: conv weight OIHW f32 -> bf16 [oc][(kt*3+kf)*IC + ic]
// ---------------------------------------------------------------------------
__global__ __launch_bounds__(256) void reorder_w_k(const float* __restrict__ in,
                                                   bf16* __restrict__ out,
                                                   int OC, int IC)
{
    int idx = blockIdx.x * 256 + threadIdx.x;
    if (idx >= OC * IC * 9) return;
    int oc = idx / (IC * 9);
    int r = idx - oc * (IC * 9);
    int g = r / IC;
    int ic = r - g * IC;
    out[idx] = __float2bfloat16(in[((size_t)oc * IC + ic) * 9 + g]);
}

// ---------------------------------------------------------------------------
// Prep: f32 [K][N] -> bf16 [N][K]; z: in stride K*N, out stride ozs
// ---------------------------------------------------------------------------
__global__ __launch_bounds__(256) void transpose_k(const float* __restrict__ in,
                                                   bf16* __restrict__ out,
                                                   int K, int N, size_t ozs)
{
    __shared__ float t[32][33];
    const float* pin = in + (size_t)blockIdx.z * K * N;
    bf16* pout = out + (size_t)blockIdx.z * ozs;
    int n0 = blockIdx.x * 32, k0 = blockIdx.y * 32;
    int tx = threadIdx.x & 31, ty = threadIdx.x >> 5;
#pragma unroll
    for (int i = 0; i < 32; i += 8)
        t[ty + i][tx] = pin[(size_t)(k0 + ty + i) * N + n0 + tx];
    __syncthreads();
#pragma unroll
    for (int i = 0; i < 32; i += 8)
        pout[(size_t)(n0 + ty + i) * K + k0 + tx] = __float2bfloat16(t[tx][ty + i]);
}

// ---------------------------------------------------------------------------
// conv1 for a 2-batch chunk: 1 input channel, direct, channel-last output.
// ---------------------------------------------------------------------------
__global__ __launch_bounds__(256) void conv1_k(
    const float* __restrict__ x, const float* __restrict__ w,
    const float* __restrict__ bias, bf16* __restrict__ out)
{
    __shared__ float ws_[128 * 9];
    __shared__ float bs_[128];
    const int tid = threadIdx.x;
    for (int i = tid; i < 128 * 9; i += 256) ws_[i] = w[i];
    if (tid < 128) bs_[tid] = bias[tid];
    __syncthreads();

    int idx = blockIdx.x * 256 + tid;  // 2*2048*40
    int f = idx % 40;
    int t = (idx / 40) & 2047;
    int b = idx / 81920;

    float xin[9];
#pragma unroll
    for (int kt = 0; kt < 3; kt++)
#pragma unroll
        for (int kf = 0; kf < 3; kf++) {
            int ti = 2 * t - 1 + kt, fi = 2 * f - 1 + kf;
            float v = 0.f;
            if ((unsigned)ti < 4096u && (unsigned)fi < 80u)
                v = x[(size_t)b * 327680 + (size_t)ti * 80 + fi];
            xin[kt * 3 + kf] = v;
        }
    unsigned short* outu = (unsigned short*)out + (size_t)idx * 128;
#pragma unroll
    for (int oc8 = 0; oc8 < 16; oc8++) {
        unsigned short pk[8];
#pragma unroll
        for (int j = 0; j < 8; j++) {
            int oc = oc8 * 8 + j;
            float a = bs_[oc];
#pragma unroll
            for (int q = 0; q < 9; q++) a += ws_[oc * 9 + q] * xin[q];
            a = a > 0.f ? a : 0.f;
            pk[j] = f2b(a);
        }
        *(u16x8*)&outu[oc8 * 8] = *(u16x8*)pk;
    }
}

// ---------------------------------------------------------------------------
// LayerNorm over D=512, one wave per row (4 rows / block)
// ---------------------------------------------------------------------------
__global__ __launch_bounds__(256) void ln_k(
    const float* __restrict__ in, float* __restrict__ out,
    const float* __restrict__ g, const float* __restrict__ b, int M)
{
    int wave = threadIdx.x >> 6;
    int lane = threadIdx.x & 63;
    int row = blockIdx.x * 4 + wave;
    if (row >= M) return;
    const float* p = in + (size_t)row * 512;
    float v[8], s = 0.f, sq = 0.f;
#pragma unroll
    for (int i = 0; i < 8; i++) {
        v[i] = p[lane + i * 64];
        s += v[i];
        sq += v[i] * v[i];
    }
#pragma unroll
    for (int o = 32; o > 0; o >>= 1) {
        s += __shfl_xor(s, o, 64);
        sq += __shfl_xor(sq, o, 64);
    }
    float mean = s * (1.f / 512.f);
    float var = sq * (1.f / 512.f) - mean * mean;
    float r = rsqrtf(var + 1e-5f);
    float* q = out + (size_t)row * 512;
#pragma unroll
    for (int i = 0; i < 8; i++) {
        int d = lane + i * 64;
        q[d] = (v[i] - mean) * r * g[d] + b[d];
    }
}

// ---------------------------------------------------------------------------
// Fused LN + token-shift mix -> bf16 operands. One wave per row; the wave
// also recomputes the predecessor row's LN (exact same f32 math). Lane owns
// 8 contiguous dims (16-B loads/stores). NOUT=3 (att) or 2 (ffn).
// ---------------------------------------------------------------------------
template <int NOUT>
__global__ __launch_bounds__(256) void lnmix_k(
    const float* __restrict__ hb, const float* __restrict__ g,
    const float* __restrict__ b, const float* __restrict__ mk,
    const float* __restrict__ mv, const float* __restrict__ mr,
    bf16* __restrict__ ok, bf16* __restrict__ ov, bf16* __restrict__ orr)
{
    int wave = threadIdx.x >> 6, lane = threadIdx.x & 63;
    int row = blockIdx.x * 4 + wave;     // 8192 rows
    int u = row & 1023;
    int d0 = lane * 8;
    const float* pc = hb + (size_t)row * 512 + d0;

    float vc[8], vp[8];
    *(float4*)&vc[0] = *(const float4*)pc;
    *(float4*)&vc[4] = *(const float4*)(pc + 4);
    float s = 0.f, sq = 0.f, sp = 0.f, sqp = 0.f;
#pragma unroll
    for (int i = 0; i < 8; i++) { s += vc[i]; sq += vc[i] * vc[i]; }
    if (u) {
        *(float4*)&vp[0] = *(const float4*)(pc - 512);
        *(float4*)&vp[4] = *(const float4*)(pc - 508);
#pragma unroll
        for (int i = 0; i < 8; i++) { sp += vp[i]; sqp += vp[i] * vp[i]; }
    } else {
#pragma unroll
        for (int i = 0; i < 8; i++) vp[i] = 0.f;
    }
#pragma unroll
    for (int o = 32; o > 0; o >>= 1) {
        s += __shfl_xor(s, o, 64);
        sq += __shfl_xor(sq, o, 64);
        sp += __shfl_xor(sp, o, 64);
        sqp += __shfl_xor(sqp, o, 64);
    }
    float mc = s * (1.f / 512.f);
    float rc = rsqrtf(sq * (1.f / 512.f) - mc * mc + 1e-5f);
    float mp = sp * (1.f / 512.f);
    float rp = rsqrtf(sqp * (1.f / 512.f) - mp * mp + 1e-5f);

    float gv[8], bv[8], xc[8], xp[8];
    *(float4*)&gv[0] = *(const float4*)(g + d0);
    *(float4*)&gv[4] = *(const float4*)(g + d0 + 4);
    *(float4*)&bv[0] = *(const float4*)(b + d0);
    *(float4*)&bv[4] = *(const float4*)(b + d0 + 4);
#pragma unroll
    for (int i = 0; i < 8; i++) {
        xc[i] = (vc[i] - mc) * rc * gv[i] + bv[i];
        xp[i] = u ? (vp[i] - mp) * rp * gv[i] + bv[i] : 0.f;
    }

    size_t ob = (size_t)row * 512 + d0;
    float a[8];
    unsigned short o16[8];
    *(float4*)&a[0] = *(const float4*)(mk + d0);
    *(float4*)&a[4] = *(const float4*)(mk + d0 + 4);
#pragma unroll
    for (int i = 0; i < 8; i++) o16[i] = f2b(xc[i] * a[i] + xp[i] * (1.f - a[i]));
    *(u16x8*)((unsigned short*)ok + ob) = *(u16x8*)o16;
    if constexpr (NOUT == 3) {
        *(float4*)&a[0] = *(const float4*)(mv + d0);
        *(float4*)&a[4] = *(const float4*)(mv + d0 + 4);
#pragma unroll
        for (int i = 0; i < 8; i++) o16[i] = f2b(xc[i] * a[i] + xp[i] * (1.f - a[i]));
        *(u16x8*)((unsigned short*)ov + ob) = *(u16x8*)o16;
    }
    *(float4*)&a[0] = *(const float4*)(mr + d0);
    *(float4*)&a[4] = *(const float4*)(mr + d0 + 4);
#pragma unroll
    for (int i = 0; i < 8; i++) o16[i] = f2b(xc[i] * a[i] + xp[i] * (1.f - a[i]));
    *(u16x8*)((unsigned short*)orr + ob) = *(u16x8*)o16;
}

// ---------------------------------------------------------------------------
// WKV chunked scan. State (aa,bb,pp): num = aa*e^pp, den = bb*e^pp.
// Chunk combine: S_out = e^{w*WT} * S_in + S_local (associative).
// Pass 1: per (chunk,b,d) local state from zero. idx = c*4096 + b*512 + d;
// planes [aa|bb|pp] stride WPLANE. Coalesced: consecutive threads = consec d.
// ---------------------------------------------------------------------------
__global__ __launch_bounds__(256) void wkv_loc_k(
    const float* __restrict__ kbuf, const float* __restrict__ vbuf,
    float* __restrict__ st, const float* __restrict__ decay)
{
    int idx = blockIdx.x * 256 + threadIdx.x;   // [c][b][d]
    int bd = idx & 4095;
    int c = idx >> 12;
    int d = bd & 511;
    int b = bd >> 9;
    float w = -__expf(decay[d]);
    float aa = 0.f, bb = 0.f, pp = -1e38f;
    size_t base = ((size_t)b * 1024 + c * WT) * 512 + d;
#pragma unroll
    for (int s = 0; s < WT; s++) {
        float kt = kbuf[base + (size_t)s * 512];
        float vt = vbuf[base + (size_t)s * 512];
        float ww2 = pp + w;
        float p2 = ww2 > kt ? ww2 : kt;
        float e1 = __expf(ww2 - p2), e2 = __expf(kt - p2);
        aa = e1 * aa + e2 * vt;
        bb = e1 * bb + e2;
        pp = p2;
    }
    st[idx] = aa;
    st[WPLANE + idx] = bb;
    st[2 * WPLANE + idx] = pp;
}

// ---------------------------------------------------------------------------
// Pass 2: per (b,d), fold WC chunk-local states sequentially; write EXCLUSIVE
// incoming state per chunk. Decay of a full chunk = e^{w*WT}.
// ---------------------------------------------------------------------------
__global__ __launch_bounds__(256) void wkv_comb_k(
    const float* __restrict__ loc, float* __restrict__ inc,
    const float* __restrict__ decay)
{
    int bd = blockIdx.x * 256 + threadIdx.x;  // 4096
    int d = bd & 511;
    float wT = -__expf(decay[d]) * (float)WT;
    float aa = 0.f, bb = 0.f, pp = -1e38f;
    for (int c = 0; c < WC; c++) {
        int i = c * 4096 + bd;
        inc[i] = aa;
        inc[WPLANE + i] = bb;
        inc[2 * WPLANE + i] = pp;
        float la = loc[i], lb = loc[WPLANE + i], lp = loc[2 * WPLANE + i];
        float pd = pp + wT;
        float p2 = pd > lp ? pd : lp;
        float e1 = __expf(pd - p2), e2 = __expf(lp - p2);
        aa = e1 * aa + e2 * la;
        bb = e1 * bb + e2 * lb;
        pp = p2;
    }
}

// ---------------------------------------------------------------------------
// Pass 3: per (chunk,b,d), replay chunk from incoming state with the exact
// original per-step math. out = bf16(r * wkv).
// ---------------------------------------------------------------------------
__global__ __launch_bounds__(256) void wkv_out_k(
    const float* __restrict__ kbuf, const float* __restrict__ vbuf,
    const float* __restrict__ rbuf, bf16* __restrict__ outbuf,
    const float* __restrict__ inc,
    const float* __restrict__ decay, const float* __restrict__ first)
{
    int idx = blockIdx.x * 256 + threadIdx.x;
    int bd = idx & 4095;
    int c = idx >> 12;
    int d = bd & 511;
    int b = bd >> 9;
    float w = -__expf(decay[d]);
    float u = first[d];
    float aa = inc[idx], bb = inc[WPLANE + idx], pp = inc[2 * WPLANE + idx];
    size_t base = ((size_t)b * 1024 + c * WT) * 512 + d;
#pragma unroll
    for (int s = 0; s < WT; s++) {
        float kt = kbuf[base + (size_t)s * 512];
        float vt = vbuf[base + (size_t)s * 512];
        float rt = rbuf[base + (size_t)s * 512];
        float ww = u + kt;
        float p = pp > ww ? pp : ww;
        float e1 = __expf(pp - p), e2 = __expf(ww - p);
        float out = (e1 * aa + e2 * vt) / (e1 * bb + e2);
        outbuf[base + (size_t)s * 512] = __float2bfloat16(rt * out);
        float ww2 = pp + w;
        float p2 = ww2 > kt ? ww2 : kt;
        e1 = __expf(ww2 - p2);
        e2 = __expf(kt - p2);
        aa = e1 * aa + e2 * vt;
        bb = e1 * bb + e2;
        pp = p2;
    }
}

__global__ void olens_k(const int* __restrict__ x_len, float* __restrict__ out)
{
    int i = threadIdx.x;
    if (i < 8) {
        int l1 = (x_len[i] - 1) / 2 + 1;
        int ol = (l1 - 1) / 2 + 1;
        out[i] = (float)ol;
    }
}

// ---------------------------------------------------------------------------
extern "C" void kernel_launch(void* const* d_in, const int* in_sizes, int n_in,
                              void* d_out, int out_size, void* d_ws, size_t ws_size,
                              hipStream_t stream)
{
    (void)in_sizes; (void)n_in; (void)out_size; (void)ws_size;
    const float* x         = (const float*)d_in[0];
    const int*   x_len     = (const int*)d_in[1];
    const float* conv1_w   = (const float*)d_in[2];
    const float* conv1_b   = (const float*)d_in[3];
    const float* conv2_w   = (const float*)d_in[4];
    const float* conv2_b   = (const float*)d_in[5];
    const float* conv3_w   = (const float*)d_in[6];
    const float* conv3_b   = (const float*)d_in[7];
    const float* embed_w   = (const float*)d_in[8];
    const float* embed_b   = (const float*)d_in[9];
    const float* embed_ln_g= (const float*)d_in[10];
    const float* embed_ln_b= (const float*)d_in[11];
    const float* ln_att_g  = (const float*)d_in[12];
    const float* ln_att_b  = (const float*)d_in[13];
    const float* att_decay = (const float*)d_in[14];
    const float* att_first = (const float*)d_in[15];
    const float* att_mix_k = (const float*)d_in[16];
    const float* att_mix_v = (const float*)d_in[17];
    const float* att_mix_r = (const float*)d_in[18];
    const float* att_wk    = (const float*)d_in[19];
    const float* att_wv    = (const float*)d_in[20];
    const float* att_wr    = (const float*)d_in[21];
    const float* att_wo    = (const float*)d_in[22];
    const float* ln_ffn_g  = (const float*)d_in[23];
    const float* ln_ffn_b  = (const float*)d_in[24];
    const float* ffn_mix_k = (const float*)d_in[25];
    const float* ffn_mix_r = (const float*)d_in[26];
    const float* ffn_wk    = (const float*)d_in[27];
    const float* ffn_wv    = (const float*)d_in[28];
    const float* ffn_wr    = (const float*)d_in[29];
    const float* final_ln_g= (const float*)d_in[30];
    const float* final_ln_b= (const float*)d_in[31];

    // ---- workspace layout (MiB offsets, ~183 MiB) ----
    // 0..16 h | 16..32 xn (frontend) / wkv states (RWKV loop) | 32..40 rwkvb
    // 40..64 xkvr (xf aliases 40..56) | 64..112 kvrb | 112..144 kkb
    // conv overlay: c1b 40..80 | c2b(halo) 80..102.1 | zpg 103..103.004 |
    //               c3b 104..144
    // weights: attT 144..150 | attTo 150..152 | ffnT 152..162 | ffnTv 162..170
    //          embT 170..180 | c2wb 180..180.6 | c3wb 180.6..182.9
    char* wsb = (char*)d_ws;
    float* h     = (float*)(wsb);
    float* xn    = (float*)(wsb + (16LL << 20));
    float* sloc  = (float*)(wsb + (16LL << 20));   // [3][WC][4096] f32 (3MB)
    float* sinc  = (float*)(wsb + (20LL << 20));   // [3][WC][4096] f32 (3MB)
    bf16*  rwkvb = (bf16*) (wsb + (32LL << 20));
    bf16*  xkvr  = (bf16*) (wsb + (40LL << 20));   // [3][8192][512] bf16
    bf16*  xf    = xkvr;                           // [2][8192][512] bf16 (ffn)
    float* kvrb  = (float*)(wsb + (64LL << 20));   // [3][8192][512] f32
    bf16*  kkb   = (bf16*) (wsb + (112LL << 20));  // [8192][2048] bf16
    bf16*  c1b   = (bf16*) (wsb + (40LL << 20));   // (2,2048,40,128)
    bf16*  c2b   = (bf16*) (wsb + (80LL << 20));   // (2,1026,22,256) halo
    bf16*  zpg   = (bf16*) (wsb + (103LL << 20));  // 4KB zero page (conv2 OOB)
    bf16*  c3b   = (bf16*) (wsb + (104LL << 20));  // (2048,10240)
    bf16*  attT  = (bf16*) (wsb + (144LL << 20));  // 4 x [1536][512] (k,v,r)
    bf16*  attTo = (bf16*) (wsb + (150LL << 20));  // 4 x [512][512]  (wo)
    bf16*  ffnT  = (bf16*) (wsb + (152LL << 20));  // 4 x [2560][512] (wk|wr)
    bf16*  ffnTv = (bf16*) (wsb + (162LL << 20));  // 4 x [512][2048]
    bf16*  embT  = (bf16*) (wsb + (170LL << 20));  // [512][10240]
    bf16*  c2wb  = (bf16*) (wsb + (180LL << 20));  // 256 x 1152
    bf16*  c3wb  = (bf16*) (wsb + (180LL << 20) + 589824);  // 512 x 2304

    const size_t MD = 8192LL * 512;

    // ---- weight prep: packed transposed bf16
    transpose_k<<<dim3(16, 16, 4), 256, 0, stream>>>(att_wk, attT, 512, 512, 786432);
    transpose_k<<<dim3(16, 16, 4), 256, 0, stream>>>(att_wv, attT + 262144, 512, 512, 786432);
    transpose_k<<<dim3(16, 16, 4), 256, 0, stream>>>(att_wr, attT + 524288, 512, 512, 786432);
    transpose_k<<<dim3(16, 16, 4), 256, 0, stream>>>(att_wo, attTo, 512, 512, 262144);
    transpose_k<<<dim3(64, 16, 4), 256, 0, stream>>>(ffn_wk, ffnT, 512, 2048, 1310720);
    transpose_k<<<dim3(16, 16, 4), 256, 0, stream>>>(ffn_wr, ffnT + 1048576, 512, 512, 1310720);
    transpose_k<<<dim3(16, 64, 4), 256, 0, stream>>>(ffn_wv, ffnTv, 2048, 512, 1048576);
    transpose_k<<<dim3(16, 320, 1), 256, 0, stream>>>(embed_w, embT, 10240, 512, 0);
    reorder_w_k<<<1152, 256, 0, stream>>>(conv2_w, c2wb, 256, 128);
    reorder_w_k<<<4608, 256, 0, stream>>>(conv3_w, c3wb, 512, 256);
    hipMemsetAsync(xn, 0, 16LL << 20, stream);
    hipMemsetAsync(c2b, 0, 2LL * 1026 * 22 * 256 * 2, stream);
    hipMemsetAsync(zpg, 0, 4096, stream);

    // ---- conv frontend + embed (split-K x4, atomic), 2 batches per chunk
    for (int chunk = 0; chunk < 4; chunk++) {
        int b0 = chunk * 2;
        conv1_k<<<640, 256, 0, stream>>>(x + (size_t)b0 * 327680, conv1_w, conv1_b, c1b);
        gemm_k<128, B_CONV, EP_CONV_CL, 0, 2048, 40, 2, 128, 0><<<dim3(320, 2), 256, 0, stream>>>(
            c2wb, zpg, c1b, nullptr, c2b, conv2_b, nullptr, 256, 40960, 1152, 1152);
        gemm_k<128, B_CONV, EP_CONV_T, 0, 1024, 20, 1, 256, 1><<<dim3(320, 4), 256, 0, stream>>>(
            c3wb, nullptr, c2b, nullptr, c3b, conv3_b, nullptr, 512, 40960, 2304, 2304);
        gemm_k<64, B_T, EP_ATOMIC, 0, 0, 0, 0, 0, 0><<<dim3(4, 32, 4), 256, 0, stream>>>(
            c3b, embT, nullptr, xn + (size_t)b0 * 1024 * 512, nullptr, embed_b, nullptr,
            2048, 512, 10240, 2560);
    }
    ln_k<<<2048, 256, 0, stream>>>(xn, h, embed_ln_g, embed_ln_b, 8192);

    // ---- 4 RWKV blocks
    for (int i = 0; i < 4; i++) {
        // time mixing (LN fused into mix)
        lnmix_k<3><<<2048, 256, 0, stream>>>(h, ln_att_g + i * 512, ln_att_b + i * 512,
                                             att_mix_k + i * 512, att_mix_v + i * 512,
                                             att_mix_r + i * 512,
                                             xkvr, xkvr + MD, xkvr + 2 * MD);
        gemm_k<64, B_T, EP_KVR, 9, 0, 0, 0, 0, 0><<<dim3(12, 128), 256, 0, stream>>>(
            xkvr, attT + (size_t)i * 786432, nullptr, kvrb, nullptr, nullptr, nullptr,
            8192, 1536, 512, 512);
        wkv_loc_k<<<1024, 256, 0, stream>>>(kvrb, kvrb + MD, sloc, att_decay + i * 512);
        wkv_comb_k<<<16, 256, 0, stream>>>(sloc, sinc, att_decay + i * 512);
        wkv_out_k<<<1024, 256, 0, stream>>>(kvrb, kvrb + MD, kvrb + 2 * MD, rwkvb,
                                            sinc, att_decay + i * 512, att_first + i * 512);
        gemm_k<64, B_T, EP_ADD, 0, 0, 0, 0, 0, 0><<<dim3(4, 128), 256, 0, stream>>>(
            rwkvb, attTo + (size_t)i * 262144, nullptr, h, nullptr, nullptr, nullptr,
            8192, 512, 512, 512);
        // channel mixing (LN fused into mix)
        lnmix_k<2><<<2048, 256, 0, stream>>>(h, ln_ffn_g + i * 512, ln_ffn_b + i * 512,
                                             ffn_mix_k + i * 512, nullptr,
                                             ffn_mix_r + i * 512,
                                             xf, nullptr, xf + MD);
        gemm_k<64, B_T, EP_FFN, 11, 0, 0, 0, 0, 0><<<dim3(20, 128), 256, 0, stream>>>(
            xf, ffnT + (size_t)i * 1310720, nullptr, kvrb + 2 * MD, kkb, nullptr, nullptr,
            8192, 2560, 512, 512);
        gemm_k<64, B_T, EP_ADDMUL, 0, 0, 0, 0, 0, 0><<<dim3(4, 128), 256, 0, stream>>>(
            kkb, ffnTv + (size_t)i * 1048576, nullptr, h, nullptr, nullptr, kvrb + 2 * MD,
            8192, 512, 2048, 2048);
    }

    // ---- final LN straight into d_out, then olens
    ln_k<<<2048, 256, 0, stream>>>(h, (float*)d_out, final_ln_g, final_ln_b, 8192);
    olens_k<<<1, 64, 0, stream>>>(x_len, (float*)d_out + 4194304);
}

// Round 5
// 1984.452 us; speedup vs baseline: 1.4014x; 1.0226x over previous
//
#include <hip/hip_runtime.h>
#include <hip/hip_bf16.h>

typedef __hip_bfloat16 bf16;
typedef __bf16 v8bf __attribute__((ext_vector_type(8)));
typedef float v4f __attribute__((ext_vector_type(4)));
typedef unsigned short u16x8 __attribute__((ext_vector_type(8)));

// ---------------------------------------------------------------------------
//   x: (8,4096,80) -> conv1(1->128,s2) -> (8,2048,40,128)   [channel-last]
//   -> conv2(128->256,s2) -> halo (8,1026,22,256)           [channel-last+halo]
//   -> conv3(256->512,s1) -> tokens (8,1024,10240)          [token-major]
//   -> embed GEMM (split-K) -> 4 RWKV blocks -> final LN
// GEMM core: bf16 MFMA 16x16x32, TM x 128 tile, BK=32.
// Staging: __builtin_amdgcn_global_load_lds width=16 into LINEAR (unpadded)
// [rows][32] bf16 LDS tiles, TRIPLE-BUFFERED counted-vmcnt pipeline (T3+T4):
// stages t..t+2 in flight; per phase: s_waitcnt vmcnt(2L) (NEVER 0 in steady
// state) + s_barrier -> compute(t) -> s_barrier -> stage(t+3). Only vmem ops
// in the K-loop are the global_load_lds, so vmcnt counts are exact.
// BUGFIX r4: conv3(HALO) B-staging double-added sc (bPtr already carries it);
// rounds 1-3 staged channel-shifted B (absmax 4.8). Now ic0 excludes sc.
// WKV: 3-pass chunked associative scan (C=64 chunks of T=16).
// ---------------------------------------------------------------------------

constexpr int B_T = 0, B_CONV = 1;
constexpr int EP_CONV_CL = 0, EP_CONV_T = 1, EP_ATOMIC = 2, EP_KVR = 3,
              EP_ADD = 4, EP_FFN = 5, EP_ADDMUL = 6;

constexpr int WC = 64;          // wkv chunks per sequence
constexpr int WT = 1024 / WC;   // 16 steps per chunk
constexpr int WPLANE = WC * 4096;  // 262144 states per plane

static __device__ __forceinline__ unsigned short f2b(float f) {
    return __builtin_bit_cast(unsigned short, __float2bfloat16(f));
}

// global -> LDS async copy, 16B per lane. LDS dest must be the wave-uniform
// base; HW writes lane i at base + i*16.
static __device__ __forceinline__ void gld16(const unsigned short* g,
                                             unsigned short* l) {
    __builtin_amdgcn_global_load_lds(
        (__attribute__((address_space(1))) void*)g,
        (__attribute__((address_space(3))) void*)l, 16, 0, 0);
}

// ---------------------------------------------------------------------------
// MFMA GEMM: C[M,N] = A[M,K] * B[K,N]. A bf16 [M][K]; B bf16 [N][K] (B_T) or
// channel-last im2col gather (B_CONV; HALO=1 -> unconditional loads from the
// zero-padded (b,1026,22,256) buffer; HALO=0 -> OOB lanes read zero page Bw).
// ASH>0: A += (n0>>ASH)*M*K (fused ops).
// Loads per wave per stage: L = TM/64 + 2 (TM=128 -> 4, TM=64 -> 3).
// Steady-state wait: vmcnt(2L); epilogue peels vmcnt(L), vmcnt(0).
// ---------------------------------------------------------------------------
template <int TM, int BL, int EPM, int ASH, int TIN, int FIN, int STRIDE,
          int ICN, int HALO>
__global__ __launch_bounds__(256) void gemm_k(
    const bf16* __restrict__ A, const bf16* __restrict__ Bw,
    const bf16* __restrict__ Bact,
    float* __restrict__ C, bf16* __restrict__ Cb,
    const float* __restrict__ bias, const float* __restrict__ mul,
    int M, int N, int K, int KLEN)
{
    constexpr int MI = TM / 32;
    __shared__ __align__(16) unsigned short As[3][TM * 32];
    __shared__ __align__(16) unsigned short Bs[3][128 * 32];
    const int tid = threadIdx.x;
    const int n0 = blockIdx.x * 128;
    const int m0 = blockIdx.y * TM;
    const int kbase = blockIdx.z * KLEN;
    const int wave = tid >> 6, lane = tid & 63;
    const int wr = wave >> 1, wc = wave & 1;
    const int lq = lane >> 4, lr = lane & 15;

    if constexpr (ASH > 0) A += (size_t)(n0 >> ASH) * M * K;

    v4f acc[MI][4];
#pragma unroll
    for (int i = 0; i < MI; i++)
#pragma unroll
        for (int j = 0; j < 4; j++) acc[i][j] = v4f{0.f, 0.f, 0.f, 0.f};

    // staging geometry: chunk = c*256 + tid -> row c*64 + (tid>>2), col (tid&3)*8
    const int sr = tid >> 2;
    const int sc = (tid & 3) * 8;

    // hoisted per-lane source pointers
    const unsigned short* aPtr[TM / 64];
#pragma unroll
    for (int c = 0; c < TM / 64; c++)
        aPtr[c] = (const unsigned short*)A + (size_t)(m0 + c * 64 + sr) * K + sc;

    const unsigned short* bPtr[2];
    int cb0 = 0, cb1 = 0, cto0 = 0, cto1 = 0, cfo0 = 0, cfo1 = 0;
    if constexpr (BL == B_T) {
#pragma unroll
        for (int c = 0; c < 2; c++)
            bPtr[c] = (const unsigned short*)Bw + (size_t)(n0 + c * 64 + sr) * K + sc;
    } else {
        {
            int n = n0 + sr;
            cb0 = n / 20480;
            int s = n - cb0 * 20480;
            cto0 = s / 20;
            cfo0 = s - cto0 * 20;
        }
        {
            int n = n0 + 64 + sr;
            cb1 = n / 20480;
            int s = n - cb1 * 20480;
            cto1 = s / 20;
            cfo1 = s - cto1 * 20;
        }
        if constexpr (HALO) {
            bPtr[0] = (const unsigned short*)Bact +
                      (((size_t)cb0 * 1026 + cto0) * 22 + cfo0) * 256 + sc;
            bPtr[1] = (const unsigned short*)Bact +
                      (((size_t)cb1 * 1026 + cto1) * 22 + cfo1) * 256 + sc;
        }
    }

    auto stageA = [&](int k0, int sel) {
#pragma unroll
        for (int c = 0; c < TM / 64; c++)
            gld16(aPtr[c] + k0, &As[sel][c * 2048 + wave * 512]);
    };
    auto stageB = [&](int k0, int sel) {
        if constexpr (BL == B_T) {
#pragma unroll
            for (int c = 0; c < 2; c++)
                gld16(bPtr[c] + k0, &Bs[sel][c * 2048 + wave * 512]);
        } else {
            int kg = k0 / ICN;             // kt*3+kf
            int ic0 = k0 - kg * ICN;       // channel base of this K-slice (no sc!)
            int kt = kg / 3, kf = kg - kt * 3;
            if constexpr (HALO) {          // conv3: bPtr already includes +sc
                gld16(bPtr[0] + (kt * 22 + kf) * 256 + ic0, &Bs[sel][wave * 512]);
                gld16(bPtr[1] + (kt * 22 + kf) * 256 + ic0, &Bs[sel][2048 + wave * 512]);
            } else {                       // conv2: clamp OOB to zero page (Bw)
                int ti0 = cto0 * STRIDE - 1 + kt, fi0 = cfo0 * STRIDE - 1 + kf;
                const unsigned short* s0 =
                    ((unsigned)ti0 < (unsigned)TIN && (unsigned)fi0 < (unsigned)FIN)
                    ? (const unsigned short*)Bact +
                      (((size_t)cb0 * TIN + ti0) * FIN + fi0) * ICN + ic0 + sc
                    : (const unsigned short*)Bw;
                gld16(s0, &Bs[sel][wave * 512]);
                int ti1 = cto1 * STRIDE - 1 + kt, fi1 = cfo1 * STRIDE - 1 + kf;
                const unsigned short* s1 =
                    ((unsigned)ti1 < (unsigned)TIN && (unsigned)fi1 < (unsigned)FIN)
                    ? (const unsigned short*)Bact +
                      (((size_t)cb1 * TIN + ti1) * FIN + fi1) * ICN + ic0 + sc
                    : (const unsigned short*)Bw;
                gld16(s1, &Bs[sel][2048 + wave * 512]);
            }
        }
    };
    auto compute = [&](int sel) {
        v8bf fa[MI], fb[4];
#pragma unroll
        for (int mi = 0; mi < MI; mi++)
            fa[mi] = *(const v8bf*)&As[sel][(wr * (TM / 2) + mi * 16 + lr) * 32 + lq * 8];
#pragma unroll
        for (int ni = 0; ni < 4; ni++)
            fb[ni] = *(const v8bf*)&Bs[sel][(wc * 64 + ni * 16 + lr) * 32 + lq * 8];
#pragma unroll
        for (int mi = 0; mi < MI; mi++)
#pragma unroll
            for (int ni = 0; ni < 4; ni++)
                acc[mi][ni] = __builtin_amdgcn_mfma_f32_16x16x32_bf16(
                    fa[mi], fb[ni], acc[mi][ni], 0, 0, 0);
    };

    // ---- 3-buffer counted-vmcnt pipeline. NT >= 8 for all instances.
    const int NT = KLEN / 32;
    stageA(kbase, 0);       stageB(kbase, 0);
    stageA(kbase + 32, 1);  stageB(kbase + 32, 1);
    stageA(kbase + 64, 2);  stageB(kbase + 64, 2);
    int sel = 0;
    for (int t = 0; t < NT - 2; ++t) {
        if constexpr (TM == 128)
            asm volatile("s_waitcnt vmcnt(8)" ::: "memory");
        else
            asm volatile("s_waitcnt vmcnt(6)" ::: "memory");
        __builtin_amdgcn_sched_barrier(0);
        __builtin_amdgcn_s_barrier();     // all waves' stage(t) landed
        compute(sel);
        __builtin_amdgcn_s_barrier();     // all reads of buf[sel] done
        if (t + 3 < NT) {
            int k0 = kbase + (t + 3) * 32;
            stageA(k0, sel);
            stageB(k0, sel);
        }
        sel = sel == 2 ? 0 : sel + 1;
    }
    // t = NT-2: two stages outstanding -> wait for the older one
    if constexpr (TM == 128)
        asm volatile("s_waitcnt vmcnt(4)" ::: "memory");
    else
        asm volatile("s_waitcnt vmcnt(3)" ::: "memory");
    __builtin_amdgcn_sched_barrier(0);
    __builtin_amdgcn_s_barrier();
    compute(sel);
    sel = sel == 2 ? 0 : sel + 1;
    // t = NT-1: last stage
    asm volatile("s_waitcnt vmcnt(0)" ::: "memory");
    __builtin_amdgcn_sched_barrier(0);
    __builtin_amdgcn_s_barrier();
    compute(sel);

    // ---- epilogue
#pragma unroll
    for (int mi = 0; mi < MI; mi++) {
#pragma unroll
        for (int ni = 0; ni < 4; ni++) {
#pragma unroll
            for (int reg = 0; reg < 4; reg++) {
                int row = m0 + wr * (TM / 2) + mi * 16 + lq * 4 + reg;
                int col = n0 + wc * 64 + ni * 16 + lr;
                float v = acc[mi][ni][reg];
                if constexpr (EPM == EP_CONV_CL) {
                    v += bias[row];
                    v = v > 0.f ? v : 0.f;
                    int b = col / 20480;
                    int s = col - b * 20480;
                    int t = s / 20, fo = s - t * 20;
                    Cb[(((size_t)b * 1026 + t + 1) * 22 + fo + 1) * 256 + row] =
                        __float2bfloat16(v);
                } else if constexpr (EPM == EP_CONV_T) {
                    v += bias[row];
                    v = v > 0.f ? v : 0.f;
                    int b = col / 20480;
                    int s = col - b * 20480;
                    int t = s / 20, fo = s - t * 20;
                    Cb[(size_t)(b * 1024 + t) * 10240 + row * 20 + fo] = __float2bfloat16(v);
                } else if constexpr (EPM == EP_ATOMIC) {
                    float add = (blockIdx.z == 0) ? bias[col] : 0.f;
                    atomicAdd(&C[(size_t)row * N + col], v + add);
                } else if constexpr (EPM == EP_KVR) {
                    int seg = col >> 9;     // 0=k,1=v,2=r (uniform per block)
                    if (seg == 2) v = 1.f / (1.f + __expf(-v));
                    C[(size_t)seg * M * 512 + (size_t)row * 512 + (col & 511)] = v;
                } else if constexpr (EPM == EP_ADD) {
                    C[(size_t)row * N + col] += v;
                } else if constexpr (EPM == EP_FFN) {
                    if (col < 2048) {       // wk branch: sqrelu -> bf16 kkb
                        float t = v > 0.f ? v : 0.f;
                        Cb[(size_t)row * 2048 + col] = __float2bfloat16(t * t);
                    } else {                // wr branch: sigmoid -> f32 rb
                        C[(size_t)row * 512 + (col - 2048)] = 1.f / (1.f + __expf(-v));
                    }
                } else if constexpr (EPM == EP_ADDMUL) {
                    size_t idx = (size_t)row * N + col;
                    C[idx] += mul[idx] * v;
                }
            }
        }
    }
}

// ---------------------------------------------------------------------------
// Prep: conv weight OIHW f32 -> bf16 [oc][(kt*3+kf)*IC + ic]
// ---------------------------------------------------------------------------
__global__ __launch_bounds__(256) void reorder_w_k(const float* __restrict__ in,
                                                   bf16* __restrict__ out,
                                                   int OC, int IC)
{
    int idx = blockIdx.x * 256 + threadIdx.x;
    if (idx >= OC * IC * 9) return;
    int oc = idx / (IC * 9);
    int r = idx - oc * (IC * 9);
    int g = r / IC;
    int ic = r - g * IC;
    out[idx] = __float2bfloat16(in[((size_t)oc * IC + ic) * 9 + g]);
}

// ---------------------------------------------------------------------------
// Prep: f32 [K][N] -> bf16 [N][K]; z: in stride K*N, out stride ozs
// ---------------------------------------------------------------------------
__global__ __launch_bounds__(256) void transpose_k(const float* __restrict__ in,
                                                   bf16* __restrict__ out,
                                                   int K, int N, size_t ozs)
{
    __shared__ float t[32][33];
    const float* pin = in + (size_t)blockIdx.z * K * N;
    bf16* pout = out + (size_t)blockIdx.z * ozs;
    int n0 = blockIdx.x * 32, k0 = blockIdx.y * 32;
    int tx = threadIdx.x & 31, ty = threadIdx.x >> 5;
#pragma unroll
    for (int i = 0; i < 32; i += 8)
        t[ty + i][tx] = pin[(size_t)(k0 + ty + i) * N + n0 + tx];
    __syncthreads();
#pragma unroll
    for (int i = 0; i < 32; i += 8)
        pout[(size_t)(n0 + ty + i) * K + k0 + tx] = __float2bfloat16(t[tx][ty + i]);
}

// ---------------------------------------------------------------------------
// conv1 for a 2-batch chunk: 1 input channel, direct, channel-last output.
// ---------------------------------------------------------------------------
__global__ __launch_bounds__(256) void conv1_k(
    const float* __restrict__ x, const float* __restrict__ w,
    const float* __restrict__ bias, bf16* __restrict__ out)
{
    __shared__ float ws_[128 * 9];
    __shared__ float bs_[128];
    const int tid = threadIdx.x;
    for (int i = tid; i < 128 * 9; i += 256) ws_[i] = w[i];
    if (tid < 128) bs_[tid] = bias[tid];
    __syncthreads();

    int idx = blockIdx.x * 256 + tid;  // 2*2048*40
    int f = idx % 40;
    int t = (idx / 40) & 2047;
    int b = idx / 81920;

    float xin[9];
#pragma unroll
    for (int kt = 0; kt < 3; kt++)
#pragma unroll
        for (int kf = 0; kf < 3; kf++) {
            int ti = 2 * t - 1 + kt, fi = 2 * f - 1 + kf;
            float v = 0.f;
            if ((unsigned)ti < 4096u && (unsigned)fi < 80u)
                v = x[(size_t)b * 327680 + (size_t)ti * 80 + fi];
            xin[kt * 3 + kf] = v;
        }
    unsigned short* outu = (unsigned short*)out + (size_t)idx * 128;
#pragma unroll
    for (int oc8 = 0; oc8 < 16; oc8++) {
        unsigned short pk[8];
#pragma unroll
        for (int j = 0; j < 8; j++) {
            int oc = oc8 * 8 + j;
            float a = bs_[oc];
#pragma unroll
            for (int q = 0; q < 9; q++) a += ws_[oc * 9 + q] * xin[q];
            a = a > 0.f ? a : 0.f;
            pk[j] = f2b(a);
        }
        *(u16x8*)&outu[oc8 * 8] = *(u16x8*)pk;
    }
}

// ---------------------------------------------------------------------------
// LayerNorm over D=512, one wave per row (4 rows / block)
// ---------------------------------------------------------------------------
__global__ __launch_bounds__(256) void ln_k(
    const float* __restrict__ in, float* __restrict__ out,
    const float* __restrict__ g, const float* __restrict__ b, int M)
{
    int wave = threadIdx.x >> 6;
    int lane = threadIdx.x & 63;
    int row = blockIdx.x * 4 + wave;
    if (row >= M) return;
    const float* p = in + (size_t)row * 512;
    float v[8], s = 0.f, sq = 0.f;
#pragma unroll
    for (int i = 0; i < 8; i++) {
        v[i] = p[lane + i * 64];
        s += v[i];
        sq += v[i] * v[i];
    }
#pragma unroll
    for (int o = 32; o > 0; o >>= 1) {
        s += __shfl_xor(s, o, 64);
        sq += __shfl_xor(sq, o, 64);
    }
    float mean = s * (1.f / 512.f);
    float var = sq * (1.f / 512.f) - mean * mean;
    float r = rsqrtf(var + 1e-5f);
    float* q = out + (size_t)row * 512;
#pragma unroll
    for (int i = 0; i < 8; i++) {
        int d = lane + i * 64;
        q[d] = (v[i] - mean) * r * g[d] + b[d];
    }
}

// ---------------------------------------------------------------------------
// Fused LN + token-shift mix -> bf16 operands. One wave per row; the wave
// also recomputes the predecessor row's LN (exact same f32 math). Lane owns
// 8 contiguous dims (16-B loads/stores). NOUT=3 (att) or 2 (ffn).
// ---------------------------------------------------------------------------
template <int NOUT>
__global__ __launch_bounds__(256) void lnmix_k(
    const float* __restrict__ hb, const float* __restrict__ g,
    const float* __restrict__ b, const float* __restrict__ mk,
    const float* __restrict__ mv, const float* __restrict__ mr,
    bf16* __restrict__ ok, bf16* __restrict__ ov, bf16* __restrict__ orr)
{
    int wave = threadIdx.x >> 6, lane = threadIdx.x & 63;
    int row = blockIdx.x * 4 + wave;     // 8192 rows
    int u = row & 1023;
    int d0 = lane * 8;
    const float* pc = hb + (size_t)row * 512 + d0;

    float vc[8], vp[8];
    *(float4*)&vc[0] = *(const float4*)pc;
    *(float4*)&vc[4] = *(const float4*)(pc + 4);
    float s = 0.f, sq = 0.f, sp = 0.f, sqp = 0.f;
#pragma unroll
    for (int i = 0; i < 8; i++) { s += vc[i]; sq += vc[i] * vc[i]; }
    if (u) {
        *(float4*)&vp[0] = *(const float4*)(pc - 512);
        *(float4*)&vp[4] = *(const float4*)(pc - 508);
#pragma unroll
        for (int i = 0; i < 8; i++) { sp += vp[i]; sqp += vp[i] * vp[i]; }
    } else {
#pragma unroll
        for (int i = 0; i < 8; i++) vp[i] = 0.f;
    }
#pragma unroll
    for (int o = 32; o > 0; o >>= 1) {
        s += __shfl_xor(s, o, 64);
        sq += __shfl_xor(sq, o, 64);
        sp += __shfl_xor(sp, o, 64);
        sqp += __shfl_xor(sqp, o, 64);
    }
    float mc = s * (1.f / 512.f);
    float rc = rsqrtf(sq * (1.f / 512.f) - mc * mc + 1e-5f);
    float mp = sp * (1.f / 512.f);
    float rp = rsqrtf(sqp * (1.f / 512.f) - mp * mp + 1e-5f);

    float gv[8], bv[8], xc[8], xp[8];
    *(float4*)&gv[0] = *(const float4*)(g + d0);
    *(float4*)&gv[4] = *(const float4*)(g + d0 + 4);
    *(float4*)&bv[0] = *(const float4*)(b + d0);
    *(float4*)&bv[4] = *(const float4*)(b + d0 + 4);
#pragma unroll
    for (int i = 0; i < 8; i++) {
        xc[i] = (vc[i] - mc) * rc * gv[i] + bv[i];
        xp[i] = u ? (vp[i] - mp) * rp * gv[i] + bv[i] : 0.f;
    }

    size_t ob = (size_t)row * 512 + d0;
    float a[8];
    unsigned short o16[8];
    *(float4*)&a[0] = *(const float4*)(mk + d0);
    *(float4*)&a[4] = *(const float4*)(mk + d0 + 4);
#pragma unroll
    for (int i = 0; i < 8; i++) o16[i] = f2b(xc[i] * a[i] + xp[i] * (1.f - a[i]));
    *(u16x8*)((unsigned short*)ok + ob) = *(u16x8*)o16;
    if constexpr (NOUT == 3) {
        *(float4*)&a[0] = *(const float4*)(mv + d0);
        *(float4*)&a[4] = *(const float4*)(mv + d0 + 4);
#pragma unroll
        for (int i = 0; i < 8; i++) o16[i] = f2b(xc[i] * a[i] + xp[i] * (1.f - a[i]));
        *(u16x8*)((unsigned short*)ov + ob) = *(u16x8*)o16;
    }
    *(float4*)&a[0] = *(const float4*)(mr + d0);
    *(float4*)&a[4] = *(const float4*)(mr + d0 + 4);
#pragma unroll
    for (int i = 0; i < 8; i++) o16[i] = f2b(xc[i] * a[i] + xp[i] * (1.f - a[i]));
    *(u16x8*)((unsigned short*)orr + ob) = *(u16x8*)o16;
}

// ---------------------------------------------------------------------------
// WKV chunked scan. State (aa,bb,pp): num = aa*e^pp, den = bb*e^pp.
// Chunk combine: S_out = e^{w*WT} * S_in + S_local (associative).
// Pass 1: per (chunk,b,d) local state from zero. idx = c*4096 + b*512 + d;
// planes [aa|bb|pp] stride WPLANE. Coalesced: consecutive threads = consec d.
// ---------------------------------------------------------------------------
__global__ __launch_bounds__(256) void wkv_loc_k(
    const float* __restrict__ kbuf, const float* __restrict__ vbuf,
    float* __restrict__ st, const float* __restrict__ decay)
{
    int idx = blockIdx.x * 256 + threadIdx.x;   // [c][b][d]
    int bd = idx & 4095;
    int c = idx >> 12;
    int d = bd & 511;
    int b = bd >> 9;
    float w = -__expf(decay[d]);
    float aa = 0.f, bb = 0.f, pp = -1e38f;
    size_t base = ((size_t)b * 1024 + c * WT) * 512 + d;
#pragma unroll
    for (int s = 0; s < WT; s++) {
        float kt = kbuf[base + (size_t)s * 512];
        float vt = vbuf[base + (size_t)s * 512];
        float ww2 = pp + w;
        float p2 = ww2 > kt ? ww2 : kt;
        float e1 = __expf(ww2 - p2), e2 = __expf(kt - p2);
        aa = e1 * aa + e2 * vt;
        bb = e1 * bb + e2;
        pp = p2;
    }
    st[idx] = aa;
    st[WPLANE + idx] = bb;
    st[2 * WPLANE + idx] = pp;
}

// ---------------------------------------------------------------------------
// Pass 2: per (b,d), fold WC chunk-local states sequentially; write EXCLUSIVE
// incoming state per chunk. Decay of a full chunk = e^{w*WT}.
// ---------------------------------------------------------------------------
__global__ __launch_bounds__(256) void wkv_comb_k(
    const float* __restrict__ loc, float* __restrict__ inc,
    const float* __restrict__ decay)
{
    int bd = blockIdx.x * 256 + threadIdx.x;  // 4096
    int d = bd & 511;
    float wT = -__expf(decay[d]) * (float)WT;
    float aa = 0.f, bb = 0.f, pp = -1e38f;
    for (int c = 0; c < WC; c++) {
        int i = c * 4096 + bd;
        inc[i] = aa;
        inc[WPLANE + i] = bb;
        inc[2 * WPLANE + i] = pp;
        float la = loc[i], lb = loc[WPLANE + i], lp = loc[2 * WPLANE + i];
        float pd = pp + wT;
        float p2 = pd > lp ? pd : lp;
        float e1 = __expf(pd - p2), e2 = __expf(lp - p2);
        aa = e1 * aa + e2 * la;
        bb = e1 * bb + e2 * lb;
        pp = p2;
    }
}

// ---------------------------------------------------------------------------
// Pass 3: per (chunk,b,d), replay chunk from incoming state with the exact
// original per-step math. out = bf16(r * wkv).
// ---------------------------------------------------------------------------
__global__ __launch_bounds__(256) void wkv_out_k(
    const float* __restrict__ kbuf, const float* __restrict__ vbuf,
    const float* __restrict__ rbuf, bf16* __restrict__ outbuf,
    const float* __restrict__ inc,
    const float* __restrict__ decay, const float* __restrict__ first)
{
    int idx = blockIdx.x * 256 + threadIdx.x;
    int bd = idx & 4095;
    int c = idx >> 12;
    int d = bd & 511;
    int b = bd >> 9;
    float w = -__expf(decay[d]);
    float u = first[d];
    float aa = inc[idx], bb = inc[WPLANE + idx], pp = inc[2 * WPLANE + idx];
    size_t base = ((size_t)b * 1024 + c * WT) * 512 + d;
#pragma unroll
    for (int s = 0; s < WT; s++) {
        float kt = kbuf[base + (size_t)s * 512];
        float vt = vbuf[base + (size_t)s * 512];
        float rt = rbuf[base + (size_t)s * 512];
        float ww = u + kt;
        float p = pp > ww ? pp : ww;
        float e1 = __expf(pp - p), e2 = __expf(ww - p);
        float out = (e1 * aa + e2 * vt) / (e1 * bb + e2);
        outbuf[base + (size_t)s * 512] = __float2bfloat16(rt * out);
        float ww2 = pp + w;
        float p2 = ww2 > kt ? ww2 : kt;
        e1 = __expf(ww2 - p2);
        e2 = __expf(kt - p2);
        aa = e1 * aa + e2 * vt;
        bb = e1 * bb + e2;
        pp = p2;
    }
}

__global__ void olens_k(const int* __restrict__ x_len, float* __restrict__ out)
{
    int i = threadIdx.x;
    if (i < 8) {
        int l1 = (x_len[i] - 1) / 2 + 1;
        int ol = (l1 - 1) / 2 + 1;
        out[i] = (float)ol;
    }
}

// ---------------------------------------------------------------------------
extern "C" void kernel_launch(void* const* d_in, const int* in_sizes, int n_in,
                              void* d_out, int out_size, void* d_ws, size_t ws_size,
                              hipStream_t stream)
{
    (void)in_sizes; (void)n_in; (void)out_size; (void)ws_size;
    const float* x         = (const float*)d_in[0];
    const int*   x_len     = (const int*)d_in[1];
    const float* conv1_w   = (const float*)d_in[2];
    const float* conv1_b   = (const float*)d_in[3];
    const float* conv2_w   = (const float*)d_in[4];
    const float* conv2_b   = (const float*)d_in[5];
    const float* conv3_w   = (const float*)d_in[6];
    const float* conv3_b   = (const float*)d_in[7];
    const float* embed_w   = (const float*)d_in[8];
    const float* embed_b   = (const float*)d_in[9];
    const float* embed_ln_g= (const float*)d_in[10];
    const float* embed_ln_b= (const float*)d_in[11];
    const float* ln_att_g  = (const float*)d_in[12];
    const float* ln_att_b  = (const float*)d_in[13];
    const float* att_decay = (const float*)d_in[14];
    const float* att_first = (const float*)d_in[15];
    const float* att_mix_k = (const float*)d_in[16];
    const float* att_mix_v = (const float*)d_in[17];
    const float* att_mix_r = (const float*)d_in[18];
    const float* att_wk    = (const float*)d_in[19];
    const float* att_wv    = (const float*)d_in[20];
    const float* att_wr    = (const float*)d_in[21];
    const float* att_wo    = (const float*)d_in[22];
    const float* ln_ffn_g  = (const float*)d_in[23];
    const float* ln_ffn_b  = (const float*)d_in[24];
    const float* ffn_mix_k = (const float*)d_in[25];
    const float* ffn_mix_r = (const float*)d_in[26];
    const float* ffn_wk    = (const float*)d_in[27];
    const float* ffn_wv    = (const float*)d_in[28];
    const float* ffn_wr    = (const float*)d_in[29];
    const float* final_ln_g= (const float*)d_in[30];
    const float* final_ln_b= (const float*)d_in[31];

    // ---- workspace layout (MiB offsets, ~183 MiB) ----
    // 0..16 h | 16..32 xn (frontend) / wkv states (RWKV loop) | 32..40 rwkvb
    // 40..64 xkvr (xf aliases 40..56) | 64..112 kvrb | 112..144 kkb
    // conv overlay: c1b 40..80 | c2b(halo) 80..102.1 | zpg 103..103.004 |
    //               c3b 104..144
    // weights: attT 144..150 | attTo 150..152 | ffnT 152..162 | ffnTv 162..170
    //          embT 170..180 | c2wb 180..180.6 | c3wb 180.6..182.9
    char* wsb = (char*)d_ws;
    float* h     = (float*)(wsb);
    float* xn    = (float*)(wsb + (16LL << 20));
    float* sloc  = (float*)(wsb + (16LL << 20));   // [3][WC][4096] f32 (3MB)
    float* sinc  = (float*)(wsb + (20LL << 20));   // [3][WC][4096] f32 (3MB)
    bf16*  rwkvb = (bf16*) (wsb + (32LL << 20));
    bf16*  xkvr  = (bf16*) (wsb + (40LL << 20));   // [3][8192][512] bf16
    bf16*  xf    = xkvr;                           // [2][8192][512] bf16 (ffn)
    float* kvrb  = (float*)(wsb + (64LL << 20));   // [3][8192][512] f32
    bf16*  kkb   = (bf16*) (wsb + (112LL << 20));  // [8192][2048] bf16
    bf16*  c1b   = (bf16*) (wsb + (40LL << 20));   // (2,2048,40,128)
    bf16*  c2b   = (bf16*) (wsb + (80LL << 20));   // (2,1026,22,256) halo
    bf16*  zpg   = (bf16*) (wsb + (103LL << 20));  // 4KB zero page (conv2 OOB)
    bf16*  c3b   = (bf16*) (wsb + (104LL << 20));  // (2048,10240)
    bf16*  attT  = (bf16*) (wsb + (144LL << 20));  // 4 x [1536][512] (k,v,r)
    bf16*  attTo = (bf16*) (wsb + (150LL << 20));  // 4 x [512][512]  (wo)
    bf16*  ffnT  = (bf16*) (wsb + (152LL << 20));  // 4 x [2560][512] (wk|wr)
    bf16*  ffnTv = (bf16*) (wsb + (162LL << 20));  // 4 x [512][2048]
    bf16*  embT  = (bf16*) (wsb + (170LL << 20));  // [512][10240]
    bf16*  c2wb  = (bf16*) (wsb + (180LL << 20));  // 256 x 1152
    bf16*  c3wb  = (bf16*) (wsb + (180LL << 20) + 589824);  // 512 x 2304

    const size_t MD = 8192LL * 512;

    // ---- weight prep: packed transposed bf16
    transpose_k<<<dim3(16, 16, 4), 256, 0, stream>>>(att_wk, attT, 512, 512, 786432);
    transpose_k<<<dim3(16, 16, 4), 256, 0, stream>>>(att_wv, attT + 262144, 512, 512, 786432);
    transpose_k<<<dim3(16, 16, 4), 256, 0, stream>>>(att_wr, attT + 524288, 512, 512, 786432);
    transpose_k<<<dim3(16, 16, 4), 256, 0, stream>>>(att_wo, attTo, 512, 512, 262144);
    transpose_k<<<dim3(64, 16, 4), 256, 0, stream>>>(ffn_wk, ffnT, 512, 2048, 1310720);
    transpose_k<<<dim3(16, 16, 4), 256, 0, stream>>>(ffn_wr, ffnT + 1048576, 512, 512, 1310720);
    transpose_k<<<dim3(16, 64, 4), 256, 0, stream>>>(ffn_wv, ffnTv, 2048, 512, 1048576);
    transpose_k<<<dim3(16, 320, 1), 256, 0, stream>>>(embed_w, embT, 10240, 512, 0);
    reorder_w_k<<<1152, 256, 0, stream>>>(conv2_w, c2wb, 256, 128);
    reorder_w_k<<<4608, 256, 0, stream>>>(conv3_w, c3wb, 512, 256);
    hipMemsetAsync(xn, 0, 16LL << 20, stream);
    hipMemsetAsync(c2b, 0, 2LL * 1026 * 22 * 256 * 2, stream);
    hipMemsetAsync(zpg, 0, 4096, stream);

    // ---- conv frontend + embed (split-K x4, atomic), 2 batches per chunk
    for (int chunk = 0; chunk < 4; chunk++) {
        int b0 = chunk * 2;
        conv1_k<<<640, 256, 0, stream>>>(x + (size_t)b0 * 327680, conv1_w, conv1_b, c1b);
        gemm_k<128, B_CONV, EP_CONV_CL, 0, 2048, 40, 2, 128, 0><<<dim3(320, 2), 256, 0, stream>>>(
            c2wb, zpg, c1b, nullptr, c2b, conv2_b, nullptr, 256, 40960, 1152, 1152);
        gemm_k<128, B_CONV, EP_CONV_T, 0, 1024, 20, 1, 256, 1><<<dim3(320, 4), 256, 0, stream>>>(
            c3wb, nullptr, c2b, nullptr, c3b, conv3_b, nullptr, 512, 40960, 2304, 2304);
        gemm_k<64, B_T, EP_ATOMIC, 0, 0, 0, 0, 0, 0><<<dim3(4, 32, 4), 256, 0, stream>>>(
            c3b, embT, nullptr, xn + (size_t)b0 * 1024 * 512, nullptr, embed_b, nullptr,
            2048, 512, 10240, 2560);
    }
    ln_k<<<2048, 256, 0, stream>>>(xn, h, embed_ln_g, embed_ln_b, 8192);

    // ---- 4 RWKV blocks
    for (int i = 0; i < 4; i++) {
        // time mixing (LN fused into mix)
        lnmix_k<3><<<2048, 256, 0, stream>>>(h, ln_att_g + i * 512, ln_att_b + i * 512,
                                             att_mix_k + i * 512, att_mix_v + i * 512,
                                             att_mix_r + i * 512,
                                             xkvr, xkvr + MD, xkvr + 2 * MD);
        gemm_k<64, B_T, EP_KVR, 9, 0, 0, 0, 0, 0><<<dim3(12, 128), 256, 0, stream>>>(
            xkvr, attT + (size_t)i * 786432, nullptr, kvrb, nullptr, nullptr, nullptr,
            8192, 1536, 512, 512);
        wkv_loc_k<<<1024, 256, 0, stream>>>(kvrb, kvrb + MD, sloc, att_decay + i * 512);
        wkv_comb_k<<<16, 256, 0, stream>>>(sloc, sinc, att_decay + i * 512);
        wkv_out_k<<<1024, 256, 0, stream>>>(kvrb, kvrb + MD, kvrb + 2 * MD, rwkvb,
                                            sinc, att_decay + i * 512, att_first + i * 512);
        gemm_k<64, B_T, EP_ADD, 0, 0, 0, 0, 0, 0><<<dim3(4, 128), 256, 0, stream>>>(
            rwkvb, attTo + (size_t)i * 262144, nullptr, h, nullptr, nullptr, nullptr,
            8192, 512, 512, 512);
        // channel mixing (LN fused into mix)
        lnmix_k<2><<<2048, 256, 0, stream>>>(h, ln_ffn_g + i * 512, ln_ffn_b + i * 512,
                                             ffn_mix_k + i * 512, nullptr,
                                             ffn_mix_r + i * 512,
                                             xf, nullptr, xf + MD);
        gemm_k<64, B_T, EP_FFN, 11, 0, 0, 0, 0, 0><<<dim3(20, 128), 256, 0, stream>>>(
            xf, ffnT + (size_t)i * 1310720, nullptr, kvrb + 2 * MD, kkb, nullptr, nullptr,
            8192, 2560, 512, 512);
        gemm_k<64, B_T, EP_ADDMUL, 0, 0, 0, 0, 0, 0><<<dim3(4, 128), 256, 0, stream>>>(
            kkb, ffnTv + (size_t)i * 1048576, nullptr, h, nullptr, nullptr, kvrb + 2 * MD,
            8192, 512, 2048, 2048);
    }

    // ---- final LN straight into d_out, then olens
    ln_k<<<2048, 256, 0, stream>>>(h, (float*)d_out, final_ln_g, final_ln_b, 8192);
    olens_k<<<1, 64, 0, stream>>>(x_len, (float*)d_out + 4194304);
}

// Round 7
// 1936.219 us; speedup vs baseline: 1.4363x; 1.0249x over previous
//
#include <hip/hip_runtime.h>
#include <hip/hip_bf16.h>

typedef __hip_bfloat16 bf16;
typedef __bf16 v8bf __attribute__((ext_vector_type(8)));
typedef float v4f __attribute__((ext_vector_type(4)));
typedef unsigned short u16x8 __attribute__((ext_vector_type(8)));

// ---------------------------------------------------------------------------
//   x: (8,4096,80) -> conv1(1->128,s2) -> (8,2048,40,128)   [channel-last]
//   -> conv2(128->256,s2) -> halo (8,1026,22,256)           [channel-last+halo]
//   -> conv3(256->512,s1) -> tokens (8,1024,10240)          [token-major]
//   -> embed GEMM (split-K) -> 4 RWKV blocks -> final LN
// GEMM core: bf16 MFMA 16x16x32, TM x 128 tile, BK=32.
// Staging: __builtin_amdgcn_global_load_lds width=16 into LINEAR (unpadded)
// [rows][32] bf16 LDS tiles, TRIPLE-BUFFERED counted-vmcnt pipeline (T3+T4).
// T2 (r5/r6): 64B rows made ds_read_b128 8-way bank-conflicted (14% of
// cycles). Fix per rule #21 (both-sides-or-neither): LDS stays linear; the
// GLOBAL source chunk is permuted per lane (scS = ((tid&3)^((tid>>3)&3))*8)
// and the fragment read applies the same XOR (slot = lq ^ ((lr>>1)&3)) ->
// 16 rows spread over 8 bank-groups (2-way, ~free). Coalescing unchanged
// (row-quad still covers the same 64B run, order permuted).
// WKV: 3-pass chunked associative scan (C=64 chunks of T=16).
// ---------------------------------------------------------------------------

constexpr int B_T = 0, B_CONV = 1;
constexpr int EP_CONV_CL = 0, EP_CONV_T = 1, EP_ATOMIC = 2, EP_KVR = 3,
              EP_ADD = 4, EP_FFN = 5, EP_ADDMUL = 6;

constexpr int WC = 64;          // wkv chunks per sequence
constexpr int WT = 1024 / WC;   // 16 steps per chunk
constexpr int WPLANE = WC * 4096;  // 262144 states per plane

static __device__ __forceinline__ unsigned short f2b(float f) {
    return __builtin_bit_cast(unsigned short, __float2bfloat16(f));
}

// global -> LDS async copy, 16B per lane. LDS dest must be the wave-uniform
// base; HW writes lane i at base + i*16.
static __device__ __forceinline__ void gld16(const unsigned short* g,
                                             unsigned short* l) {
    __builtin_amdgcn_global_load_lds(
        (__attribute__((address_space(1))) void*)g,
        (__attribute__((address_space(3))) void*)l, 16, 0, 0);
}

// ---------------------------------------------------------------------------
// MFMA GEMM: C[M,N] = A[M,K] * B[K,N]. A bf16 [M][K]; B bf16 [N][K] (B_T) or
// channel-last im2col gather (B_CONV; HALO=1 -> unconditional loads from the
// zero-padded (b,1026,22,256) buffer; HALO=0 -> OOB lanes read zero page Bw).
// ASH>0: A += (n0>>ASH)*M*K (fused ops).
// Loads per wave per stage: L = TM/64 + 2 (TM=128 -> 4, TM=64 -> 3).
// Steady-state wait: vmcnt(2L); epilogue peels vmcnt(L), vmcnt(0).
// ---------------------------------------------------------------------------
template <int TM, int BL, int EPM, int ASH, int TIN, int FIN, int STRIDE,
          int ICN, int HALO>
__global__ __launch_bounds__(256) void gemm_k(
    const bf16* __restrict__ A, const bf16* __restrict__ Bw,
    const bf16* __restrict__ Bact,
    float* __restrict__ C, bf16* __restrict__ Cb,
    const float* __restrict__ bias, const float* __restrict__ mul,
    int M, int N, int K, int KLEN)
{
    constexpr int MI = TM / 32;
    __shared__ __align__(16) unsigned short As[3][TM * 32];
    __shared__ __align__(16) unsigned short Bs[3][128 * 32];
    const int tid = threadIdx.x;
    const int n0 = blockIdx.x * 128;
    const int m0 = blockIdx.y * TM;
    const int kbase = blockIdx.z * KLEN;
    const int wave = tid >> 6, lane = tid & 63;
    const int wr = wave >> 1, wc = wave & 1;
    const int lq = lane >> 4, lr = lane & 15;

    if constexpr (ASH > 0) A += (size_t)(n0 >> ASH) * M * K;

    v4f acc[MI][4];
#pragma unroll
    for (int i = 0; i < MI; i++)
#pragma unroll
        for (int j = 0; j < 4; j++) acc[i][j] = v4f{0.f, 0.f, 0.f, 0.f};

    // staging geometry: chunk = c*256 + tid -> row c*64 + (tid>>2).
    // T2 swizzle: lane fetches global 16B-chunk (tid&3)^((tid>>3)&3) of its
    // row (XOR of row bits 1:2 into the chunk index); reads undo it.
    const int sr = tid >> 2;
    const int scS = ((tid & 3) ^ ((tid >> 3) & 3)) * 8;
    // read-side XOR (fragment row = 16*q + lr -> (row>>1)&3 = (lr>>1)&3)
    const int lsw = (lr >> 1) & 3;

    // hoisted per-lane source pointers
    const unsigned short* aPtr[TM / 64];
#pragma unroll
    for (int c = 0; c < TM / 64; c++)
        aPtr[c] = (const unsigned short*)A + (size_t)(m0 + c * 64 + sr) * K + scS;

    const unsigned short* bPtr[2];
    int cb0 = 0, cb1 = 0, cto0 = 0, cto1 = 0, cfo0 = 0, cfo1 = 0;
    if constexpr (BL == B_T) {
#pragma unroll
        for (int c = 0; c < 2; c++)
            bPtr[c] = (const unsigned short*)Bw + (size_t)(n0 + c * 64 + sr) * K + scS;
    } else {
        {
            int n = n0 + sr;
            cb0 = n / 20480;
            int s = n - cb0 * 20480;
            cto0 = s / 20;
            cfo0 = s - cto0 * 20;
        }
        {
            int n = n0 + 64 + sr;
            cb1 = n / 20480;
            int s = n - cb1 * 20480;
            cto1 = s / 20;
            cfo1 = s - cto1 * 20;
        }
        if constexpr (HALO) {
            bPtr[0] = (const unsigned short*)Bact +
                      (((size_t)cb0 * 1026 + cto0) * 22 + cfo0) * 256 + scS;
            bPtr[1] = (const unsigned short*)Bact +
                      (((size_t)cb1 * 1026 + cto1) * 22 + cfo1) * 256 + scS;
        }
    }

    auto stageA = [&](int k0, int sel) {
#pragma unroll
        for (int c = 0; c < TM / 64; c++)
            gld16(aPtr[c] + k0, &As[sel][c * 2048 + wave * 512]);
    };
    auto stageB = [&](int k0, int sel) {
        if constexpr (BL == B_T) {
#pragma unroll
            for (int c = 0; c < 2; c++)
                gld16(bPtr[c] + k0, &Bs[sel][c * 2048 + wave * 512]);
        } else {
            int kg = k0 / ICN;             // kt*3+kf
            int ic0 = k0 - kg * ICN;       // channel base of this K-slice
            int kt = kg / 3, kf = kg - kt * 3;
            if constexpr (HALO) {          // conv3: bPtr already includes +scS
                gld16(bPtr[0] + (kt * 22 + kf) * 256 + ic0, &Bs[sel][wave * 512]);
                gld16(bPtr[1] + (kt * 22 + kf) * 256 + ic0, &Bs[sel][2048 + wave * 512]);
            } else {                       // conv2: clamp OOB to zero page (Bw)
                int ti0 = cto0 * STRIDE - 1 + kt, fi0 = cfo0 * STRIDE - 1 + kf;
                const unsigned short* s0 =
                    ((unsigned)ti0 < (unsigned)TIN && (unsigned)fi0 < (unsigned)FIN)
                    ? (const unsigned short*)Bact +
                      (((size_t)cb0 * TIN + ti0) * FIN + fi0) * ICN + ic0 + scS
                    : (const unsigned short*)Bw;
                gld16(s0, &Bs[sel][wave * 512]);
                int ti1 = cto1 * STRIDE - 1 + kt, fi1 = cfo1 * STRIDE - 1 + kf;
                const unsigned short* s1 =
                    ((unsigned)ti1 < (unsigned)TIN && (unsigned)fi1 < (unsigned)FIN)
                    ? (const unsigned short*)Bact +
                      (((size_t)cb1 * TIN + ti1) * FIN + fi1) * ICN + ic0 + scS
                    : (const unsigned short*)Bw;
                gld16(s1, &Bs[sel][2048 + wave * 512]);
            }
        }
    };
    auto compute = [&](int sel) {
        v8bf fa[MI], fb[4];
#pragma unroll
        for (int mi = 0; mi < MI; mi++)
            fa[mi] = *(const v8bf*)&As[sel][(wr * (TM / 2) + mi * 16 + lr) * 32 +
                                            ((lq ^ lsw) * 8)];
#pragma unroll
        for (int ni = 0; ni < 4; ni++)
            fb[ni] = *(const v8bf*)&Bs[sel][(wc * 64 + ni * 16 + lr) * 32 +
                                            ((lq ^ lsw) * 8)];
#pragma unroll
        for (int mi = 0; mi < MI; mi++)
#pragma unroll
            for (int ni = 0; ni < 4; ni++)
                acc[mi][ni] = __builtin_amdgcn_mfma_f32_16x16x32_bf16(
                    fa[mi], fb[ni], acc[mi][ni], 0, 0, 0);
    };

    // ---- 3-buffer counted-vmcnt pipeline. NT >= 8 for all instances.
    const int NT = KLEN / 32;
    stageA(kbase, 0);       stageB(kbase, 0);
    stageA(kbase + 32, 1);  stageB(kbase + 32, 1);
    stageA(kbase + 64, 2);  stageB(kbase + 64, 2);
    int sel = 0;
    for (int t = 0; t < NT - 2; ++t) {
        if constexpr (TM == 128)
            asm volatile("s_waitcnt vmcnt(8)" ::: "memory");
        else
            asm volatile("s_waitcnt vmcnt(6)" ::: "memory");
        __builtin_amdgcn_sched_barrier(0);
        __builtin_amdgcn_s_barrier();     // all waves' stage(t) landed
        compute(sel);
        __builtin_amdgcn_s_barrier();     // all reads of buf[sel] done
        if (t + 3 < NT) {
            int k0 = kbase + (t + 3) * 32;
            stageA(k0, sel);
            stageB(k0, sel);
        }
        sel = sel == 2 ? 0 : sel + 1;
    }
    // t = NT-2: two stages outstanding -> wait for the older one
    if constexpr (TM == 128)
        asm volatile("s_waitcnt vmcnt(4)" ::: "memory");
    else
        asm volatile("s_waitcnt vmcnt(3)" ::: "memory");
    __builtin_amdgcn_sched_barrier(0);
    __builtin_amdgcn_s_barrier();
    compute(sel);
    sel = sel == 2 ? 0 : sel + 1;
    // t = NT-1: last stage
    asm volatile("s_waitcnt vmcnt(0)" ::: "memory");
    __builtin_amdgcn_sched_barrier(0);
    __builtin_amdgcn_s_barrier();
    compute(sel);

    // ---- epilogue
#pragma unroll
    for (int mi = 0; mi < MI; mi++) {
#pragma unroll
        for (int ni = 0; ni < 4; ni++) {
#pragma unroll
            for (int reg = 0; reg < 4; reg++) {
                int row = m0 + wr * (TM / 2) + mi * 16 + lq * 4 + reg;
                int col = n0 + wc * 64 + ni * 16 + lr;
                float v = acc[mi][ni][reg];
                if constexpr (EPM == EP_CONV_CL) {
                    v += bias[row];
                    v = v > 0.f ? v : 0.f;
                    int b = col / 20480;
                    int s = col - b * 20480;
                    int t = s / 20, fo = s - t * 20;
                    Cb[(((size_t)b * 1026 + t + 1) * 22 + fo + 1) * 256 + row] =
                        __float2bfloat16(v);
                } else if constexpr (EPM == EP_CONV_T) {
                    v += bias[row];
                    v = v > 0.f ? v : 0.f;
                    int b = col / 20480;
                    int s = col - b * 20480;
                    int t = s / 20, fo = s - t * 20;
                    Cb[(size_t)(b * 1024 + t) * 10240 + row * 20 + fo] = __float2bfloat16(v);
                } else if constexpr (EPM == EP_ATOMIC) {
                    float add = (blockIdx.z == 0) ? bias[col] : 0.f;
                    atomicAdd(&C[(size_t)row * N + col], v + add);
                } else if constexpr (EPM == EP_KVR) {
                    int seg = col >> 9;     // 0=k,1=v,2=r (uniform per block)
                    if (seg == 2) v = 1.f / (1.f + __expf(-v));
                    C[(size_t)seg * M * 512 + (size_t)row * 512 + (col & 511)] = v;
                } else if constexpr (EPM == EP_ADD) {
                    C[(size_t)row * N + col] += v;
                } else if constexpr (EPM == EP_FFN) {
                    if (col < 2048) {       // wk branch: sqrelu -> bf16 kkb
                        float t = v > 0.f ? v : 0.f;
                        Cb[(size_t)row * 2048 + col] = __float2bfloat16(t * t);
                    } else {                // wr branch: sigmoid -> f32 rb
                        C[(size_t)row * 512 + (col - 2048)] = 1.f / (1.f + __expf(-v));
                    }
                } else if constexpr (EPM == EP_ADDMUL) {
                    size_t idx = (size_t)row * N + col;
                    C[idx] += mul[idx] * v;
                }
            }
        }
    }
}

// ---------------------------------------------------------------------------
// Prep: conv weight OIHW f32 -> bf16 [oc][(kt*3+kf)*IC + ic]
// ---------------------------------------------------------------------------
__global__ __launch_bounds__(256) void reorder_w_k(const float* __restrict__ in,
                                                   bf16* __restrict__ out,
                                                   int OC, int IC)
{
    int idx = blockIdx.x * 256 + threadIdx.x;
    if (idx >= OC * IC * 9) return;
    int oc = idx / (IC * 9);
    int r = idx - oc * (IC * 9);
    int g = r / IC;
    int ic = r - g * IC;
    out[idx] = __float2bfloat16(in[((size_t)oc * IC + ic) * 9 + g]);
}

// ---------------------------------------------------------------------------
// Prep: f32 [K][N] -> bf16 [N][K]; z: in stride K*N, out stride ozs
// ---------------------------------------------------------------------------
__global__ __launch_bounds__(256) void transpose_k(const float* __restrict__ in,
                                                   bf16* __restrict__ out,
                                                   int K, int N, size_t ozs)
{
    __shared__ float t[32][33];
    const float* pin = in + (size_t)blockIdx.z * K * N;
    bf16* pout = out + (size_t)blockIdx.z * ozs;
    int n0 = blockIdx.x * 32, k0 = blockIdx.y * 32;
    int tx = threadIdx.x & 31, ty = threadIdx.x >> 5;
#pragma unroll
    for (int i = 0; i < 32; i += 8)
        t[ty + i][tx] = pin[(size_t)(k0 + ty + i) * N + n0 + tx];
    __syncthreads();
#pragma unroll
    for (int i = 0; i < 32; i += 8)
        pout[(size_t)(n0 + ty + i) * K + k0 + tx] = __float2bfloat16(t[tx][ty + i]);
}

// ---------------------------------------------------------------------------
// conv1 for a 2-batch chunk: 1 input channel, direct, channel-last output.
// ---------------------------------------------------------------------------
__global__ __launch_bounds__(256) void conv1_k(
    const float* __restrict__ x, const float* __restrict__ w,
    const float* __restrict__ bias, bf16* __restrict__ out)
{
    __shared__ float ws_[128 * 9];
    __shared__ float bs_[128];
    const int tid = threadIdx.x;
    for (int i = tid; i < 128 * 9; i += 256) ws_[i] = w[i];
    if (tid < 128) bs_[tid] = bias[tid];
    __syncthreads();

    int idx = blockIdx.x * 256 + tid;  // 2*2048*40
    int f = idx % 40;
    int t = (idx / 40) & 2047;
    int b = idx / 81920;

    float xin[9];
#pragma unroll
    for (int kt = 0; kt < 3; kt++)
#pragma unroll
        for (int kf = 0; kf < 3; kf++) {
            int ti = 2 * t - 1 + kt, fi = 2 * f - 1 + kf;
            float v = 0.f;
            if ((unsigned)ti < 4096u && (unsigned)fi < 80u)
                v = x[(size_t)b * 327680 + (size_t)ti * 80 + fi];
            xin[kt * 3 + kf] = v;
        }
    unsigned short* outu = (unsigned short*)out + (size_t)idx * 128;
#pragma unroll
    for (int oc8 = 0; oc8 < 16; oc8++) {
        unsigned short pk[8];
#pragma unroll
        for (int j = 0; j < 8; j++) {
            int oc = oc8 * 8 + j;
            float a = bs_[oc];
#pragma unroll
            for (int q = 0; q < 9; q++) a += ws_[oc * 9 + q] * xin[q];
            a = a > 0.f ? a : 0.f;
            pk[j] = f2b(a);
        }
        *(u16x8*)&outu[oc8 * 8] = *(u16x8*)pk;
    }
}

// ---------------------------------------------------------------------------
// LayerNorm over D=512, one wave per row (4 rows / block)
// ---------------------------------------------------------------------------
__global__ __launch_bounds__(256) void ln_k(
    const float* __restrict__ in, float* __restrict__ out,
    const float* __restrict__ g, const float* __restrict__ b, int M)
{
    int wave = threadIdx.x >> 6;
    int lane = threadIdx.x & 63;
    int row = blockIdx.x * 4 + wave;
    if (row >= M) return;
    const float* p = in + (size_t)row * 512;
    float v[8], s = 0.f, sq = 0.f;
#pragma unroll
    for (int i = 0; i < 8; i++) {
        v[i] = p[lane + i * 64];
        s += v[i];
        sq += v[i] * v[i];
    }
#pragma unroll
    for (int o = 32; o > 0; o >>= 1) {
        s += __shfl_xor(s, o, 64);
        sq += __shfl_xor(sq, o, 64);
    }
    float mean = s * (1.f / 512.f);
    float var = sq * (1.f / 512.f) - mean * mean;
    float r = rsqrtf(var + 1e-5f);
    float* q = out + (size_t)row * 512;
#pragma unroll
    for (int i = 0; i < 8; i++) {
        int d = lane + i * 64;
        q[d] = (v[i] - mean) * r * g[d] + b[d];
    }
}

// ---------------------------------------------------------------------------
// Fused LN + token-shift mix -> bf16 operands. One wave per row; the wave
// also recomputes the predecessor row's LN (exact same f32 math). Lane owns
// 8 contiguous dims (16-B loads/stores). NOUT=3 (att) or 2 (ffn).
// ---------------------------------------------------------------------------
template <int NOUT>
__global__ __launch_bounds__(256) void lnmix_k(
    const float* __restrict__ hb, const float* __restrict__ g,
    const float* __restrict__ b, const float* __restrict__ mk,
    const float* __restrict__ mv, const float* __restrict__ mr,
    bf16* __restrict__ ok, bf16* __restrict__ ov, bf16* __restrict__ orr)
{
    int wave = threadIdx.x >> 6, lane = threadIdx.x & 63;
    int row = blockIdx.x * 4 + wave;     // 8192 rows
    int u = row & 1023;
    int d0 = lane * 8;
    const float* pc = hb + (size_t)row * 512 + d0;

    float vc[8], vp[8];
    *(float4*)&vc[0] = *(const float4*)pc;
    *(float4*)&vc[4] = *(const float4*)(pc + 4);
    float s = 0.f, sq = 0.f, sp = 0.f, sqp = 0.f;
#pragma unroll
    for (int i = 0; i < 8; i++) { s += vc[i]; sq += vc[i] * vc[i]; }
    if (u) {
        *(float4*)&vp[0] = *(const float4*)(pc - 512);
        *(float4*)&vp[4] = *(const float4*)(pc - 508);
#pragma unroll
        for (int i = 0; i < 8; i++) { sp += vp[i]; sqp += vp[i] * vp[i]; }
    } else {
#pragma unroll
        for (int i = 0; i < 8; i++) vp[i] = 0.f;
    }
#pragma unroll
    for (int o = 32; o > 0; o >>= 1) {
        s += __shfl_xor(s, o, 64);
        sq += __shfl_xor(sq, o, 64);
        sp += __shfl_xor(sp, o, 64);
        sqp += __shfl_xor(sqp, o, 64);
    }
    float mc = s * (1.f / 512.f);
    float rc = rsqrtf(sq * (1.f / 512.f) - mc * mc + 1e-5f);
    float mp = sp * (1.f / 512.f);
    float rp = rsqrtf(sqp * (1.f / 512.f) - mp * mp + 1e-5f);

    float gv[8], bv[8], xc[8], xp[8];
    *(float4*)&gv[0] = *(const float4*)(g + d0);
    *(float4*)&gv[4] = *(const float4*)(g + d0 + 4);
    *(float4*)&bv[0] = *(const float4*)(b + d0);
    *(float4*)&bv[4] = *(const float4*)(b + d0 + 4);
#pragma unroll
    for (int i = 0; i < 8; i++) {
        xc[i] = (vc[i] - mc) * rc * gv[i] + bv[i];
        xp[i] = u ? (vp[i] - mp) * rp * gv[i] + bv[i] : 0.f;
    }

    size_t ob = (size_t)row * 512 + d0;
    float a[8];
    unsigned short o16[8];
    *(float4*)&a[0] = *(const float4*)(mk + d0);
    *(float4*)&a[4] = *(const float4*)(mk + d0 + 4);
#pragma unroll
    for (int i = 0; i < 8; i++) o16[i] = f2b(xc[i] * a[i] + xp[i] * (1.f - a[i]));
    *(u16x8*)((unsigned short*)ok + ob) = *(u16x8*)o16;
    if constexpr (NOUT == 3) {
        *(float4*)&a[0] = *(const float4*)(mv + d0);
        *(float4*)&a[4] = *(const float4*)(mv + d0 + 4);
#pragma unroll
        for (int i = 0; i < 8; i++) o16[i] = f2b(xc[i] * a[i] + xp[i] * (1.f - a[i]));
        *(u16x8*)((unsigned short*)ov + ob) = *(u16x8*)o16;
    }
    *(float4*)&a[0] = *(const float4*)(mr + d0);
    *(float4*)&a[4] = *(const float4*)(mr + d0 + 4);
#pragma unroll
    for (int i = 0; i < 8; i++) o16[i] = f2b(xc[i] * a[i] + xp[i] * (1.f - a[i]));
    *(u16x8*)((unsigned short*)orr + ob) = *(u16x8*)o16;
}

// ---------------------------------------------------------------------------
// WKV chunked scan. State (aa,bb,pp): num = aa*e^pp, den = bb*e^pp.
// Chunk combine: S_out = e^{w*WT} * S_in + S_local (associative).
// Pass 1: per (chunk,b,d) local state from zero. idx = c*4096 + b*512 + d;
// planes [aa|bb|pp] stride WPLANE. Coalesced: consecutive threads = consec d.
// ---------------------------------------------------------------------------
__global__ __launch_bounds__(256) void wkv_loc_k(
    const float* __restrict__ kbuf, const float* __restrict__ vbuf,
    float* __restrict__ st, const float* __restrict__ decay)
{
    int idx = blockIdx.x * 256 + threadIdx.x;   // [c][b][d]
    int bd = idx & 4095;
    int c = idx >> 12;
    int d = bd & 511;
    int b = bd >> 9;
    float w = -__expf(decay[d]);
    float aa = 0.f, bb = 0.f, pp = -1e38f;
    size_t base = ((size_t)b * 1024 + c * WT) * 512 + d;
#pragma unroll
    for (int s = 0; s < WT; s++) {
        float kt = kbuf[base + (size_t)s * 512];
        float vt = vbuf[base + (size_t)s * 512];
        float ww2 = pp + w;
        float p2 = ww2 > kt ? ww2 : kt;
        float e1 = __expf(ww2 - p2), e2 = __expf(kt - p2);
        aa = e1 * aa + e2 * vt;
        bb = e1 * bb + e2;
        pp = p2;
    }
    st[idx] = aa;
    st[WPLANE + idx] = bb;
    st[2 * WPLANE + idx] = pp;
}

// ---------------------------------------------------------------------------
// Pass 2: per (b,d), fold WC chunk-local states sequentially; write EXCLUSIVE
// incoming state per chunk. Decay of a full chunk = e^{w*WT}.
// ---------------------------------------------------------------------------
__global__ __launch_bounds__(256) void wkv_comb_k(
    const float* __restrict__ loc, float* __restrict__ inc,
    const float* __restrict__ decay)
{
    int bd = blockIdx.x * 256 + threadIdx.x;  // 4096
    int d = bd & 511;
    float wT = -__expf(decay[d]) * (float)WT;
    float aa = 0.f, bb = 0.f, pp = -1e38f;
    for (int c = 0; c < WC; c++) {
        int i = c * 4096 + bd;
        inc[i] = aa;
        inc[WPLANE + i] = bb;
        inc[2 * WPLANE + i] = pp;
        float la = loc[i], lb = loc[WPLANE + i], lp = loc[2 * WPLANE + i];
        float pd = pp + wT;
        float p2 = pd > lp ? pd : lp;
        float e1 = __expf(pd - p2), e2 = __expf(lp - p2);
        aa = e1 * aa + e2 * la;
        bb = e1 * bb + e2 * lb;
        pp = p2;
    }
}

// ---------------------------------------------------------------------------
// Pass 3: per (chunk,b,d), replay chunk from incoming state with the exact
// original per-step math. out = bf16(r * wkv).
// ---------------------------------------------------------------------------
__global__ __launch_bounds__(256) void wkv_out_k(
    const float* __restrict__ kbuf, const float* __restrict__ vbuf,
    const float* __restrict__ rbuf, bf16* __restrict__ outbuf,
    const float* __restrict__ inc,
    const float* __restrict__ decay, const float* __restrict__ first)
{
    int idx = blockIdx.x * 256 + threadIdx.x;
    int bd = idx & 4095;
    int c = idx >> 12;
    int d = bd & 511;
    int b = bd >> 9;
    float w = -__expf(decay[d]);
    float u = first[d];
    float aa = inc[idx], bb = inc[WPLANE + idx], pp = inc[2 * WPLANE + idx];
    size_t base = ((size_t)b * 1024 + c * WT) * 512 + d;
#pragma unroll
    for (int s = 0; s < WT; s++) {
        float kt = kbuf[base + (size_t)s * 512];
        float vt = vbuf[base + (size_t)s * 512];
        float rt = rbuf[base + (size_t)s * 512];
        float ww = u + kt;
        float p = pp > ww ? pp : ww;
        float e1 = __expf(pp - p), e2 = __expf(ww - p);
        float out = (e1 * aa + e2 * vt) / (e1 * bb + e2);
        outbuf[base + (size_t)s * 512] = __float2bfloat16(rt * out);
        float ww2 = pp + w;
        float p2 = ww2 > kt ? ww2 : kt;
        e1 = __expf(ww2 - p2);
        e2 = __expf(kt - p2);
        aa = e1 * aa + e2 * vt;
        bb = e1 * bb + e2;
        pp = p2;
    }
}

__global__ void olens_k(const int* __restrict__ x_len, float* __restrict__ out)
{
    int i = threadIdx.x;
    if (i < 8) {
        int l1 = (x_len[i] - 1) / 2 + 1;
        int ol = (l1 - 1) / 2 + 1;
        out[i] = (float)ol;
    }
}

// ---------------------------------------------------------------------------
extern "C" void kernel_launch(void* const* d_in, const int* in_sizes, int n_in,
                              void* d_out, int out_size, void* d_ws, size_t ws_size,
                              hipStream_t stream)
{
    (void)in_sizes; (void)n_in; (void)out_size; (void)ws_size;
    const float* x         = (const float*)d_in[0];
    const int*   x_len     = (const int*)d_in[1];
    const float* conv1_w   = (const float*)d_in[2];
    const float* conv1_b   = (const float*)d_in[3];
    const float* conv2_w   = (const float*)d_in[4];
    const float* conv2_b   = (const float*)d_in[5];
    const float* conv3_w   = (const float*)d_in[6];
    const float* conv3_b   = (const float*)d_in[7];
    const float* embed_w   = (const float*)d_in[8];
    const float* embed_b   = (const float*)d_in[9];
    const float* embed_ln_g= (const float*)d_in[10];
    const float* embed_ln_b= (const float*)d_in[11];
    const float* ln_att_g  = (const float*)d_in[12];
    const float* ln_att_b  = (const float*)d_in[13];
    const float* att_decay = (const float*)d_in[14];
    const float* att_first = (const float*)d_in[15];
    const float* att_mix_k = (const float*)d_in[16];
    const float* att_mix_v = (const float*)d_in[17];
    const float* att_mix_r = (const float*)d_in[18];
    const float* att_wk    = (const float*)d_in[19];
    const float* att_wv    = (const float*)d_in[20];
    const float* att_wr    = (const float*)d_in[21];
    const float* att_wo    = (const float*)d_in[22];
    const float* ln_ffn_g  = (const float*)d_in[23];
    const float* ln_ffn_b  = (const float*)d_in[24];
    const float* ffn_mix_k = (const float*)d_in[25];
    const float* ffn_mix_r = (const float*)d_in[26];
    const float* ffn_wk    = (const float*)d_in[27];
    const float* ffn_wv    = (const float*)d_in[28];
    const float* ffn_wr    = (const float*)d_in[29];
    const float* final_ln_g= (const float*)d_in[30];
    const float* final_ln_b= (const float*)d_in[31];

    // ---- workspace layout (MiB offsets, ~183 MiB) ----
    // 0..16 h | 16..32 xn (frontend) / wkv states (RWKV loop) | 32..40 rwkvb
    // 40..64 xkvr (xf aliases 40..56) | 64..112 kvrb | 112..144 kkb
    // conv overlay: c1b 40..80 | c2b(halo) 80..102.1 | zpg 103..103.004 |
    //               c3b 104..144
    // weights: attT 144..150 | attTo 150..152 | ffnT 152..162 | ffnTv 162..170
    //          embT 170..180 | c2wb 180..180.6 | c3wb 180.6..182.9
    char* wsb = (char*)d_ws;
    float* h     = (float*)(wsb);
    float* xn    = (float*)(wsb + (16LL << 20));
    float* sloc  = (float*)(wsb + (16LL << 20));   // [3][WC][4096] f32 (3MB)
    float* sinc  = (float*)(wsb + (20LL << 20));   // [3][WC][4096] f32 (3MB)
    bf16*  rwkvb = (bf16*) (wsb + (32LL << 20));
    bf16*  xkvr  = (bf16*) (wsb + (40LL << 20));   // [3][8192][512] bf16
    bf16*  xf    = xkvr;                           // [2][8192][512] bf16 (ffn)
    float* kvrb  = (float*)(wsb + (64LL << 20));   // [3][8192][512] f32
    bf16*  kkb   = (bf16*) (wsb + (112LL << 20));  // [8192][2048] bf16
    bf16*  c1b   = (bf16*) (wsb + (40LL << 20));   // (2,2048,40,128)
    bf16*  c2b   = (bf16*) (wsb + (80LL << 20));   // (2,1026,22,256) halo
    bf16*  zpg   = (bf16*) (wsb + (103LL << 20));  // 4KB zero page (conv2 OOB)
    bf16*  c3b   = (bf16*) (wsb + (104LL << 20));  // (2048,10240)
    bf16*  attT  = (bf16*) (wsb + (144LL << 20));  // 4 x [1536][512] (k,v,r)
    bf16*  attTo = (bf16*) (wsb + (150LL << 20));  // 4 x [512][512]  (wo)
    bf16*  ffnT  = (bf16*) (wsb + (152LL << 20));  // 4 x [2560][512] (wk|wr)
    bf16*  ffnTv = (bf16*) (wsb + (162LL << 20));  // 4 x [512][2048]
    bf16*  embT  = (bf16*) (wsb + (170LL << 20));  // [512][10240]
    bf16*  c2wb  = (bf16*) (wsb + (180LL << 20));  // 256 x 1152
    bf16*  c3wb  = (bf16*) (wsb + (180LL << 20) + 589824);  // 512 x 2304

    const size_t MD = 8192LL * 512;

    // ---- weight prep: packed transposed bf16
    transpose_k<<<dim3(16, 16, 4), 256, 0, stream>>>(att_wk, attT, 512, 512, 786432);
    transpose_k<<<dim3(16, 16, 4), 256, 0, stream>>>(att_wv, attT + 262144, 512, 512, 786432);
    transpose_k<<<dim3(16, 16, 4), 256, 0, stream>>>(att_wr, attT + 524288, 512, 512, 786432);
    transpose_k<<<dim3(16, 16, 4), 256, 0, stream>>>(att_wo, attTo, 512, 512, 262144);
    transpose_k<<<dim3(64, 16, 4), 256, 0, stream>>>(ffn_wk, ffnT, 512, 2048, 1310720);
    transpose_k<<<dim3(16, 16, 4), 256, 0, stream>>>(ffn_wr, ffnT + 1048576, 512, 512, 1310720);
    transpose_k<<<dim3(16, 64, 4), 256, 0, stream>>>(ffn_wv, ffnTv, 2048, 512, 1048576);
    transpose_k<<<dim3(16, 320, 1), 256, 0, stream>>>(embed_w, embT, 10240, 512, 0);
    reorder_w_k<<<1152, 256, 0, stream>>>(conv2_w, c2wb, 256, 128);
    reorder_w_k<<<4608, 256, 0, stream>>>(conv3_w, c3wb, 512, 256);
    hipMemsetAsync(xn, 0, 16LL << 20, stream);
    hipMemsetAsync(c2b, 0, 2LL * 1026 * 22 * 256 * 2, stream);
    hipMemsetAsync(zpg, 0, 4096, stream);

    // ---- conv frontend + embed (split-K x4, atomic), 2 batches per chunk
    for (int chunk = 0; chunk < 4; chunk++) {
        int b0 = chunk * 2;
        conv1_k<<<640, 256, 0, stream>>>(x + (size_t)b0 * 327680, conv1_w, conv1_b, c1b);
        gemm_k<128, B_CONV, EP_CONV_CL, 0, 2048, 40, 2, 128, 0><<<dim3(320, 2), 256, 0, stream>>>(
            c2wb, zpg, c1b, nullptr, c2b, conv2_b, nullptr, 256, 40960, 1152, 1152);
        gemm_k<128, B_CONV, EP_CONV_T, 0, 1024, 20, 1, 256, 1><<<dim3(320, 4), 256, 0, stream>>>(
            c3wb, nullptr, c2b, nullptr, c3b, conv3_b, nullptr, 512, 40960, 2304, 2304);
        gemm_k<64, B_T, EP_ATOMIC, 0, 0, 0, 0, 0, 0><<<dim3(4, 32, 4), 256, 0, stream>>>(
            c3b, embT, nullptr, xn + (size_t)b0 * 1024 * 512, nullptr, embed_b, nullptr,
            2048, 512, 10240, 2560);
    }
    ln_k<<<2048, 256, 0, stream>>>(xn, h, embed_ln_g, embed_ln_b, 8192);

    // ---- 4 RWKV blocks
    for (int i = 0; i < 4; i++) {
        // time mixing (LN fused into mix)
        lnmix_k<3><<<2048, 256, 0, stream>>>(h, ln_att_g + i * 512, ln_att_b + i * 512,
                                             att_mix_k + i * 512, att_mix_v + i * 512,
                                             att_mix_r + i * 512,
                                             xkvr, xkvr + MD, xkvr + 2 * MD);
        gemm_k<64, B_T, EP_KVR, 9, 0, 0, 0, 0, 0><<<dim3(12, 128), 256, 0, stream>>>(
            xkvr, attT + (size_t)i * 786432, nullptr, kvrb, nullptr, nullptr, nullptr,
            8192, 1536, 512, 512);
        wkv_loc_k<<<1024, 256, 0, stream>>>(kvrb, kvrb + MD, sloc, att_decay + i * 512);
        wkv_comb_k<<<16, 256, 0, stream>>>(sloc, sinc, att_decay + i * 512);
        wkv_out_k<<<1024, 256, 0, stream>>>(kvrb, kvrb + MD, kvrb + 2 * MD, rwkvb,
                                            sinc, att_decay + i * 512, att_first + i * 512);
        gemm_k<64, B_T, EP_ADD, 0, 0, 0, 0, 0, 0><<<dim3(4, 128), 256, 0, stream>>>(
            rwkvb, attTo + (size_t)i * 262144, nullptr, h, nullptr, nullptr, nullptr,
            8192, 512, 512, 512);
        // channel mixing (LN fused into mix)
        lnmix_k<2><<<2048, 256, 0, stream>>>(h, ln_ffn_g + i * 512, ln_ffn_b + i * 512,
                                             ffn_mix_k + i * 512, nullptr,
                                             ffn_mix_r + i * 512,
                                             xf, nullptr, xf + MD);
        gemm_k<64, B_T, EP_FFN, 11, 0, 0, 0, 0, 0><<<dim3(20, 128), 256, 0, stream>>>(
            xf, ffnT + (size_t)i * 1310720, nullptr, kvrb + 2 * MD, kkb, nullptr, nullptr,
            8192, 2560, 512, 512);
        gemm_k<64, B_T, EP_ADDMUL, 0, 0, 0, 0, 0, 0><<<dim3(4, 128), 256, 0, stream>>>(
            kkb, ffnTv + (size_t)i * 1048576, nullptr, h, nullptr, nullptr, kvrb + 2 * MD,
            8192, 512, 2048, 2048);
    }

    // ---- final LN straight into d_out, then olens
    ln_k<<<2048, 256, 0, stream>>>(h, (float*)d_out, final_ln_g, final_ln_b, 8192);
    olens_k<<<1, 64, 0, stream>>>(x_len, (float*)d_out + 4194304);
}

// Round 8
// 1860.863 us; speedup vs baseline: 1.4945x; 1.0405x over previous
//
#include <hip/hip_runtime.h>
#include <hip/hip_bf16.h>
#include <hip/hip_fp8.h>

typedef __hip_bfloat16 bf16;
typedef __bf16 v8bf __attribute__((ext_vector_type(8)));
typedef float v4f __attribute__((ext_vector_type(4)));
typedef unsigned short u16x8 __attribute__((ext_vector_type(8)));

// ---------------------------------------------------------------------------
//   x: (8,4096,80) -> conv1(1->128,s2) -> (8,2048,40,128)   [channel-last fp8]
//   -> conv2(128->256,s2) -> halo (8,1026,22,256) fp8
//   -> conv3(256->512,s1) -> tokens (8,1024,10240) fp8
//   -> embed GEMM fp8 (split-K, atomic) -> 4 RWKV blocks (bf16) -> final LN
// GEMM core: TM x 128 tile, BK=32, 3-buffer counted-vmcnt pipeline (T3+T4).
// F8=1 path: mfma_f32_16x16x32_fp8_fp8 (same rate/shape as bf16, half bytes:
// staging L=2, LDS 24KB, ds_read_b64). Weights pre-scaled (x16 conv, x64
// embed; sigma~0.01 would land subnormal in e4m3); epilogue multiplies 1/scale.
// fp8 swizzle (32B rows): stage-half ^= (tid>>4)&1; read slot = lq^(((lr>>3)&1)<<1)
// -> residual 2-way bank alias (free, m136). bf16 swizzle as r7 (conflicts=0).
// TM=64 fp8 A-tile: waves 2,3 duplicate-load rows (identical bytes) to keep
// per-wave load counts UNIFORM -- masking would break counted vmcnt.
// WKV: 3-pass chunked associative scan (C=64 chunks of T=16).
// ---------------------------------------------------------------------------

constexpr int B_T = 0, B_CONV = 1;
constexpr int EP_CONV_CL = 0, EP_CONV_T = 1, EP_ATOMIC = 2, EP_KVR = 3,
              EP_ADD = 4, EP_FFN = 5, EP_ADDMUL = 6;

constexpr int WC = 64;          // wkv chunks per sequence
constexpr int WT = 1024 / WC;   // 16 steps per chunk
constexpr int WPLANE = WC * 4096;  // 262144 states per plane

static __device__ __forceinline__ unsigned short f2b(float f) {
    return __builtin_bit_cast(unsigned short, __float2bfloat16(f));
}
static __device__ __forceinline__ unsigned char f2e4(float f) {
    __hip_fp8_e4m3 q(f);
    return (unsigned char)q.__x;
}

// global -> LDS async copy, 16B per lane. LDS dest must be the wave-uniform
// base; HW writes lane i at base + i*16.
static __device__ __forceinline__ void gld16(const unsigned char* g,
                                             unsigned char* l) {
    __builtin_amdgcn_global_load_lds(
        (__attribute__((address_space(1))) void*)g,
        (__attribute__((address_space(3))) void*)l, 16, 0, 0);
}

// ---------------------------------------------------------------------------
// MFMA GEMM: C[M,N] = A[M,K] * B[K,N]. A [M][K]; B [N][K] (B_T) or
// channel-last im2col gather (B_CONV; HALO=1 -> zero-padded halo buffer;
// HALO=0 -> OOB lanes read zero page Bw). ASH>0: A += (n0>>ASH)*M*K.
// Loads/wave/stage: bf16 L = TM/64+2; fp8 L = 2. Steady wait vmcnt(2L).
// ---------------------------------------------------------------------------
template <int TM, int BL, int EPM, int ASH, int TIN, int FIN, int STRIDE,
          int ICN, int HALO, int F8>
__global__ __launch_bounds__(256) void gemm_k(
    const void* __restrict__ Av, const void* __restrict__ Bwv,
    const void* __restrict__ Bactv,
    float* __restrict__ C, void* __restrict__ Cbv,
    const float* __restrict__ bias, const float* __restrict__ mul,
    int M, int N, int K, int KLEN, float wsc)
{
    constexpr int MI = TM / 32;
    constexpr int ESZ = F8 ? 1 : 2;
    constexpr int RB = 32 * ESZ;               // bytes per BK=32 row
    __shared__ __align__(16) unsigned char As[3][TM * RB];
    __shared__ __align__(16) unsigned char Bs[3][128 * RB];
    const unsigned char* A    = (const unsigned char*)Av;
    const unsigned char* Bw   = (const unsigned char*)Bwv;
    const unsigned char* Bact = (const unsigned char*)Bactv;
    const int tid = threadIdx.x;
    const int n0 = blockIdx.x * 128;
    const int m0 = blockIdx.y * TM;
    const int kbase = blockIdx.z * KLEN;
    const int wave = tid >> 6, lane = tid & 63;
    const int wr = wave >> 1, wc = wave & 1;
    const int lq = lane >> 4, lr = lane & 15;

    if constexpr (ASH > 0) A += (size_t)(n0 >> ASH) * M * K * ESZ;

    v4f acc[MI][4];
#pragma unroll
    for (int i = 0; i < MI; i++)
#pragma unroll
        for (int j = 0; j < 4; j++) acc[i][j] = v4f{0.f, 0.f, 0.f, 0.f};

    // staging swizzles (T2, both-sides-or-neither):
    const int swz8 = ((tid & 1) ^ ((tid >> 4) & 1)) * 16;   // fp8: byte off in 32B row
    const int scS  = ((tid & 3) ^ ((tid >> 3) & 3)) * 8;    // bf16: elem off in row

    constexpr int NAP = F8 ? 1 : TM / 64;
    const unsigned char* aP[NAP];
    const unsigned char* bP[2];
    int cb0 = 0, cb1 = 0, cto0 = 0, cto1 = 0, cfo0 = 0, cfo1 = 0;

    if constexpr (F8) {
        const int ar = (tid >> 1) % TM;        // rows dup for TM=64 (uniform L!)
        aP[0] = A + (size_t)(m0 + ar) * K + swz8;
        if constexpr (BL == B_T) {
            bP[0] = Bw + (size_t)(n0 + (tid >> 1)) * K + swz8;
        } else {
            int n = n0 + (tid >> 1);
            cb0 = n / 20480;
            int s = n - cb0 * 20480;
            cto0 = s / 20;
            cfo0 = s - cto0 * 20;
            if constexpr (HALO)
                bP[0] = Bact + (((size_t)cb0 * 1026 + cto0) * 22 + cfo0) * 256 + swz8;
        }
    } else {
        const int sr = tid >> 2;
#pragma unroll
        for (int c = 0; c < NAP; c++)
            aP[c] = A + ((size_t)(m0 + c * 64 + sr) * K + scS) * 2;
        if constexpr (BL == B_T) {
#pragma unroll
            for (int c = 0; c < 2; c++)
                bP[c] = Bw + ((size_t)(n0 + c * 64 + sr) * K + scS) * 2;
        } else {
            {
                int n = n0 + sr;
                cb0 = n / 20480;
                int s = n - cb0 * 20480;
                cto0 = s / 20;
                cfo0 = s - cto0 * 20;
            }
            {
                int n = n0 + 64 + sr;
                cb1 = n / 20480;
                int s = n - cb1 * 20480;
                cto1 = s / 20;
                cfo1 = s - cto1 * 20;
            }
            if constexpr (HALO) {
                bP[0] = Bact + ((((size_t)cb0 * 1026 + cto0) * 22 + cfo0) * 256 + scS) * 2;
                bP[1] = Bact + ((((size_t)cb1 * 1026 + cto1) * 22 + cfo1) * 256 + scS) * 2;
            }
        }
    }

    auto stageA = [&](int k0, int sel) {
        if constexpr (F8) {
            constexpr int AW = (TM * RB) / 1024;   // 4 (TM128) / 2 (TM64)
            gld16(aP[0] + k0, &As[sel][(wave % AW) * 1024]);
        } else {
#pragma unroll
            for (int c = 0; c < NAP; c++)
                gld16(aP[c] + (size_t)k0 * 2, &As[sel][c * 4096 + wave * 1024]);
        }
    };
    auto stageB = [&](int k0, int sel) {
        if constexpr (BL == B_T) {
            if constexpr (F8) {
                gld16(bP[0] + k0, &Bs[sel][wave * 1024]);
            } else {
#pragma unroll
                for (int c = 0; c < 2; c++)
                    gld16(bP[c] + (size_t)k0 * 2, &Bs[sel][c * 4096 + wave * 1024]);
            }
        } else {
            int kg = k0 / ICN;             // kt*3+kf
            int ic0 = k0 - kg * ICN;       // channel base of this K-slice
            int kt = kg / 3, kf = kg - kt * 3;
            if constexpr (F8) {
                if constexpr (HALO) {      // conv3: bP already carries swz8
                    gld16(bP[0] + (kt * 22 + kf) * 256 + ic0, &Bs[sel][wave * 1024]);
                } else {                   // conv2: OOB -> zero page (Bw)
                    int ti = cto0 * STRIDE - 1 + kt, fi = cfo0 * STRIDE - 1 + kf;
                    const unsigned char* s0 =
                        ((unsigned)ti < (unsigned)TIN && (unsigned)fi < (unsigned)FIN)
                        ? Bact + (((size_t)cb0 * TIN + ti) * FIN + fi) * ICN + ic0 + swz8
                        : Bw;
                    gld16(s0, &Bs[sel][wave * 1024]);
                }
            } else {
                if constexpr (HALO) {
                    gld16(bP[0] + ((size_t)(kt * 22 + kf) * 256 + ic0) * 2,
                          &Bs[sel][wave * 1024]);
                    gld16(bP[1] + ((size_t)(kt * 22 + kf) * 256 + ic0) * 2,
                          &Bs[sel][4096 + wave * 1024]);
                } else {
                    int ti0 = cto0 * STRIDE - 1 + kt, fi0 = cfo0 * STRIDE - 1 + kf;
                    const unsigned char* s0 =
                        ((unsigned)ti0 < (unsigned)TIN && (unsigned)fi0 < (unsigned)FIN)
                        ? Bact + ((((size_t)cb0 * TIN + ti0) * FIN + fi0) * ICN + ic0 + scS) * 2
                        : Bw;
                    gld16(s0, &Bs[sel][wave * 1024]);
                    int ti1 = cto1 * STRIDE - 1 + kt, fi1 = cfo1 * STRIDE - 1 + kf;
                    const unsigned char* s1 =
                        ((unsigned)ti1 < (unsigned)TIN && (unsigned)fi1 < (unsigned)FIN)
                        ? Bact + ((((size_t)cb1 * TIN + ti1) * FIN + fi1) * ICN + ic0 + scS) * 2
                        : Bw;
                    gld16(s1, &Bs[sel][4096 + wave * 1024]);
                }
            }
        }
    };
    auto compute = [&](int sel) {
        if constexpr (F8) {
            const int so = ((lr >> 3) & 1) << 1;
            long fa[MI], fb[4];
#pragma unroll
            for (int mi = 0; mi < MI; mi++)
                fa[mi] = *(const long*)&As[sel][(wr * (TM / 2) + mi * 16 + lr) * 32 +
                                                (lq ^ so) * 8];
#pragma unroll
            for (int ni = 0; ni < 4; ni++)
                fb[ni] = *(const long*)&Bs[sel][(wc * 64 + ni * 16 + lr) * 32 +
                                                (lq ^ so) * 8];
#pragma unroll
            for (int mi = 0; mi < MI; mi++)
#pragma unroll
                for (int ni = 0; ni < 4; ni++)
                    acc[mi][ni] = __builtin_amdgcn_mfma_f32_16x16x32_fp8_fp8(
                        fa[mi], fb[ni], acc[mi][ni], 0, 0, 0);
        } else {
            const int lsw = (lr >> 1) & 3;
            v8bf fa[MI], fb[4];
#pragma unroll
            for (int mi = 0; mi < MI; mi++)
                fa[mi] = *(const v8bf*)&As[sel][(wr * (TM / 2) + mi * 16 + lr) * 64 +
                                               (lq ^ lsw) * 16];
#pragma unroll
            for (int ni = 0; ni < 4; ni++)
                fb[ni] = *(const v8bf*)&Bs[sel][(wc * 64 + ni * 16 + lr) * 64 +
                                               (lq ^ lsw) * 16];
#pragma unroll
            for (int mi = 0; mi < MI; mi++)
#pragma unroll
                for (int ni = 0; ni < 4; ni++)
                    acc[mi][ni] = __builtin_amdgcn_mfma_f32_16x16x32_bf16(
                        fa[mi], fb[ni], acc[mi][ni], 0, 0, 0);
        }
    };

    // ---- 3-buffer counted-vmcnt pipeline. NT >= 8 for all instances.
    const int NT = KLEN / 32;
    stageA(kbase, 0);       stageB(kbase, 0);
    stageA(kbase + 32, 1);  stageB(kbase + 32, 1);
    stageA(kbase + 64, 2);  stageB(kbase + 64, 2);
    int sel = 0;
    for (int t = 0; t < NT - 2; ++t) {
        if constexpr (F8)
            asm volatile("s_waitcnt vmcnt(4)" ::: "memory");
        else if constexpr (TM == 128)
            asm volatile("s_waitcnt vmcnt(8)" ::: "memory");
        else
            asm volatile("s_waitcnt vmcnt(6)" ::: "memory");
        __builtin_amdgcn_sched_barrier(0);
        __builtin_amdgcn_s_barrier();     // all waves' stage(t) landed
        compute(sel);
        __builtin_amdgcn_s_barrier();     // all reads of buf[sel] done
        if (t + 3 < NT) {
            int k0 = kbase + (t + 3) * 32;
            stageA(k0, sel);
            stageB(k0, sel);
        }
        sel = sel == 2 ? 0 : sel + 1;
    }
    // t = NT-2: two stages outstanding -> wait for the older one
    if constexpr (F8)
        asm volatile("s_waitcnt vmcnt(2)" ::: "memory");
    else if constexpr (TM == 128)
        asm volatile("s_waitcnt vmcnt(4)" ::: "memory");
    else
        asm volatile("s_waitcnt vmcnt(3)" ::: "memory");
    __builtin_amdgcn_sched_barrier(0);
    __builtin_amdgcn_s_barrier();
    compute(sel);
    sel = sel == 2 ? 0 : sel + 1;
    // t = NT-1: last stage
    asm volatile("s_waitcnt vmcnt(0)" ::: "memory");
    __builtin_amdgcn_sched_barrier(0);
    __builtin_amdgcn_s_barrier();
    compute(sel);

    // ---- epilogue
#pragma unroll
    for (int mi = 0; mi < MI; mi++) {
#pragma unroll
        for (int ni = 0; ni < 4; ni++) {
#pragma unroll
            for (int reg = 0; reg < 4; reg++) {
                int row = m0 + wr * (TM / 2) + mi * 16 + lq * 4 + reg;
                int col = n0 + wc * 64 + ni * 16 + lr;
                float v = acc[mi][ni][reg] * wsc;
                if constexpr (EPM == EP_CONV_CL) {
                    v += bias[row];
                    v = v > 0.f ? v : 0.f;
                    int b = col / 20480;
                    int s = col - b * 20480;
                    int t = s / 20, fo = s - t * 20;
                    ((unsigned char*)Cbv)[(((size_t)b * 1026 + t + 1) * 22 + fo + 1) * 256 + row] =
                        f2e4(v);
                } else if constexpr (EPM == EP_CONV_T) {
                    v += bias[row];
                    v = v > 0.f ? v : 0.f;
                    int b = col / 20480;
                    int s = col - b * 20480;
                    int t = s / 20, fo = s - t * 20;
                    ((unsigned char*)Cbv)[(size_t)(b * 1024 + t) * 10240 + row * 20 + fo] =
                        f2e4(v);
                } else if constexpr (EPM == EP_ATOMIC) {
                    float add = (blockIdx.z == 0) ? bias[col] : 0.f;
                    atomicAdd(&C[(size_t)row * N + col], v + add);
                } else if constexpr (EPM == EP_KVR) {
                    int seg = col >> 9;     // 0=k,1=v,2=r (uniform per block)
                    if (seg == 2) v = 1.f / (1.f + __expf(-v));
                    C[(size_t)seg * M * 512 + (size_t)row * 512 + (col & 511)] = v;
                } else if constexpr (EPM == EP_ADD) {
                    C[(size_t)row * N + col] += v;
                } else if constexpr (EPM == EP_FFN) {
                    if (col < 2048) {       // wk branch: sqrelu -> bf16 kkb
                        float t = v > 0.f ? v : 0.f;
                        ((bf16*)Cbv)[(size_t)row * 2048 + col] = __float2bfloat16(t * t);
                    } else {                // wr branch: sigmoid -> f32 rb
                        C[(size_t)row * 512 + (col - 2048)] = 1.f / (1.f + __expf(-v));
                    }
                } else if constexpr (EPM == EP_ADDMUL) {
                    size_t idx = (size_t)row * N + col;
                    C[idx] += mul[idx] * v;
                }
            }
        }
    }
}

// ---------------------------------------------------------------------------
// Prep: conv weight OIHW f32 -> fp8 e4m3 [oc][(kt*3+kf)*IC + ic], scaled x16
// ---------------------------------------------------------------------------
__global__ __launch_bounds__(256) void reorder_w8_k(const float* __restrict__ in,
                                                    unsigned char* __restrict__ out,
                                                    int OC, int IC)
{
    int idx = blockIdx.x * 256 + threadIdx.x;
    if (idx >= OC * IC * 9) return;
    int oc = idx / (IC * 9);
    int r = idx - oc * (IC * 9);
    int g = r / IC;
    int ic = r - g * IC;
    out[idx] = f2e4(in[((size_t)oc * IC + ic) * 9 + g] * 16.f);
}

// ---------------------------------------------------------------------------
// Prep: f32 [K][N] -> bf16 [N][K]; z: in stride K*N, out stride ozs
// ---------------------------------------------------------------------------
__global__ __launch_bounds__(256) void transpose_k(const float* __restrict__ in,
                                                   bf16* __restrict__ out,
                                                   int K, int N, size_t ozs)
{
    __shared__ float t[32][33];
    const float* pin = in + (size_t)blockIdx.z * K * N;
    bf16* pout = out + (size_t)blockIdx.z * ozs;
    int n0 = blockIdx.x * 32, k0 = blockIdx.y * 32;
    int tx = threadIdx.x & 31, ty = threadIdx.x >> 5;
#pragma unroll
    for (int i = 0; i < 32; i += 8)
        t[ty + i][tx] = pin[(size_t)(k0 + ty + i) * N + n0 + tx];
    __syncthreads();
#pragma unroll
    for (int i = 0; i < 32; i += 8)
        pout[(size_t)(n0 + ty + i) * K + k0 + tx] = __float2bfloat16(t[tx][ty + i]);
}

// ---------------------------------------------------------------------------
// Prep: f32 [K][N] -> fp8 e4m3 [N][K], scaled x64 (embed weights, sigma~0.01)
// ---------------------------------------------------------------------------
__global__ __launch_bounds__(256) void transpose8_k(const float* __restrict__ in,
                                                    unsigned char* __restrict__ out,
                                                    int K, int N)
{
    __shared__ float t[32][33];
    int n0 = blockIdx.x * 32, k0 = blockIdx.y * 32;
    int tx = threadIdx.x & 31, ty = threadIdx.x >> 5;
#pragma unroll
    for (int i = 0; i < 32; i += 8)
        t[ty + i][tx] = in[(size_t)(k0 + ty + i) * N + n0 + tx];
    __syncthreads();
#pragma unroll
    for (int i = 0; i < 32; i += 8)
        out[(size_t)(n0 + ty + i) * K + k0 + tx] = f2e4(t[tx][ty + i] * 64.f);
}

// ---------------------------------------------------------------------------
// conv1 for a 2-batch chunk: 1 input channel, direct, channel-last fp8 out.
// ---------------------------------------------------------------------------
__global__ __launch_bounds__(256) void conv1_k(
    const float* __restrict__ x, const float* __restrict__ w,
    const float* __restrict__ bias, unsigned char* __restrict__ out)
{
    __shared__ float ws_[128 * 9];
    __shared__ float bs_[128];
    const int tid = threadIdx.x;
    for (int i = tid; i < 128 * 9; i += 256) ws_[i] = w[i];
    if (tid < 128) bs_[tid] = bias[tid];
    __syncthreads();

    int idx = blockIdx.x * 256 + tid;  // 2*2048*40
    int f = idx % 40;
    int t = (idx / 40) & 2047;
    int b = idx / 81920;

    float xin[9];
#pragma unroll
    for (int kt = 0; kt < 3; kt++)
#pragma unroll
        for (int kf = 0; kf < 3; kf++) {
            int ti = 2 * t - 1 + kt, fi = 2 * f - 1 + kf;
            float v = 0.f;
            if ((unsigned)ti < 4096u && (unsigned)fi < 80u)
                v = x[(size_t)b * 327680 + (size_t)ti * 80 + fi];
            xin[kt * 3 + kf] = v;
        }
    unsigned char* outu = out + (size_t)idx * 128;
#pragma unroll
    for (int oc8 = 0; oc8 < 16; oc8++) {
        unsigned char pk[8];
#pragma unroll
        for (int j = 0; j < 8; j++) {
            int oc = oc8 * 8 + j;
            float a = bs_[oc];
#pragma unroll
            for (int q = 0; q < 9; q++) a += ws_[oc * 9 + q] * xin[q];
            a = a > 0.f ? a : 0.f;
            pk[j] = f2e4(a);
        }
        *(unsigned long long*)&outu[oc8 * 8] = *(unsigned long long*)pk;
    }
}

// ---------------------------------------------------------------------------
// LayerNorm over D=512, one wave per row (4 rows / block)
// ---------------------------------------------------------------------------
__global__ __launch_bounds__(256) void ln_k(
    const float* __restrict__ in, float* __restrict__ out,
    const float* __restrict__ g, const float* __restrict__ b, int M)
{
    int wave = threadIdx.x >> 6;
    int lane = threadIdx.x & 63;
    int row = blockIdx.x * 4 + wave;
    if (row >= M) return;
    const float* p = in + (size_t)row * 512;
    float v[8], s = 0.f, sq = 0.f;
#pragma unroll
    for (int i = 0; i < 8; i++) {
        v[i] = p[lane + i * 64];
        s += v[i];
        sq += v[i] * v[i];
    }
#pragma unroll
    for (int o = 32; o > 0; o >>= 1) {
        s += __shfl_xor(s, o, 64);
        sq += __shfl_xor(sq, o, 64);
    }
    float mean = s * (1.f / 512.f);
    float var = sq * (1.f / 512.f) - mean * mean;
    float r = rsqrtf(var + 1e-5f);
    float* q = out + (size_t)row * 512;
#pragma unroll
    for (int i = 0; i < 8; i++) {
        int d = lane + i * 64;
        q[d] = (v[i] - mean) * r * g[d] + b[d];
    }
}

// ---------------------------------------------------------------------------
// Fused LN + token-shift mix -> bf16 operands. One wave per row; the wave
// also recomputes the predecessor row's LN (exact same f32 math). Lane owns
// 8 contiguous dims (16-B loads/stores). NOUT=3 (att) or 2 (ffn).
// ---------------------------------------------------------------------------
template <int NOUT>
__global__ __launch_bounds__(256) void lnmix_k(
    const float* __restrict__ hb, const float* __restrict__ g,
    const float* __restrict__ b, const float* __restrict__ mk,
    const float* __restrict__ mv, const float* __restrict__ mr,
    bf16* __restrict__ ok, bf16* __restrict__ ov, bf16* __restrict__ orr)
{
    int wave = threadIdx.x >> 6, lane = threadIdx.x & 63;
    int row = blockIdx.x * 4 + wave;     // 8192 rows
    int u = row & 1023;
    int d0 = lane * 8;
    const float* pc = hb + (size_t)row * 512 + d0;

    float vc[8], vp[8];
    *(float4*)&vc[0] = *(const float4*)pc;
    *(float4*)&vc[4] = *(const float4*)(pc + 4);
    float s = 0.f, sq = 0.f, sp = 0.f, sqp = 0.f;
#pragma unroll
    for (int i = 0; i < 8; i++) { s += vc[i]; sq += vc[i] * vc[i]; }
    if (u) {
        *(float4*)&vp[0] = *(const float4*)(pc - 512);
        *(float4*)&vp[4] = *(const float4*)(pc - 508);
#pragma unroll
        for (int i = 0; i < 8; i++) { sp += vp[i]; sqp += vp[i] * vp[i]; }
    } else {
#pragma unroll
        for (int i = 0; i < 8; i++) vp[i] = 0.f;
    }
#pragma unroll
    for (int o = 32; o > 0; o >>= 1) {
        s += __shfl_xor(s, o, 64);
        sq += __shfl_xor(sq, o, 64);
        sp += __shfl_xor(sp, o, 64);
        sqp += __shfl_xor(sqp, o, 64);
    }
    float mc = s * (1.f / 512.f);
    float rc = rsqrtf(sq * (1.f / 512.f) - mc * mc + 1e-5f);
    float mp = sp * (1.f / 512.f);
    float rp = rsqrtf(sqp * (1.f / 512.f) - mp * mp + 1e-5f);

    float gv[8], bv[8], xc[8], xp[8];
    *(float4*)&gv[0] = *(const float4*)(g + d0);
    *(float4*)&gv[4] = *(const float4*)(g + d0 + 4);
    *(float4*)&bv[0] = *(const float4*)(b + d0);
    *(float4*)&bv[4] = *(const float4*)(b + d0 + 4);
#pragma unroll
    for (int i = 0; i < 8; i++) {
        xc[i] = (vc[i] - mc) * rc * gv[i] + bv[i];
        xp[i] = u ? (vp[i] - mp) * rp * gv[i] + bv[i] : 0.f;
    }

    size_t ob = (size_t)row * 512 + d0;
    float a[8];
    unsigned short o16[8];
    *(float4*)&a[0] = *(const float4*)(mk + d0);
    *(float4*)&a[4] = *(const float4*)(mk + d0 + 4);
#pragma unroll
    for (int i = 0; i < 8; i++) o16[i] = f2b(xc[i] * a[i] + xp[i] * (1.f - a[i]));
    *(u16x8*)((unsigned short*)ok + ob) = *(u16x8*)o16;
    if constexpr (NOUT == 3) {
        *(float4*)&a[0] = *(const float4*)(mv + d0);
        *(float4*)&a[4] = *(const float4*)(mv + d0 + 4);
#pragma unroll
        for (int i = 0; i < 8; i++) o16[i] = f2b(xc[i] * a[i] + xp[i] * (1.f - a[i]));
        *(u16x8*)((unsigned short*)ov + ob) = *(u16x8*)o16;
    }
    *(float4*)&a[0] = *(const float4*)(mr + d0);
    *(float4*)&a[4] = *(const float4*)(mr + d0 + 4);
#pragma unroll
    for (int i = 0; i < 8; i++) o16[i] = f2b(xc[i] * a[i] + xp[i] * (1.f - a[i]));
    *(u16x8*)((unsigned short*)orr + ob) = *(u16x8*)o16;
}

// ---------------------------------------------------------------------------
// WKV chunked scan. State (aa,bb,pp): num = aa*e^pp, den = bb*e^pp.
// Chunk combine: S_out = e^{w*WT} * S_in + S_local (associative).
// ---------------------------------------------------------------------------
__global__ __launch_bounds__(256) void wkv_loc_k(
    const float* __restrict__ kbuf, const float* __restrict__ vbuf,
    float* __restrict__ st, const float* __restrict__ decay)
{
    int idx = blockIdx.x * 256 + threadIdx.x;   // [c][b][d]
    int bd = idx & 4095;
    int c = idx >> 12;
    int d = bd & 511;
    int b = bd >> 9;
    float w = -__expf(decay[d]);
    float aa = 0.f, bb = 0.f, pp = -1e38f;
    size_t base = ((size_t)b * 1024 + c * WT) * 512 + d;
#pragma unroll
    for (int s = 0; s < WT; s++) {
        float kt = kbuf[base + (size_t)s * 512];
        float vt = vbuf[base + (size_t)s * 512];
        float ww2 = pp + w;
        float p2 = ww2 > kt ? ww2 : kt;
        float e1 = __expf(ww2 - p2), e2 = __expf(kt - p2);
        aa = e1 * aa + e2 * vt;
        bb = e1 * bb + e2;
        pp = p2;
    }
    st[idx] = aa;
    st[WPLANE + idx] = bb;
    st[2 * WPLANE + idx] = pp;
}

__global__ __launch_bounds__(256) void wkv_comb_k(
    const float* __restrict__ loc, float* __restrict__ inc,
    const float* __restrict__ decay)
{
    int bd = blockIdx.x * 256 + threadIdx.x;  // 4096
    int d = bd & 511;
    float wT = -__expf(decay[d]) * (float)WT;
    float aa = 0.f, bb = 0.f, pp = -1e38f;
    for (int c = 0; c < WC; c++) {
        int i = c * 4096 + bd;
        inc[i] = aa;
        inc[WPLANE + i] = bb;
        inc[2 * WPLANE + i] = pp;
        float la = loc[i], lb = loc[WPLANE + i], lp = loc[2 * WPLANE + i];
        float pd = pp + wT;
        float p2 = pd > lp ? pd : lp;
        float e1 = __expf(pd - p2), e2 = __expf(lp - p2);
        aa = e1 * aa + e2 * la;
        bb = e1 * bb + e2 * lb;
        pp = p2;
    }
}

__global__ __launch_bounds__(256) void wkv_out_k(
    const float* __restrict__ kbuf, const float* __restrict__ vbuf,
    const float* __restrict__ rbuf, bf16* __restrict__ outbuf,
    const float* __restrict__ inc,
    const float* __restrict__ decay, const float* __restrict__ first)
{
    int idx = blockIdx.x * 256 + threadIdx.x;
    int bd = idx & 4095;
    int c = idx >> 12;
    int d = bd & 511;
    int b = bd >> 9;
    float w = -__expf(decay[d]);
    float u = first[d];
    float aa = inc[idx], bb = inc[WPLANE + idx], pp = inc[2 * WPLANE + idx];
    size_t base = ((size_t)b * 1024 + c * WT) * 512 + d;
#pragma unroll
    for (int s = 0; s < WT; s++) {
        float kt = kbuf[base + (size_t)s * 512];
        float vt = vbuf[base + (size_t)s * 512];
        float rt = rbuf[base + (size_t)s * 512];
        float ww = u + kt;
        float p = pp > ww ? pp : ww;
        float e1 = __expf(pp - p), e2 = __expf(ww - p);
        float out = (e1 * aa + e2 * vt) / (e1 * bb + e2);
        outbuf[base + (size_t)s * 512] = __float2bfloat16(rt * out);
        float ww2 = pp + w;
        float p2 = ww2 > kt ? ww2 : kt;
        e1 = __expf(ww2 - p2);
        e2 = __expf(kt - p2);
        aa = e1 * aa + e2 * vt;
        bb = e1 * bb + e2;
        pp = p2;
    }
}

__global__ void olens_k(const int* __restrict__ x_len, float* __restrict__ out)
{
    int i = threadIdx.x;
    if (i < 8) {
        int l1 = (x_len[i] - 1) / 2 + 1;
        int ol = (l1 - 1) / 2 + 1;
        out[i] = (float)ol;
    }
}

// ---------------------------------------------------------------------------
extern "C" void kernel_launch(void* const* d_in, const int* in_sizes, int n_in,
                              void* d_out, int out_size, void* d_ws, size_t ws_size,
                              hipStream_t stream)
{
    (void)in_sizes; (void)n_in; (void)out_size; (void)ws_size;
    const float* x         = (const float*)d_in[0];
    const int*   x_len     = (const int*)d_in[1];
    const float* conv1_w   = (const float*)d_in[2];
    const float* conv1_b   = (const float*)d_in[3];
    const float* conv2_w   = (const float*)d_in[4];
    const float* conv2_b   = (const float*)d_in[5];
    const float* conv3_w   = (const float*)d_in[6];
    const float* conv3_b   = (const float*)d_in[7];
    const float* embed_w   = (const float*)d_in[8];
    const float* embed_b   = (const float*)d_in[9];
    const float* embed_ln_g= (const float*)d_in[10];
    const float* embed_ln_b= (const float*)d_in[11];
    const float* ln_att_g  = (const float*)d_in[12];
    const float* ln_att_b  = (const float*)d_in[13];
    const float* att_decay = (const float*)d_in[14];
    const float* att_first = (const float*)d_in[15];
    const float* att_mix_k = (const float*)d_in[16];
    const float* att_mix_v = (const float*)d_in[17];
    const float* att_mix_r = (const float*)d_in[18];
    const float* att_wk    = (const float*)d_in[19];
    const float* att_wv    = (const float*)d_in[20];
    const float* att_wr    = (const float*)d_in[21];
    const float* att_wo    = (const float*)d_in[22];
    const float* ln_ffn_g  = (const float*)d_in[23];
    const float* ln_ffn_b  = (const float*)d_in[24];
    const float* ffn_mix_k = (const float*)d_in[25];
    const float* ffn_mix_r = (const float*)d_in[26];
    const float* ffn_wk    = (const float*)d_in[27];
    const float* ffn_wv    = (const float*)d_in[28];
    const float* ffn_wr    = (const float*)d_in[29];
    const float* final_ln_g= (const float*)d_in[30];
    const float* final_ln_b= (const float*)d_in[31];

    // ---- workspace layout (MiB offsets, ~183 MiB) ----
    // 0..16 h | 16..32 xn / wkv states | 32..40 rwkvb
    // 40..64 xkvr (xf aliases) | 64..112 kvrb | 112..144 kkb
    // conv overlay (fp8): c1b 40..60 | c2b(halo) 80..91.1 | zpg 103 |
    //                     c3b 104..124
    // weights: attT 144..150 | attTo 150..152 | ffnT 152..162 | ffnTv 162..170
    //          embT(fp8) 170..175 | c2wb 180.. | c3wb 180.3..
    char* wsb = (char*)d_ws;
    float* h     = (float*)(wsb);
    float* xn    = (float*)(wsb + (16LL << 20));
    float* sloc  = (float*)(wsb + (16LL << 20));   // [3][WC][4096] f32 (3MB)
    float* sinc  = (float*)(wsb + (20LL << 20));   // [3][WC][4096] f32 (3MB)
    bf16*  rwkvb = (bf16*) (wsb + (32LL << 20));
    bf16*  xkvr  = (bf16*) (wsb + (40LL << 20));   // [3][8192][512] bf16
    bf16*  xf    = xkvr;                           // [2][8192][512] bf16 (ffn)
    float* kvrb  = (float*)(wsb + (64LL << 20));   // [3][8192][512] f32
    bf16*  kkb   = (bf16*) (wsb + (112LL << 20));  // [8192][2048] bf16
    unsigned char* c1b  = (unsigned char*)(wsb + (40LL << 20));  // (2,2048,40,128) fp8
    unsigned char* c2b  = (unsigned char*)(wsb + (80LL << 20));  // (2,1026,22,256) fp8
    unsigned char* zpg  = (unsigned char*)(wsb + (103LL << 20)); // 4KB zero page
    unsigned char* c3b  = (unsigned char*)(wsb + (104LL << 20)); // (2048,10240) fp8
    bf16*  attT  = (bf16*) (wsb + (144LL << 20));  // 4 x [1536][512] (k,v,r)
    bf16*  attTo = (bf16*) (wsb + (150LL << 20));  // 4 x [512][512]  (wo)
    bf16*  ffnT  = (bf16*) (wsb + (152LL << 20));  // 4 x [2560][512] (wk|wr)
    bf16*  ffnTv = (bf16*) (wsb + (162LL << 20));  // 4 x [512][2048]
    unsigned char* embT = (unsigned char*)(wsb + (170LL << 20)); // [512][10240] fp8
    unsigned char* c2wb = (unsigned char*)(wsb + (180LL << 20)); // 256 x 1152 fp8
    unsigned char* c3wb = (unsigned char*)(wsb + (180LL << 20) + 294912); // 512x2304 fp8

    const size_t MD = 8192LL * 512;

    // ---- weight prep
    transpose_k<<<dim3(16, 16, 4), 256, 0, stream>>>(att_wk, attT, 512, 512, 786432);
    transpose_k<<<dim3(16, 16, 4), 256, 0, stream>>>(att_wv, attT + 262144, 512, 512, 786432);
    transpose_k<<<dim3(16, 16, 4), 256, 0, stream>>>(att_wr, attT + 524288, 512, 512, 786432);
    transpose_k<<<dim3(16, 16, 4), 256, 0, stream>>>(att_wo, attTo, 512, 512, 262144);
    transpose_k<<<dim3(64, 16, 4), 256, 0, stream>>>(ffn_wk, ffnT, 512, 2048, 1310720);
    transpose_k<<<dim3(16, 16, 4), 256, 0, stream>>>(ffn_wr, ffnT + 1048576, 512, 512, 1310720);
    transpose_k<<<dim3(16, 64, 4), 256, 0, stream>>>(ffn_wv, ffnTv, 2048, 512, 1048576);
    transpose8_k<<<dim3(16, 320), 256, 0, stream>>>(embed_w, embT, 10240, 512);
    reorder_w8_k<<<1152, 256, 0, stream>>>(conv2_w, c2wb, 256, 128);
    reorder_w8_k<<<4608, 256, 0, stream>>>(conv3_w, c3wb, 512, 256);
    hipMemsetAsync(xn, 0, 16LL << 20, stream);
    hipMemsetAsync(c2b, 0, 2LL * 1026 * 22 * 256, stream);
    hipMemsetAsync(zpg, 0, 4096, stream);

    // ---- conv frontend + embed (fp8 path), 2 batches per chunk
    for (int chunk = 0; chunk < 4; chunk++) {
        int b0 = chunk * 2;
        conv1_k<<<640, 256, 0, stream>>>(x + (size_t)b0 * 327680, conv1_w, conv1_b, c1b);
        gemm_k<128, B_CONV, EP_CONV_CL, 0, 2048, 40, 2, 128, 0, 1><<<dim3(320, 2), 256, 0, stream>>>(
            c2wb, zpg, c1b, nullptr, c2b, conv2_b, nullptr,
            256, 40960, 1152, 1152, 0.0625f);
        gemm_k<128, B_CONV, EP_CONV_T, 0, 1024, 20, 1, 256, 1, 1><<<dim3(320, 4), 256, 0, stream>>>(
            c3wb, nullptr, c2b, nullptr, c3b, conv3_b, nullptr,
            512, 40960, 2304, 2304, 0.0625f);
        gemm_k<64, B_T, EP_ATOMIC, 0, 0, 0, 0, 0, 0, 1><<<dim3(4, 32, 4), 256, 0, stream>>>(
            c3b, embT, nullptr, xn + (size_t)b0 * 1024 * 512, nullptr, embed_b, nullptr,
            2048, 512, 10240, 2560, 0.015625f);
    }
    ln_k<<<2048, 256, 0, stream>>>(xn, h, embed_ln_g, embed_ln_b, 8192);

    // ---- 4 RWKV blocks (bf16 GEMMs)
    for (int i = 0; i < 4; i++) {
        lnmix_k<3><<<2048, 256, 0, stream>>>(h, ln_att_g + i * 512, ln_att_b + i * 512,
                                             att_mix_k + i * 512, att_mix_v + i * 512,
                                             att_mix_r + i * 512,
                                             xkvr, xkvr + MD, xkvr + 2 * MD);
        gemm_k<64, B_T, EP_KVR, 9, 0, 0, 0, 0, 0, 0><<<dim3(12, 128), 256, 0, stream>>>(
            xkvr, attT + (size_t)i * 786432, nullptr, kvrb, nullptr, nullptr, nullptr,
            8192, 1536, 512, 512, 1.f);
        wkv_loc_k<<<1024, 256, 0, stream>>>(kvrb, kvrb + MD, sloc, att_decay + i * 512);
        wkv_comb_k<<<16, 256, 0, stream>>>(sloc, sinc, att_decay + i * 512);
        wkv_out_k<<<1024, 256, 0, stream>>>(kvrb, kvrb + MD, kvrb + 2 * MD, rwkvb,
                                            sinc, att_decay + i * 512, att_first + i * 512);
        gemm_k<64, B_T, EP_ADD, 0, 0, 0, 0, 0, 0, 0><<<dim3(4, 128), 256, 0, stream>>>(
            rwkvb, attTo + (size_t)i * 262144, nullptr, h, nullptr, nullptr, nullptr,
            8192, 512, 512, 512, 1.f);
        lnmix_k<2><<<2048, 256, 0, stream>>>(h, ln_ffn_g + i * 512, ln_ffn_b + i * 512,
                                             ffn_mix_k + i * 512, nullptr,
                                             ffn_mix_r + i * 512,
                                             xf, nullptr, xf + MD);
        gemm_k<64, B_T, EP_FFN, 11, 0, 0, 0, 0, 0, 0><<<dim3(20, 128), 256, 0, stream>>>(
            xf, ffnT + (size_t)i * 1310720, nullptr, kvrb + 2 * MD, kkb, nullptr, nullptr,
            8192, 2560, 512, 512, 1.f);
        gemm_k<64, B_T, EP_ADDMUL, 0, 0, 0, 0, 0, 0, 0><<<dim3(4, 128), 256, 0, stream>>>(
            kkb, ffnTv + (size_t)i * 1048576, nullptr, h, nullptr, nullptr, kvrb + 2 * MD,
            8192, 512, 2048, 2048, 1.f);
    }

    // ---- final LN straight into d_out, then olens
    ln_k<<<2048, 256, 0, stream>>>(h, (float*)d_out, final_ln_g, final_ln_b, 8192);
    olens_k<<<1, 64, 0, stream>>>(x_len, (float*)d_out + 4194304);
}

// Round 9
// 1644.875 us; speedup vs baseline: 1.6908x; 1.1313x over previous
//
#include <hip/hip_runtime.h>
#include <hip/hip_bf16.h>
#include <hip/hip_fp8.h>

typedef __hip_bfloat16 bf16;
typedef __bf16 v8bf __attribute__((ext_vector_type(8)));
typedef float v4f __attribute__((ext_vector_type(4)));
typedef unsigned short u16x8 __attribute__((ext_vector_type(8)));

// ---------------------------------------------------------------------------
//   x: (8,4096,80) -> conv1(1->128,s2) -> (8,2048,40,128)   [channel-last fp8]
//   -> conv2(128->256,s2) -> halo (8,1026,22,256) fp8
//   -> conv3(256->512,s1) -> tokens (8,1024,10240) fp8
//   -> embed GEMM fp8 (split-K, atomic) -> 4 RWKV blocks (bf16) -> final LN
// GEMM core: TM x 128 tile, 64 BYTES of K per phase (bf16 BK=32, fp8 BK=64),
// 3-buffer counted-vmcnt pipeline (T3+T4). fp8 BK=64 halves the phase count
// vs r8 (barrier overhead was ~860cy/phase, the limiter) and makes staging
// geometry IDENTICAL to bf16: 4 threads/row, 16B chunks, source-chunk XOR
// (tid&3)^((tid>>3)&3) (T2 both-sides swizzle). Reads undo it:
//   bf16: 16B at (lq ^ ((lr>>1)&3))*16        (r7-verified, conflicts=0)
//   fp8 : 8B at ((kk*4+lq) ^ (((lr>>1)&3)<<1))*8  (r8's 2-value XOR was wrong)
// Weights pre-scaled (x16 conv, x64 embed); epilogue multiplies 1/scale.
// WKV: 3-pass chunked associative scan (C=64 chunks of T=16).
// ---------------------------------------------------------------------------

constexpr int B_T = 0, B_CONV = 1;
constexpr int EP_CONV_CL = 0, EP_CONV_T = 1, EP_ATOMIC = 2, EP_KVR = 3,
              EP_ADD = 4, EP_FFN = 5, EP_ADDMUL = 6;

constexpr int WC = 64;          // wkv chunks per sequence
constexpr int WT = 1024 / WC;   // 16 steps per chunk
constexpr int WPLANE = WC * 4096;  // 262144 states per plane

static __device__ __forceinline__ unsigned short f2b(float f) {
    return __builtin_bit_cast(unsigned short, __float2bfloat16(f));
}
static __device__ __forceinline__ unsigned char f2e4(float f) {
    __hip_fp8_e4m3 q(f);
    return (unsigned char)q.__x;
}

// global -> LDS async copy, 16B per lane. LDS dest must be the wave-uniform
// base; HW writes lane i at base + i*16.
static __device__ __forceinline__ void gld16(const unsigned char* g,
                                             unsigned char* l) {
    __builtin_amdgcn_global_load_lds(
        (__attribute__((address_space(1))) void*)g,
        (__attribute__((address_space(3))) void*)l, 16, 0, 0);
}

// ---------------------------------------------------------------------------
// MFMA GEMM: C[M,N] = A[M,K] * B[K,N]. A [M][K]; B [N][K] (B_T) or
// channel-last im2col gather (B_CONV; HALO=1 -> zero-padded halo buffer;
// HALO=0 -> OOB lanes read zero page Bw). ASH>0: A += (n0>>ASH)*M*K.
// K-phase = 64 bytes/row both dtypes. Loads/wave/stage L = TM/64 + 2.
// Steady wait vmcnt(2L); tail peels vmcnt(L), vmcnt(0).
// ---------------------------------------------------------------------------
template <int TM, int BL, int EPM, int ASH, int TIN, int FIN, int STRIDE,
          int ICN, int HALO, int F8>
__global__ __launch_bounds__(256) void gemm_k(
    const void* __restrict__ Av, const void* __restrict__ Bwv,
    const void* __restrict__ Bactv,
    float* __restrict__ C, void* __restrict__ Cbv,
    const float* __restrict__ bias, const float* __restrict__ mul,
    int M, int N, int K, int KLEN, float wsc)
{
    constexpr int MI = TM / 32;
    constexpr int ESZ = F8 ? 1 : 2;
    constexpr int BKe = 64 / ESZ;          // K-elements per phase (64B/row)
    __shared__ __align__(16) unsigned char As[3][TM * 64];
    __shared__ __align__(16) unsigned char Bs[3][128 * 64];
    const unsigned char* A    = (const unsigned char*)Av;
    const unsigned char* Bw   = (const unsigned char*)Bwv;
    const unsigned char* Bact = (const unsigned char*)Bactv;
    const int tid = threadIdx.x;
    const int n0 = blockIdx.x * 128;
    const int m0 = blockIdx.y * TM;
    const int kbase = blockIdx.z * KLEN;
    const int wave = tid >> 6, lane = tid & 63;
    const int wr = wave >> 1, wc = wave & 1;
    const int lq = lane >> 4, lr = lane & 15;

    if constexpr (ASH > 0) A += (size_t)(n0 >> ASH) * M * K * ESZ;

    v4f acc[MI][4];
#pragma unroll
    for (int i = 0; i < MI; i++)
#pragma unroll
        for (int j = 0; j < 4; j++) acc[i][j] = v4f{0.f, 0.f, 0.f, 0.f};

    // staging geometry (both dtypes): 4 threads/row, row = c*64 + (tid>>2);
    // lane fetches global 16B-chunk (tid&3)^((tid>>3)&3) of its 64B row slice.
    const int sr = tid >> 2;
    const int swzB = ((tid & 3) ^ ((tid >> 3) & 3)) * 16;   // byte off in row

    const unsigned char* aP[TM / 64];
#pragma unroll
    for (int c = 0; c < TM / 64; c++)
        aP[c] = A + (size_t)(m0 + c * 64 + sr) * K * ESZ + swzB;

    const unsigned char* bP[2];
    int cb0 = 0, cb1 = 0, cto0 = 0, cto1 = 0, cfo0 = 0, cfo1 = 0;
    if constexpr (BL == B_T) {
#pragma unroll
        for (int c = 0; c < 2; c++)
            bP[c] = Bw + (size_t)(n0 + c * 64 + sr) * K * ESZ + swzB;
    } else {
        {
            int n = n0 + sr;
            cb0 = n / 20480;
            int s = n - cb0 * 20480;
            cto0 = s / 20;
            cfo0 = s - cto0 * 20;
        }
        {
            int n = n0 + 64 + sr;
            cb1 = n / 20480;
            int s = n - cb1 * 20480;
            cto1 = s / 20;
            cfo1 = s - cto1 * 20;
        }
        if constexpr (HALO) {
            bP[0] = Bact + ((((size_t)cb0 * 1026 + cto0) * 22 + cfo0) * 256) * ESZ + swzB;
            bP[1] = Bact + ((((size_t)cb1 * 1026 + cto1) * 22 + cfo1) * 256) * ESZ + swzB;
        }
    }

    auto stageA = [&](int k0, int sel) {
#pragma unroll
        for (int c = 0; c < TM / 64; c++)
            gld16(aP[c] + (size_t)k0 * ESZ, &As[sel][c * 4096 + wave * 1024]);
    };
    auto stageB = [&](int k0, int sel) {
        if constexpr (BL == B_T) {
#pragma unroll
            for (int c = 0; c < 2; c++)
                gld16(bP[c] + (size_t)k0 * ESZ, &Bs[sel][c * 4096 + wave * 1024]);
        } else {
            int kg = k0 / ICN;             // kt*3+kf (BKe never crosses a tap)
            int ic0 = k0 - kg * ICN;       // channel base of this K-slice
            int kt = kg / 3, kf = kg - kt * 3;
            if constexpr (HALO) {          // conv3: bP already carries swzB
                gld16(bP[0] + ((size_t)(kt * 22 + kf) * 256 + ic0) * ESZ,
                      &Bs[sel][wave * 1024]);
                gld16(bP[1] + ((size_t)(kt * 22 + kf) * 256 + ic0) * ESZ,
                      &Bs[sel][4096 + wave * 1024]);
            } else {                       // conv2: OOB -> zero page (Bw)
                int ti0 = cto0 * STRIDE - 1 + kt, fi0 = cfo0 * STRIDE - 1 + kf;
                const unsigned char* s0 =
                    ((unsigned)ti0 < (unsigned)TIN && (unsigned)fi0 < (unsigned)FIN)
                    ? Bact + ((((size_t)cb0 * TIN + ti0) * FIN + fi0) * ICN + ic0) * ESZ + swzB
                    : Bw;
                gld16(s0, &Bs[sel][wave * 1024]);
                int ti1 = cto1 * STRIDE - 1 + kt, fi1 = cfo1 * STRIDE - 1 + kf;
                const unsigned char* s1 =
                    ((unsigned)ti1 < (unsigned)TIN && (unsigned)fi1 < (unsigned)FIN)
                    ? Bact + ((((size_t)cb1 * TIN + ti1) * FIN + fi1) * ICN + ic0) * ESZ + swzB
                    : Bw;
                gld16(s1, &Bs[sel][4096 + wave * 1024]);
            }
        }
    };
    auto compute = [&](int sel) {
        if constexpr (F8) {
            const int so2 = ((lr >> 1) & 3) << 1;
            long fa8[MI][2], fb8[4][2];
#pragma unroll
            for (int mi = 0; mi < MI; mi++)
#pragma unroll
                for (int kk = 0; kk < 2; kk++)
                    fa8[mi][kk] = *(const long*)&As[sel][
                        (wr * (TM / 2) + mi * 16 + lr) * 64 +
                        (((kk << 2) | lq) ^ so2) * 8];
#pragma unroll
            for (int ni = 0; ni < 4; ni++)
#pragma unroll
                for (int kk = 0; kk < 2; kk++)
                    fb8[ni][kk] = *(const long*)&Bs[sel][
                        (wc * 64 + ni * 16 + lr) * 64 +
                        (((kk << 2) | lq) ^ so2) * 8];
#pragma unroll
            for (int mi = 0; mi < MI; mi++)
#pragma unroll
                for (int ni = 0; ni < 4; ni++) {
                    acc[mi][ni] = __builtin_amdgcn_mfma_f32_16x16x32_fp8_fp8(
                        fa8[mi][0], fb8[ni][0], acc[mi][ni], 0, 0, 0);
                    acc[mi][ni] = __builtin_amdgcn_mfma_f32_16x16x32_fp8_fp8(
                        fa8[mi][1], fb8[ni][1], acc[mi][ni], 0, 0, 0);
                }
        } else {
            const int lsw = (lr >> 1) & 3;
            v8bf fa[MI], fb[4];
#pragma unroll
            for (int mi = 0; mi < MI; mi++)
                fa[mi] = *(const v8bf*)&As[sel][(wr * (TM / 2) + mi * 16 + lr) * 64 +
                                               (lq ^ lsw) * 16];
#pragma unroll
            for (int ni = 0; ni < 4; ni++)
                fb[ni] = *(const v8bf*)&Bs[sel][(wc * 64 + ni * 16 + lr) * 64 +
                                               (lq ^ lsw) * 16];
#pragma unroll
            for (int mi = 0; mi < MI; mi++)
#pragma unroll
                for (int ni = 0; ni < 4; ni++)
                    acc[mi][ni] = __builtin_amdgcn_mfma_f32_16x16x32_bf16(
                        fa[mi], fb[ni], acc[mi][ni], 0, 0, 0);
        }
    };

    // ---- 3-buffer counted-vmcnt pipeline. NT >= 3 for all instances.
    const int NT = KLEN / BKe;
    stageA(kbase, 0);            stageB(kbase, 0);
    stageA(kbase + BKe, 1);      stageB(kbase + BKe, 1);
    stageA(kbase + 2 * BKe, 2);  stageB(kbase + 2 * BKe, 2);
    int sel = 0;
    for (int t = 0; t < NT - 2; ++t) {
        if constexpr (TM == 128)
            asm volatile("s_waitcnt vmcnt(8)" ::: "memory");
        else
            asm volatile("s_waitcnt vmcnt(6)" ::: "memory");
        __builtin_amdgcn_sched_barrier(0);
        __builtin_amdgcn_s_barrier();     // all waves' stage(t) landed
        compute(sel);
        __builtin_amdgcn_s_barrier();     // all reads of buf[sel] done
        if (t + 3 < NT) {
            int k0 = kbase + (t + 3) * BKe;
            stageA(k0, sel);
            stageB(k0, sel);
        }
        sel = sel == 2 ? 0 : sel + 1;
    }
    // t = NT-2: two stages outstanding -> wait for the older one
    if constexpr (TM == 128)
        asm volatile("s_waitcnt vmcnt(4)" ::: "memory");
    else
        asm volatile("s_waitcnt vmcnt(3)" ::: "memory");
    __builtin_amdgcn_sched_barrier(0);
    __builtin_amdgcn_s_barrier();
    compute(sel);
    sel = sel == 2 ? 0 : sel + 1;
    // t = NT-1: last stage
    asm volatile("s_waitcnt vmcnt(0)" ::: "memory");
    __builtin_amdgcn_sched_barrier(0);
    __builtin_amdgcn_s_barrier();
    compute(sel);

    // ---- epilogue
#pragma unroll
    for (int mi = 0; mi < MI; mi++) {
#pragma unroll
        for (int ni = 0; ni < 4; ni++) {
#pragma unroll
            for (int reg = 0; reg < 4; reg++) {
                int row = m0 + wr * (TM / 2) + mi * 16 + lq * 4 + reg;
                int col = n0 + wc * 64 + ni * 16 + lr;
                float v = acc[mi][ni][reg] * wsc;
                if constexpr (EPM == EP_CONV_CL) {
                    v += bias[row];
                    v = v > 0.f ? v : 0.f;
                    int b = col / 20480;
                    int s = col - b * 20480;
                    int t = s / 20, fo = s - t * 20;
                    ((unsigned char*)Cbv)[(((size_t)b * 1026 + t + 1) * 22 + fo + 1) * 256 + row] =
                        f2e4(v);
                } else if constexpr (EPM == EP_CONV_T) {
                    v += bias[row];
                    v = v > 0.f ? v : 0.f;
                    int b = col / 20480;
                    int s = col - b * 20480;
                    int t = s / 20, fo = s - t * 20;
                    ((unsigned char*)Cbv)[(size_t)(b * 1024 + t) * 10240 + row * 20 + fo] =
                        f2e4(v);
                } else if constexpr (EPM == EP_ATOMIC) {
                    float add = (blockIdx.z == 0) ? bias[col] : 0.f;
                    atomicAdd(&C[(size_t)row * N + col], v + add);
                } else if constexpr (EPM == EP_KVR) {
                    int seg = col >> 9;     // 0=k,1=v,2=r (uniform per block)
                    if (seg == 2) v = 1.f / (1.f + __expf(-v));
                    C[(size_t)seg * M * 512 + (size_t)row * 512 + (col & 511)] = v;
                } else if constexpr (EPM == EP_ADD) {
                    C[(size_t)row * N + col] += v;
                } else if constexpr (EPM == EP_FFN) {
                    if (col < 2048) {       // wk branch: sqrelu -> bf16 kkb
                        float t = v > 0.f ? v : 0.f;
                        ((bf16*)Cbv)[(size_t)row * 2048 + col] = __float2bfloat16(t * t);
                    } else {                // wr branch: sigmoid -> f32 rb
                        C[(size_t)row * 512 + (col - 2048)] = 1.f / (1.f + __expf(-v));
                    }
                } else if constexpr (EPM == EP_ADDMUL) {
                    size_t idx = (size_t)row * N + col;
                    C[idx] += mul[idx] * v;
                }
            }
        }
    }
}

// ---------------------------------------------------------------------------
// Prep: conv weight OIHW f32 -> fp8 e4m3 [oc][(kt*3+kf)*IC + ic], scaled x16
// ---------------------------------------------------------------------------
__global__ __launch_bounds__(256) void reorder_w8_k(const float* __restrict__ in,
                                                    unsigned char* __restrict__ out,
                                                    int OC, int IC)
{
    int idx = blockIdx.x * 256 + threadIdx.x;
    if (idx >= OC * IC * 9) return;
    int oc = idx / (IC * 9);
    int r = idx - oc * (IC * 9);
    int g = r / IC;
    int ic = r - g * IC;
    out[idx] = f2e4(in[((size_t)oc * IC + ic) * 9 + g] * 16.f);
}

// ---------------------------------------------------------------------------
// Prep: f32 [K][N] -> bf16 [N][K]; z: in stride K*N, out stride ozs
// ---------------------------------------------------------------------------
__global__ __launch_bounds__(256) void transpose_k(const float* __restrict__ in,
                                                   bf16* __restrict__ out,
                                                   int K, int N, size_t ozs)
{
    __shared__ float t[32][33];
    const float* pin = in + (size_t)blockIdx.z * K * N;
    bf16* pout = out + (size_t)blockIdx.z * ozs;
    int n0 = blockIdx.x * 32, k0 = blockIdx.y * 32;
    int tx = threadIdx.x & 31, ty = threadIdx.x >> 5;
#pragma unroll
    for (int i = 0; i < 32; i += 8)
        t[ty + i][tx] = pin[(size_t)(k0 + ty + i) * N + n0 + tx];
    __syncthreads();
#pragma unroll
    for (int i = 0; i < 32; i += 8)
        pout[(size_t)(n0 + ty + i) * K + k0 + tx] = __float2bfloat16(t[tx][ty + i]);
}

// ---------------------------------------------------------------------------
// Prep: f32 [K][N] -> fp8 e4m3 [N][K], scaled x64 (embed weights, sigma~0.01)
// ---------------------------------------------------------------------------
__global__ __launch_bounds__(256) void transpose8_k(const float* __restrict__ in,
                                                    unsigned char* __restrict__ out,
                                                    int K, int N)
{
    __shared__ float t[32][33];
    int n0 = blockIdx.x * 32, k0 = blockIdx.y * 32;
    int tx = threadIdx.x & 31, ty = threadIdx.x >> 5;
#pragma unroll
    for (int i = 0; i < 32; i += 8)
        t[ty + i][tx] = in[(size_t)(k0 + ty + i) * N + n0 + tx];
    __syncthreads();
#pragma unroll
    for (int i = 0; i < 32; i += 8)
        out[(size_t)(n0 + ty + i) * K + k0 + tx] = f2e4(t[tx][ty + i] * 64.f);
}

// ---------------------------------------------------------------------------
// conv1 for a 2-batch chunk: 1 input channel, direct, channel-last fp8 out.
// ---------------------------------------------------------------------------
__global__ __launch_bounds__(256) void conv1_k(
    const float* __restrict__ x, const float* __restrict__ w,
    const float* __restrict__ bias, unsigned char* __restrict__ out)
{
    __shared__ float ws_[128 * 9];
    __shared__ float bs_[128];
    const int tid = threadIdx.x;
    for (int i = tid; i < 128 * 9; i += 256) ws_[i] = w[i];
    if (tid < 128) bs_[tid] = bias[tid];
    __syncthreads();

    int idx = blockIdx.x * 256 + tid;  // 2*2048*40
    int f = idx % 40;
    int t = (idx / 40) & 2047;
    int b = idx / 81920;

    float xin[9];
#pragma unroll
    for (int kt = 0; kt < 3; kt++)
#pragma unroll
        for (int kf = 0; kf < 3; kf++) {
            int ti = 2 * t - 1 + kt, fi = 2 * f - 1 + kf;
            float v = 0.f;
            if ((unsigned)ti < 4096u && (unsigned)fi < 80u)
                v = x[(size_t)b * 327680 + (size_t)ti * 80 + fi];
            xin[kt * 3 + kf] = v;
        }
    unsigned char* outu = out + (size_t)idx * 128;
#pragma unroll
    for (int oc8 = 0; oc8 < 16; oc8++) {
        unsigned char pk[8];
#pragma unroll
        for (int j = 0; j < 8; j++) {
            int oc = oc8 * 8 + j;
            float a = bs_[oc];
#pragma unroll
            for (int q = 0; q < 9; q++) a += ws_[oc * 9 + q] * xin[q];
            a = a > 0.f ? a : 0.f;
            pk[j] = f2e4(a);
        }
        *(unsigned long long*)&outu[oc8 * 8] = *(unsigned long long*)pk;
    }
}

// ---------------------------------------------------------------------------
// LayerNorm over D=512, one wave per row (4 rows / block)
// ---------------------------------------------------------------------------
__global__ __launch_bounds__(256) void ln_k(
    const float* __restrict__ in, float* __restrict__ out,
    const float* __restrict__ g, const float* __restrict__ b, int M)
{
    int wave = threadIdx.x >> 6;
    int lane = threadIdx.x & 63;
    int row = blockIdx.x * 4 + wave;
    if (row >= M) return;
    const float* p = in + (size_t)row * 512;
    float v[8], s = 0.f, sq = 0.f;
#pragma unroll
    for (int i = 0; i < 8; i++) {
        v[i] = p[lane + i * 64];
        s += v[i];
        sq += v[i] * v[i];
    }
#pragma unroll
    for (int o = 32; o > 0; o >>= 1) {
        s += __shfl_xor(s, o, 64);
        sq += __shfl_xor(sq, o, 64);
    }
    float mean = s * (1.f / 512.f);
    float var = sq * (1.f / 512.f) - mean * mean;
    float r = rsqrtf(var + 1e-5f);
    float* q = out + (size_t)row * 512;
#pragma unroll
    for (int i = 0; i < 8; i++) {
        int d = lane + i * 64;
        q[d] = (v[i] - mean) * r * g[d] + b[d];
    }
}

// ---------------------------------------------------------------------------
// Fused LN + token-shift mix -> bf16 operands. One wave per row; the wave
// also recomputes the predecessor row's LN (exact same f32 math). Lane owns
// 8 contiguous dims (16-B loads/stores). NOUT=3 (att) or 2 (ffn).
// ---------------------------------------------------------------------------
template <int NOUT>
__global__ __launch_bounds__(256) void lnmix_k(
    const float* __restrict__ hb, const float* __restrict__ g,
    const float* __restrict__ b, const float* __restrict__ mk,
    const float* __restrict__ mv, const float* __restrict__ mr,
    bf16* __restrict__ ok, bf16* __restrict__ ov, bf16* __restrict__ orr)
{
    int wave = threadIdx.x >> 6, lane = threadIdx.x & 63;
    int row = blockIdx.x * 4 + wave;     // 8192 rows
    int u = row & 1023;
    int d0 = lane * 8;
    const float* pc = hb + (size_t)row * 512 + d0;

    float vc[8], vp[8];
    *(float4*)&vc[0] = *(const float4*)pc;
    *(float4*)&vc[4] = *(const float4*)(pc + 4);
    float s = 0.f, sq = 0.f, sp = 0.f, sqp = 0.f;
#pragma unroll
    for (int i = 0; i < 8; i++) { s += vc[i]; sq += vc[i] * vc[i]; }
    if (u) {
        *(float4*)&vp[0] = *(const float4*)(pc - 512);
        *(float4*)&vp[4] = *(const float4*)(pc - 508);
#pragma unroll
        for (int i = 0; i < 8; i++) { sp += vp[i]; sqp += vp[i] * vp[i]; }
    } else {
#pragma unroll
        for (int i = 0; i < 8; i++) vp[i] = 0.f;
    }
#pragma unroll
    for (int o = 32; o > 0; o >>= 1) {
        s += __shfl_xor(s, o, 64);
        sq += __shfl_xor(sq, o, 64);
        sp += __shfl_xor(sp, o, 64);
        sqp += __shfl_xor(sqp, o, 64);
    }
    float mc = s * (1.f / 512.f);
    float rc = rsqrtf(sq * (1.f / 512.f) - mc * mc + 1e-5f);
    float mp = sp * (1.f / 512.f);
    float rp = rsqrtf(sqp * (1.f / 512.f) - mp * mp + 1e-5f);

    float gv[8], bv[8], xc[8], xp[8];
    *(float4*)&gv[0] = *(const float4*)(g + d0);
    *(float4*)&gv[4] = *(const float4*)(g + d0 + 4);
    *(float4*)&bv[0] = *(const float4*)(b + d0);
    *(float4*)&bv[4] = *(const float4*)(b + d0 + 4);
#pragma unroll
    for (int i = 0; i < 8; i++) {
        xc[i] = (vc[i] - mc) * rc * gv[i] + bv[i];
        xp[i] = u ? (vp[i] - mp) * rp * gv[i] + bv[i] : 0.f;
    }

    size_t ob = (size_t)row * 512 + d0;
    float a[8];
    unsigned short o16[8];
    *(float4*)&a[0] = *(const float4*)(mk + d0);
    *(float4*)&a[4] = *(const float4*)(mk + d0 + 4);
#pragma unroll
    for (int i = 0; i < 8; i++) o16[i] = f2b(xc[i] * a[i] + xp[i] * (1.f - a[i]));
    *(u16x8*)((unsigned short*)ok + ob) = *(u16x8*)o16;
    if constexpr (NOUT == 3) {
        *(float4*)&a[0] = *(const float4*)(mv + d0);
        *(float4*)&a[4] = *(const float4*)(mv + d0 + 4);
#pragma unroll
        for (int i = 0; i < 8; i++) o16[i] = f2b(xc[i] * a[i] + xp[i] * (1.f - a[i]));
        *(u16x8*)((unsigned short*)ov + ob) = *(u16x8*)o16;
    }
    *(float4*)&a[0] = *(const float4*)(mr + d0);
    *(float4*)&a[4] = *(const float4*)(mr + d0 + 4);
#pragma unroll
    for (int i = 0; i < 8; i++) o16[i] = f2b(xc[i] * a[i] + xp[i] * (1.f - a[i]));
    *(u16x8*)((unsigned short*)orr + ob) = *(u16x8*)o16;
}

// ---------------------------------------------------------------------------
// WKV chunked scan. State (aa,bb,pp): num = aa*e^pp, den = bb*e^pp.
// Chunk combine: S_out = e^{w*WT} * S_in + S_local (associative).
// ---------------------------------------------------------------------------
__global__ __launch_bounds__(256) void wkv_loc_k(
    const float* __restrict__ kbuf, const float* __restrict__ vbuf,
    float* __restrict__ st, const float* __restrict__ decay)
{
    int idx = blockIdx.x * 256 + threadIdx.x;   // [c][b][d]
    int bd = idx & 4095;
    int c = idx >> 12;
    int d = bd & 511;
    int b = bd >> 9;
    float w = -__expf(decay[d]);
    float aa = 0.f, bb = 0.f, pp = -1e38f;
    size_t base = ((size_t)b * 1024 + c * WT) * 512 + d;
#pragma unroll
    for (int s = 0; s < WT; s++) {
        float kt = kbuf[base + (size_t)s * 512];
        float vt = vbuf[base + (size_t)s * 512];
        float ww2 = pp + w;
        float p2 = ww2 > kt ? ww2 : kt;
        float e1 = __expf(ww2 - p2), e2 = __expf(kt - p2);
        aa = e1 * aa + e2 * vt;
        bb = e1 * bb + e2;
        pp = p2;
    }
    st[idx] = aa;
    st[WPLANE + idx] = bb;
    st[2 * WPLANE + idx] = pp;
}

__global__ __launch_bounds__(256) void wkv_comb_k(
    const float* __restrict__ loc, float* __restrict__ inc,
    const float* __restrict__ decay)
{
    int bd = blockIdx.x * 256 + threadIdx.x;  // 4096
    int d = bd & 511;
    float wT = -__expf(decay[d]) * (float)WT;
    float aa = 0.f, bb = 0.f, pp = -1e38f;
    for (int c = 0; c < WC; c++) {
        int i = c * 4096 + bd;
        inc[i] = aa;
        inc[WPLANE + i] = bb;
        inc[2 * WPLANE + i] = pp;
        float la = loc[i], lb = loc[WPLANE + i], lp = loc[2 * WPLANE + i];
        float pd = pp + wT;
        float p2 = pd > lp ? pd : lp;
        float e1 = __expf(pd - p2), e2 = __expf(lp - p2);
        aa = e1 * aa + e2 * la;
        bb = e1 * bb + e2 * lb;
        pp = p2;
    }
}

__global__ __launch_bounds__(256) void wkv_out_k(
    const float* __restrict__ kbuf, const float* __restrict__ vbuf,
    const float* __restrict__ rbuf, bf16* __restrict__ outbuf,
    const float* __restrict__ inc,
    const float* __restrict__ decay, const float* __restrict__ first)
{
    int idx = blockIdx.x * 256 + threadIdx.x;
    int bd = idx & 4095;
    int c = idx >> 12;
    int d = bd & 511;
    int b = bd >> 9;
    float w = -__expf(decay[d]);
    float u = first[d];
    float aa = inc[idx], bb = inc[WPLANE + idx], pp = inc[2 * WPLANE + idx];
    size_t base = ((size_t)b * 1024 + c * WT) * 512 + d;
#pragma unroll
    for (int s = 0; s < WT; s++) {
        float kt = kbuf[base + (size_t)s * 512];
        float vt = vbuf[base + (size_t)s * 512];
        float rt = rbuf[base + (size_t)s * 512];
        float ww = u + kt;
        float p = pp > ww ? pp : ww;
        float e1 = __expf(pp - p), e2 = __expf(ww - p);
        float out = (e1 * aa + e2 * vt) / (e1 * bb + e2);
        outbuf[base + (size_t)s * 512] = __float2bfloat16(rt * out);
        float ww2 = pp + w;
        float p2 = ww2 > kt ? ww2 : kt;
        e1 = __expf(ww2 - p2);
        e2 = __expf(kt - p2);
        aa = e1 * aa + e2 * vt;
        bb = e1 * bb + e2;
        pp = p2;
    }
}

__global__ void olens_k(const int* __restrict__ x_len, float* __restrict__ out)
{
    int i = threadIdx.x;
    if (i < 8) {
        int l1 = (x_len[i] - 1) / 2 + 1;
        int ol = (l1 - 1) / 2 + 1;
        out[i] = (float)ol;
    }
}

// ---------------------------------------------------------------------------
extern "C" void kernel_launch(void* const* d_in, const int* in_sizes, int n_in,
                              void* d_out, int out_size, void* d_ws, size_t ws_size,
                              hipStream_t stream)
{
    (void)in_sizes; (void)n_in; (void)out_size; (void)ws_size;
    const float* x         = (const float*)d_in[0];
    const int*   x_len     = (const int*)d_in[1];
    const float* conv1_w   = (const float*)d_in[2];
    const float* conv1_b   = (const float*)d_in[3];
    const float* conv2_w   = (const float*)d_in[4];
    const float* conv2_b   = (const float*)d_in[5];
    const float* conv3_w   = (const float*)d_in[6];
    const float* conv3_b   = (const float*)d_in[7];
    const float* embed_w   = (const float*)d_in[8];
    const float* embed_b   = (const float*)d_in[9];
    const float* embed_ln_g= (const float*)d_in[10];
    const float* embed_ln_b= (const float*)d_in[11];
    const float* ln_att_g  = (const float*)d_in[12];
    const float* ln_att_b  = (const float*)d_in[13];
    const float* att_decay = (const float*)d_in[14];
    const float* att_first = (const float*)d_in[15];
    const float* att_mix_k = (const float*)d_in[16];
    const float* att_mix_v = (const float*)d_in[17];
    const float* att_mix_r = (const float*)d_in[18];
    const float* att_wk    = (const float*)d_in[19];
    const float* att_wv    = (const float*)d_in[20];
    const float* att_wr    = (const float*)d_in[21];
    const float* att_wo    = (const float*)d_in[22];
    const float* ln_ffn_g  = (const float*)d_in[23];
    const float* ln_ffn_b  = (const float*)d_in[24];
    const float* ffn_mix_k = (const float*)d_in[25];
    const float* ffn_mix_r = (const float*)d_in[26];
    const float* ffn_wk    = (const float*)d_in[27];
    const float* ffn_wv    = (const float*)d_in[28];
    const float* ffn_wr    = (const float*)d_in[29];
    const float* final_ln_g= (const float*)d_in[30];
    const float* final_ln_b= (const float*)d_in[31];

    // ---- workspace layout (MiB offsets, ~183 MiB) ----
    char* wsb = (char*)d_ws;
    float* h     = (float*)(wsb);
    float* xn    = (float*)(wsb + (16LL << 20));
    float* sloc  = (float*)(wsb + (16LL << 20));   // [3][WC][4096] f32 (3MB)
    float* sinc  = (float*)(wsb + (20LL << 20));   // [3][WC][4096] f32 (3MB)
    bf16*  rwkvb = (bf16*) (wsb + (32LL << 20));
    bf16*  xkvr  = (bf16*) (wsb + (40LL << 20));   // [3][8192][512] bf16
    bf16*  xf    = xkvr;                           // [2][8192][512] bf16 (ffn)
    float* kvrb  = (float*)(wsb + (64LL << 20));   // [3][8192][512] f32
    bf16*  kkb   = (bf16*) (wsb + (112LL << 20));  // [8192][2048] bf16
    unsigned char* c1b  = (unsigned char*)(wsb + (40LL << 20));  // (2,2048,40,128) fp8
    unsigned char* c2b  = (unsigned char*)(wsb + (80LL << 20));  // (2,1026,22,256) fp8
    unsigned char* zpg  = (unsigned char*)(wsb + (103LL << 20)); // 4KB zero page
    unsigned char* c3b  = (unsigned char*)(wsb + (104LL << 20)); // (2048,10240) fp8
    bf16*  attT  = (bf16*) (wsb + (144LL << 20));  // 4 x [1536][512] (k,v,r)
    bf16*  attTo = (bf16*) (wsb + (150LL << 20));  // 4 x [512][512]  (wo)
    bf16*  ffnT  = (bf16*) (wsb + (152LL << 20));  // 4 x [2560][512] (wk|wr)
    bf16*  ffnTv = (bf16*) (wsb + (162LL << 20));  // 4 x [512][2048]
    unsigned char* embT = (unsigned char*)(wsb + (170LL << 20)); // [512][10240] fp8
    unsigned char* c2wb = (unsigned char*)(wsb + (180LL << 20)); // 256 x 1152 fp8
    unsigned char* c3wb = (unsigned char*)(wsb + (180LL << 20) + 294912); // 512x2304 fp8

    const size_t MD = 8192LL * 512;

    // ---- weight prep
    transpose_k<<<dim3(16, 16, 4), 256, 0, stream>>>(att_wk, attT, 512, 512, 786432);
    transpose_k<<<dim3(16, 16, 4), 256, 0, stream>>>(att_wv, attT + 262144, 512, 512, 786432);
    transpose_k<<<dim3(16, 16, 4), 256, 0, stream>>>(att_wr, attT + 524288, 512, 512, 786432);
    transpose_k<<<dim3(16, 16, 4), 256, 0, stream>>>(att_wo, attTo, 512, 512, 262144);
    transpose_k<<<dim3(64, 16, 4), 256, 0, stream>>>(ffn_wk, ffnT, 512, 2048, 1310720);
    transpose_k<<<dim3(16, 16, 4), 256, 0, stream>>>(ffn_wr, ffnT + 1048576, 512, 512, 1310720);
    transpose_k<<<dim3(16, 64, 4), 256, 0, stream>>>(ffn_wv, ffnTv, 2048, 512, 1048576);
    transpose8_k<<<dim3(16, 320), 256, 0, stream>>>(embed_w, embT, 10240, 512);
    reorder_w8_k<<<1152, 256, 0, stream>>>(conv2_w, c2wb, 256, 128);
    reorder_w8_k<<<4608, 256, 0, stream>>>(conv3_w, c3wb, 512, 256);
    hipMemsetAsync(xn, 0, 16LL << 20, stream);
    hipMemsetAsync(c2b, 0, 2LL * 1026 * 22 * 256, stream);
    hipMemsetAsync(zpg, 0, 4096, stream);

    // ---- conv frontend + embed (fp8 path, BK=64), 2 batches per chunk
    for (int chunk = 0; chunk < 4; chunk++) {
        int b0 = chunk * 2;
        conv1_k<<<640, 256, 0, stream>>>(x + (size_t)b0 * 327680, conv1_w, conv1_b, c1b);
        gemm_k<128, B_CONV, EP_CONV_CL, 0, 2048, 40, 2, 128, 0, 1><<<dim3(320, 2), 256, 0, stream>>>(
            c2wb, zpg, c1b, nullptr, c2b, conv2_b, nullptr,
            256, 40960, 1152, 1152, 0.0625f);
        gemm_k<128, B_CONV, EP_CONV_T, 0, 1024, 20, 1, 256, 1, 1><<<dim3(320, 4), 256, 0, stream>>>(
            c3wb, nullptr, c2b, nullptr, c3b, conv3_b, nullptr,
            512, 40960, 2304, 2304, 0.0625f);
        gemm_k<64, B_T, EP_ATOMIC, 0, 0, 0, 0, 0, 0, 1><<<dim3(4, 32, 4), 256, 0, stream>>>(
            c3b, embT, nullptr, xn + (size_t)b0 * 1024 * 512, nullptr, embed_b, nullptr,
            2048, 512, 10240, 2560, 0.015625f);
    }
    ln_k<<<2048, 256, 0, stream>>>(xn, h, embed_ln_g, embed_ln_b, 8192);

    // ---- 4 RWKV blocks (bf16 GEMMs)
    for (int i = 0; i < 4; i++) {
        lnmix_k<3><<<2048, 256, 0, stream>>>(h, ln_att_g + i * 512, ln_att_b + i * 512,
                                             att_mix_k + i * 512, att_mix_v + i * 512,
                                             att_mix_r + i * 512,
                                             xkvr, xkvr + MD, xkvr + 2 * MD);
        gemm_k<64, B_T, EP_KVR, 9, 0, 0, 0, 0, 0, 0><<<dim3(12, 128), 256, 0, stream>>>(
            xkvr, attT + (size_t)i * 786432, nullptr, kvrb, nullptr, nullptr, nullptr,
            8192, 1536, 512, 512, 1.f);
        wkv_loc_k<<<1024, 256, 0, stream>>>(kvrb, kvrb + MD, sloc, att_decay + i * 512);
        wkv_comb_k<<<16, 256, 0, stream>>>(sloc, sinc, att_decay + i * 512);
        wkv_out_k<<<1024, 256, 0, stream>>>(kvrb, kvrb + MD, kvrb + 2 * MD, rwkvb,
                                            sinc, att_decay + i * 512, att_first + i * 512);
        gemm_k<64, B_T, EP_ADD, 0, 0, 0, 0, 0, 0, 0><<<dim3(4, 128), 256, 0, stream>>>(
            rwkvb, attTo + (size_t)i * 262144, nullptr, h, nullptr, nullptr, nullptr,
            8192, 512, 512, 512, 1.f);
        lnmix_k<2><<<2048, 256, 0, stream>>>(h, ln_ffn_g + i * 512, ln_ffn_b + i * 512,
                                             ffn_mix_k + i * 512, nullptr,
                                             ffn_mix_r + i * 512,
                                             xf, nullptr, xf + MD);
        gemm_k<64, B_T, EP_FFN, 11, 0, 0, 0, 0, 0, 0><<<dim3(20, 128), 256, 0, stream>>>(
            xf, ffnT + (size_t)i * 1310720, nullptr, kvrb + 2 * MD, kkb, nullptr, nullptr,
            8192, 2560, 512, 512, 1.f);
        gemm_k<64, B_T, EP_ADDMUL, 0, 0, 0, 0, 0, 0, 0><<<dim3(4, 128), 256, 0, stream>>>(
            kkb, ffnTv + (size_t)i * 1048576, nullptr, h, nullptr, nullptr, kvrb + 2 * MD,
            8192, 512, 2048, 2048, 1.f);
    }

    // ---- final LN straight into d_out, then olens
    ln_k<<<2048, 256, 0, stream>>>(h, (float*)d_out, final_ln_g, final_ln_b, 8192);
    olens_k<<<1, 64, 0, stream>>>(x_len, (float*)d_out + 4194304);
}

// Round 10
// 1518.674 us; speedup vs baseline: 1.8313x; 1.0831x over previous
//
#include <hip/hip_runtime.h>
#include <hip/hip_bf16.h>
#include <hip/hip_fp8.h>

typedef __hip_bfloat16 bf16;
typedef __bf16 v8bf __attribute__((ext_vector_type(8)));
typedef float v4f __attribute__((ext_vector_type(4)));
typedef unsigned short u16x8 __attribute__((ext_vector_type(8)));

// ---------------------------------------------------------------------------
//   x: (8,4096,80) -> conv1(1->128,s2) -> (8,2048,40,128)   [channel-last fp8]
//   -> conv2(128->256,s2) -> halo (8,1026,22,256) fp8
//   -> conv3(256->512,s1) -> tokens (8,1024,10240) fp8
//   -> embed GEMM fp8 (split-K, atomic) -> 4 RWKV blocks (fp8 GEMMs) -> LN
// GEMM core: TM x 128 tile, 64 BYTES of K per phase (bf16 BK=32, fp8 BK=64),
// 3-buffer counted-vmcnt pipeline (T3+T4). Staging both dtypes: 4 thr/row,
// 16B chunks, source-chunk XOR fT (T2 both-sides swizzle); reads undo it.
//   bf16: fT=(sr>>1)&3, read slot (lq^((lr>>1)&3))*16      [r7: conflicts=0]
//   fp8 : fT=((sr>>1)&3)^((sr>>3)&1)  [r10: r9's f had period 8 -> rows
//         lr/lr+8 aliased -> 4-way b64 conflicts (1.18e7). Row-bit3 XOR
//         gives 2 rows per f-value per parity class -> 2-way (free).]
//         read l8 = g8 ^ (f(lr)<<1), f(lr)=((lr>>1)&3)^((lr>>3)&1).
// fp8 everywhere: conv chain + embed + ALL transformer GEMMs (kvr/wo/ffn/
// ffnv). Weights pre-scaled x16 (x64 embed); epilogue multiplies 1/scale.
// Activations O(1) (LN'd / sigmoid / relu^2-bounded) -> direct e4m3.
// WKV: 3-pass chunked associative scan (C=64 chunks of T=16), f32.
// ---------------------------------------------------------------------------

constexpr int B_T = 0, B_CONV = 1;
constexpr int EP_CONV_CL = 0, EP_CONV_T = 1, EP_ATOMIC = 2, EP_KVR = 3,
              EP_ADD = 4, EP_FFN = 5, EP_ADDMUL = 6;

constexpr int WC = 64;          // wkv chunks per sequence
constexpr int WT = 1024 / WC;   // 16 steps per chunk
constexpr int WPLANE = WC * 4096;  // 262144 states per plane

static __device__ __forceinline__ unsigned short f2b(float f) {
    return __builtin_bit_cast(unsigned short, __float2bfloat16(f));
}
static __device__ __forceinline__ unsigned char f2e4(float f) {
    __hip_fp8_e4m3 q(f);
    return (unsigned char)q.__x;
}

// global -> LDS async copy, 16B per lane. LDS dest must be the wave-uniform
// base; HW writes lane i at base + i*16.
static __device__ __forceinline__ void gld16(const unsigned char* g,
                                             unsigned char* l) {
    __builtin_amdgcn_global_load_lds(
        (__attribute__((address_space(1))) void*)g,
        (__attribute__((address_space(3))) void*)l, 16, 0, 0);
}

// ---------------------------------------------------------------------------
// MFMA GEMM: C[M,N] = A[M,K] * B[K,N]. A [M][K]; B [N][K] (B_T) or
// channel-last im2col gather (B_CONV; HALO=1 -> zero-padded halo buffer;
// HALO=0 -> OOB lanes read zero page Bw). ASH>0: A += (n0>>ASH)*M*K.
// K-phase = 64 bytes/row both dtypes. Loads/wave/stage L = TM/64 + 2.
// Steady wait vmcnt(2L); tail peels vmcnt(L), vmcnt(0).
// ---------------------------------------------------------------------------
template <int TM, int BL, int EPM, int ASH, int TIN, int FIN, int STRIDE,
          int ICN, int HALO, int F8>
__global__ __launch_bounds__(256) void gemm_k(
    const void* __restrict__ Av, const void* __restrict__ Bwv,
    const void* __restrict__ Bactv,
    float* __restrict__ C, void* __restrict__ Cbv,
    const float* __restrict__ bias, const float* __restrict__ mul,
    int M, int N, int K, int KLEN, float wsc)
{
    constexpr int MI = TM / 32;
    constexpr int ESZ = F8 ? 1 : 2;
    constexpr int BKe = 64 / ESZ;          // K-elements per phase (64B/row)
    __shared__ __align__(16) unsigned char As[3][TM * 64];
    __shared__ __align__(16) unsigned char Bs[3][128 * 64];
    const unsigned char* A    = (const unsigned char*)Av;
    const unsigned char* Bw   = (const unsigned char*)Bwv;
    const unsigned char* Bact = (const unsigned char*)Bactv;
    const int tid = threadIdx.x;
    const int n0 = blockIdx.x * 128;
    const int m0 = blockIdx.y * TM;
    const int kbase = blockIdx.z * KLEN;
    const int wave = tid >> 6, lane = tid & 63;
    const int wr = wave >> 1, wc = wave & 1;
    const int lq = lane >> 4, lr = lane & 15;

    if constexpr (ASH > 0) A += (size_t)(n0 >> ASH) * M * K * ESZ;

    v4f acc[MI][4];
#pragma unroll
    for (int i = 0; i < MI; i++)
#pragma unroll
        for (int j = 0; j < 4; j++) acc[i][j] = v4f{0.f, 0.f, 0.f, 0.f};

    // staging geometry (both dtypes): 4 threads/row, row = c*64 + (tid>>2);
    // lane fetches global 16B-chunk (tid&3)^fT of its 64B row slice.
    const int sr = tid >> 2;
    int fT;
    if constexpr (F8) fT = (((tid >> 3) & 3) ^ ((tid >> 5) & 1));
    else              fT = ((tid >> 3) & 3);
    const int swzB = ((tid & 3) ^ fT) * 16;   // byte offset in 64B row

    const unsigned char* aP[TM / 64];
#pragma unroll
    for (int c = 0; c < TM / 64; c++)
        aP[c] = A + (size_t)(m0 + c * 64 + sr) * K * ESZ + swzB;

    const unsigned char* bP[2];
    int cb0 = 0, cb1 = 0, cto0 = 0, cto1 = 0, cfo0 = 0, cfo1 = 0;
    if constexpr (BL == B_T) {
#pragma unroll
        for (int c = 0; c < 2; c++)
            bP[c] = Bw + (size_t)(n0 + c * 64 + sr) * K * ESZ + swzB;
    } else {
        {
            int n = n0 + sr;
            cb0 = n / 20480;
            int s = n - cb0 * 20480;
            cto0 = s / 20;
            cfo0 = s - cto0 * 20;
        }
        {
            int n = n0 + 64 + sr;
            cb1 = n / 20480;
            int s = n - cb1 * 20480;
            cto1 = s / 20;
            cfo1 = s - cto1 * 20;
        }
        if constexpr (HALO) {
            bP[0] = Bact + ((((size_t)cb0 * 1026 + cto0) * 22 + cfo0) * 256) * ESZ + swzB;
            bP[1] = Bact + ((((size_t)cb1 * 1026 + cto1) * 22 + cfo1) * 256) * ESZ + swzB;
        }
    }

    auto stageA = [&](int k0, int sel) {
#pragma unroll
        for (int c = 0; c < TM / 64; c++)
            gld16(aP[c] + (size_t)k0 * ESZ, &As[sel][c * 4096 + wave * 1024]);
    };
    auto stageB = [&](int k0, int sel) {
        if constexpr (BL == B_T) {
#pragma unroll
            for (int c = 0; c < 2; c++)
                gld16(bP[c] + (size_t)k0 * ESZ, &Bs[sel][c * 4096 + wave * 1024]);
        } else {
            int kg = k0 / ICN;             // kt*3+kf (BKe never crosses a tap)
            int ic0 = k0 - kg * ICN;       // channel base of this K-slice
            int kt = kg / 3, kf = kg - kt * 3;
            if constexpr (HALO) {          // conv3: bP already carries swzB
                gld16(bP[0] + ((size_t)(kt * 22 + kf) * 256 + ic0) * ESZ,
                      &Bs[sel][wave * 1024]);
                gld16(bP[1] + ((size_t)(kt * 22 + kf) * 256 + ic0) * ESZ,
                      &Bs[sel][4096 + wave * 1024]);
            } else {                       // conv2: OOB -> zero page (Bw)
                int ti0 = cto0 * STRIDE - 1 + kt, fi0 = cfo0 * STRIDE - 1 + kf;
                const unsigned char* s0 =
                    ((unsigned)ti0 < (unsigned)TIN && (unsigned)fi0 < (unsigned)FIN)
                    ? Bact + ((((size_t)cb0 * TIN + ti0) * FIN + fi0) * ICN + ic0) * ESZ + swzB
                    : Bw;
                gld16(s0, &Bs[sel][wave * 1024]);
                int ti1 = cto1 * STRIDE - 1 + kt, fi1 = cfo1 * STRIDE - 1 + kf;
                const unsigned char* s1 =
                    ((unsigned)ti1 < (unsigned)TIN && (unsigned)fi1 < (unsigned)FIN)
                    ? Bact + ((((size_t)cb1 * TIN + ti1) * FIN + fi1) * ICN + ic0) * ESZ + swzB
                    : Bw;
                gld16(s1, &Bs[sel][4096 + wave * 1024]);
            }
        }
    };
    auto compute = [&](int sel) {
        if constexpr (F8) {
            const int so2 = ((((lr >> 1) & 3) ^ ((lr >> 3) & 1)) << 1);
            long fa8[MI][2], fb8[4][2];
#pragma unroll
            for (int mi = 0; mi < MI; mi++)
#pragma unroll
                for (int kk = 0; kk < 2; kk++)
                    fa8[mi][kk] = *(const long*)&As[sel][
                        (wr * (TM / 2) + mi * 16 + lr) * 64 +
                        (((kk << 2) | lq) ^ so2) * 8];
#pragma unroll
            for (int ni = 0; ni < 4; ni++)
#pragma unroll
                for (int kk = 0; kk < 2; kk++)
                    fb8[ni][kk] = *(const long*)&Bs[sel][
                        (wc * 64 + ni * 16 + lr) * 64 +
                        (((kk << 2) | lq) ^ so2) * 8];
#pragma unroll
            for (int mi = 0; mi < MI; mi++)
#pragma unroll
                for (int ni = 0; ni < 4; ni++) {
                    acc[mi][ni] = __builtin_amdgcn_mfma_f32_16x16x32_fp8_fp8(
                        fa8[mi][0], fb8[ni][0], acc[mi][ni], 0, 0, 0);
                    acc[mi][ni] = __builtin_amdgcn_mfma_f32_16x16x32_fp8_fp8(
                        fa8[mi][1], fb8[ni][1], acc[mi][ni], 0, 0, 0);
                }
        } else {
            const int lsw = (lr >> 1) & 3;
            v8bf fa[MI], fb[4];
#pragma unroll
            for (int mi = 0; mi < MI; mi++)
                fa[mi] = *(const v8bf*)&As[sel][(wr * (TM / 2) + mi * 16 + lr) * 64 +
                                               (lq ^ lsw) * 16];
#pragma unroll
            for (int ni = 0; ni < 4; ni++)
                fb[ni] = *(const v8bf*)&Bs[sel][(wc * 64 + ni * 16 + lr) * 64 +
                                               (lq ^ lsw) * 16];
#pragma unroll
            for (int mi = 0; mi < MI; mi++)
#pragma unroll
                for (int ni = 0; ni < 4; ni++)
                    acc[mi][ni] = __builtin_amdgcn_mfma_f32_16x16x32_bf16(
                        fa[mi], fb[ni], acc[mi][ni], 0, 0, 0);
        }
    };

    // ---- 3-buffer counted-vmcnt pipeline. NT >= 3 for all instances.
    const int NT = KLEN / BKe;
    stageA(kbase, 0);            stageB(kbase, 0);
    stageA(kbase + BKe, 1);      stageB(kbase + BKe, 1);
    stageA(kbase + 2 * BKe, 2);  stageB(kbase + 2 * BKe, 2);
    int sel = 0;
    for (int t = 0; t < NT - 2; ++t) {
        if constexpr (TM == 128)
            asm volatile("s_waitcnt vmcnt(8)" ::: "memory");
        else
            asm volatile("s_waitcnt vmcnt(6)" ::: "memory");
        __builtin_amdgcn_sched_barrier(0);
        __builtin_amdgcn_s_barrier();     // all waves' stage(t) landed
        compute(sel);
        __builtin_amdgcn_s_barrier();     // all reads of buf[sel] done
        if (t + 3 < NT) {
            int k0 = kbase + (t + 3) * BKe;
            stageA(k0, sel);
            stageB(k0, sel);
        }
        sel = sel == 2 ? 0 : sel + 1;
    }
    // t = NT-2: two stages outstanding -> wait for the older one
    if constexpr (TM == 128)
        asm volatile("s_waitcnt vmcnt(4)" ::: "memory");
    else
        asm volatile("s_waitcnt vmcnt(3)" ::: "memory");
    __builtin_amdgcn_sched_barrier(0);
    __builtin_amdgcn_s_barrier();
    compute(sel);
    sel = sel == 2 ? 0 : sel + 1;
    // t = NT-1: last stage
    asm volatile("s_waitcnt vmcnt(0)" ::: "memory");
    __builtin_amdgcn_sched_barrier(0);
    __builtin_amdgcn_s_barrier();
    compute(sel);

    // ---- epilogue
#pragma unroll
    for (int mi = 0; mi < MI; mi++) {
#pragma unroll
        for (int ni = 0; ni < 4; ni++) {
#pragma unroll
            for (int reg = 0; reg < 4; reg++) {
                int row = m0 + wr * (TM / 2) + mi * 16 + lq * 4 + reg;
                int col = n0 + wc * 64 + ni * 16 + lr;
                float v = acc[mi][ni][reg] * wsc;
                if constexpr (EPM == EP_CONV_CL) {
                    v += bias[row];
                    v = v > 0.f ? v : 0.f;
                    int b = col / 20480;
                    int s = col - b * 20480;
                    int t = s / 20, fo = s - t * 20;
                    ((unsigned char*)Cbv)[(((size_t)b * 1026 + t + 1) * 22 + fo + 1) * 256 + row] =
                        f2e4(v);
                } else if constexpr (EPM == EP_CONV_T) {
                    v += bias[row];
                    v = v > 0.f ? v : 0.f;
                    int b = col / 20480;
                    int s = col - b * 20480;
                    int t = s / 20, fo = s - t * 20;
                    ((unsigned char*)Cbv)[(size_t)(b * 1024 + t) * 10240 + row * 20 + fo] =
                        f2e4(v);
                } else if constexpr (EPM == EP_ATOMIC) {
                    float add = (blockIdx.z == 0) ? bias[col] : 0.f;
                    atomicAdd(&C[(size_t)row * N + col], v + add);
                } else if constexpr (EPM == EP_KVR) {
                    int seg = col >> 9;     // 0=k,1=v,2=r (uniform per block)
                    if (seg == 2) v = 1.f / (1.f + __expf(-v));
                    C[(size_t)seg * M * 512 + (size_t)row * 512 + (col & 511)] = v;
                } else if constexpr (EPM == EP_ADD) {
                    C[(size_t)row * N + col] += v;
                } else if constexpr (EPM == EP_FFN) {
                    if (col < 2048) {       // wk branch: sqrelu -> fp8 kkb
                        float t = v > 0.f ? v : 0.f;
                        ((unsigned char*)Cbv)[(size_t)row * 2048 + col] = f2e4(t * t);
                    } else {                // wr branch: sigmoid -> f32 rb
                        C[(size_t)row * 512 + (col - 2048)] = 1.f / (1.f + __expf(-v));
                    }
                } else if constexpr (EPM == EP_ADDMUL) {
                    size_t idx = (size_t)row * N + col;
                    C[idx] += mul[idx] * v;
                }
            }
        }
    }
}

// ---------------------------------------------------------------------------
// Prep: conv weight OIHW f32 -> fp8 e4m3 [oc][(kt*3+kf)*IC + ic], scaled x16
// ---------------------------------------------------------------------------
__global__ __launch_bounds__(256) void reorder_w8_k(const float* __restrict__ in,
                                                    unsigned char* __restrict__ out,
                                                    int OC, int IC)
{
    int idx = blockIdx.x * 256 + threadIdx.x;
    if (idx >= OC * IC * 9) return;
    int oc = idx / (IC * 9);
    int r = idx - oc * (IC * 9);
    int g = r / IC;
    int ic = r - g * IC;
    out[idx] = f2e4(in[((size_t)oc * IC + ic) * 9 + g] * 16.f);
}

// ---------------------------------------------------------------------------
// Prep: f32 [K][N] -> fp8 e4m3 [N][K] scaled; z: in stride izs, out stride ozs
// ---------------------------------------------------------------------------
__global__ __launch_bounds__(256) void transpose8_k(const float* __restrict__ in,
                                                    unsigned char* __restrict__ out,
                                                    int K, int N, size_t izs,
                                                    size_t ozs, float sc)
{
    __shared__ float t[32][33];
    const float* pin = in + (size_t)blockIdx.z * izs;
    unsigned char* pout = out + (size_t)blockIdx.z * ozs;
    int n0 = blockIdx.x * 32, k0 = blockIdx.y * 32;
    int tx = threadIdx.x & 31, ty = threadIdx.x >> 5;
#pragma unroll
    for (int i = 0; i < 32; i += 8)
        t[ty + i][tx] = pin[(size_t)(k0 + ty + i) * N + n0 + tx];
    __syncthreads();
#pragma unroll
    for (int i = 0; i < 32; i += 8)
        pout[(size_t)(n0 + ty + i) * K + k0 + tx] = f2e4(t[tx][ty + i] * sc);
}

// ---------------------------------------------------------------------------
// conv1 for a 2-batch chunk: 1 input channel, direct, channel-last fp8 out.
// ---------------------------------------------------------------------------
__global__ __launch_bounds__(256) void conv1_k(
    const float* __restrict__ x, const float* __restrict__ w,
    const float* __restrict__ bias, unsigned char* __restrict__ out)
{
    __shared__ float ws_[128 * 9];
    __shared__ float bs_[128];
    const int tid = threadIdx.x;
    for (int i = tid; i < 128 * 9; i += 256) ws_[i] = w[i];
    if (tid < 128) bs_[tid] = bias[tid];
    __syncthreads();

    int idx = blockIdx.x * 256 + tid;  // 2*2048*40
    int f = idx % 40;
    int t = (idx / 40) & 2047;
    int b = idx / 81920;

    float xin[9];
#pragma unroll
    for (int kt = 0; kt < 3; kt++)
#pragma unroll
        for (int kf = 0; kf < 3; kf++) {
            int ti = 2 * t - 1 + kt, fi = 2 * f - 1 + kf;
            float v = 0.f;
            if ((unsigned)ti < 4096u && (unsigned)fi < 80u)
                v = x[(size_t)b * 327680 + (size_t)ti * 80 + fi];
            xin[kt * 3 + kf] = v;
        }
    unsigned char* outu = out + (size_t)idx * 128;
#pragma unroll
    for (int oc8 = 0; oc8 < 16; oc8++) {
        unsigned char pk[8];
#pragma unroll
        for (int j = 0; j < 8; j++) {
            int oc = oc8 * 8 + j;
            float a = bs_[oc];
#pragma unroll
            for (int q = 0; q < 9; q++) a += ws_[oc * 9 + q] * xin[q];
            a = a > 0.f ? a : 0.f;
            pk[j] = f2e4(a);
        }
        *(unsigned long long*)&outu[oc8 * 8] = *(unsigned long long*)pk;
    }
}

// ---------------------------------------------------------------------------
// LayerNorm over D=512, one wave per row (4 rows / block)
// ---------------------------------------------------------------------------
__global__ __launch_bounds__(256) void ln_k(
    const float* __restrict__ in, float* __restrict__ out,
    const float* __restrict__ g, const float* __restrict__ b, int M)
{
    int wave = threadIdx.x >> 6;
    int lane = threadIdx.x & 63;
    int row = blockIdx.x * 4 + wave;
    if (row >= M) return;
    const float* p = in + (size_t)row * 512;
    float v[8], s = 0.f, sq = 0.f;
#pragma unroll
    for (int i = 0; i < 8; i++) {
        v[i] = p[lane + i * 64];
        s += v[i];
        sq += v[i] * v[i];
    }
#pragma unroll
    for (int o = 32; o > 0; o >>= 1) {
        s += __shfl_xor(s, o, 64);
        sq += __shfl_xor(sq, o, 64);
    }
    float mean = s * (1.f / 512.f);
    float var = sq * (1.f / 512.f) - mean * mean;
    float r = rsqrtf(var + 1e-5f);
    float* q = out + (size_t)row * 512;
#pragma unroll
    for (int i = 0; i < 8; i++) {
        int d = lane + i * 64;
        q[d] = (v[i] - mean) * r * g[d] + b[d];
    }
}

// ---------------------------------------------------------------------------
// Fused LN + token-shift mix -> fp8 operands. One wave per row; the wave
// also recomputes the predecessor row's LN (exact same f32 math). Lane owns
// 8 contiguous dims (8B fp8 stores). NOUT=3 (att) or 2 (ffn).
// ---------------------------------------------------------------------------
template <int NOUT>
__global__ __launch_bounds__(256) void lnmix_k(
    const float* __restrict__ hb, const float* __restrict__ g,
    const float* __restrict__ b, const float* __restrict__ mk,
    const float* __restrict__ mv, const float* __restrict__ mr,
    unsigned char* __restrict__ ok, unsigned char* __restrict__ ov,
    unsigned char* __restrict__ orr)
{
    int wave = threadIdx.x >> 6, lane = threadIdx.x & 63;
    int row = blockIdx.x * 4 + wave;     // 8192 rows
    int u = row & 1023;
    int d0 = lane * 8;
    const float* pc = hb + (size_t)row * 512 + d0;

    float vc[8], vp[8];
    *(float4*)&vc[0] = *(const float4*)pc;
    *(float4*)&vc[4] = *(const float4*)(pc + 4);
    float s = 0.f, sq = 0.f, sp = 0.f, sqp = 0.f;
#pragma unroll
    for (int i = 0; i < 8; i++) { s += vc[i]; sq += vc[i] * vc[i]; }
    if (u) {
        *(float4*)&vp[0] = *(const float4*)(pc - 512);
        *(float4*)&vp[4] = *(const float4*)(pc - 508);
#pragma unroll
        for (int i = 0; i < 8; i++) { sp += vp[i]; sqp += vp[i] * vp[i]; }
    } else {
#pragma unroll
        for (int i = 0; i < 8; i++) vp[i] = 0.f;
    }
#pragma unroll
    for (int o = 32; o > 0; o >>= 1) {
        s += __shfl_xor(s, o, 64);
        sq += __shfl_xor(sq, o, 64);
        sp += __shfl_xor(sp, o, 64);
        sqp += __shfl_xor(sqp, o, 64);
    }
    float mc = s * (1.f / 512.f);
    float rc = rsqrtf(sq * (1.f / 512.f) - mc * mc + 1e-5f);
    float mp = sp * (1.f / 512.f);
    float rp = rsqrtf(sqp * (1.f / 512.f) - mp * mp + 1e-5f);

    float gv[8], bv[8], xc[8], xp[8];
    *(float4*)&gv[0] = *(const float4*)(g + d0);
    *(float4*)&gv[4] = *(const float4*)(g + d0 + 4);
    *(float4*)&bv[0] = *(const float4*)(b + d0);
    *(float4*)&bv[4] = *(const float4*)(b + d0 + 4);
#pragma unroll
    for (int i = 0; i < 8; i++) {
        xc[i] = (vc[i] - mc) * rc * gv[i] + bv[i];
        xp[i] = u ? (vp[i] - mp) * rp * gv[i] + bv[i] : 0.f;
    }

    size_t ob = (size_t)row * 512 + d0;
    float a[8];
    unsigned char o8[8];
    *(float4*)&a[0] = *(const float4*)(mk + d0);
    *(float4*)&a[4] = *(const float4*)(mk + d0 + 4);
#pragma unroll
    for (int i = 0; i < 8; i++) o8[i] = f2e4(xc[i] * a[i] + xp[i] * (1.f - a[i]));
    *(unsigned long long*)(ok + ob) = *(unsigned long long*)o8;
    if constexpr (NOUT == 3) {
        *(float4*)&a[0] = *(const float4*)(mv + d0);
        *(float4*)&a[4] = *(const float4*)(mv + d0 + 4);
#pragma unroll
        for (int i = 0; i < 8; i++) o8[i] = f2e4(xc[i] * a[i] + xp[i] * (1.f - a[i]));
        *(unsigned long long*)(ov + ob) = *(unsigned long long*)o8;
    }
    *(float4*)&a[0] = *(const float4*)(mr + d0);
    *(float4*)&a[4] = *(const float4*)(mr + d0 + 4);
#pragma unroll
    for (int i = 0; i < 8; i++) o8[i] = f2e4(xc[i] * a[i] + xp[i] * (1.f - a[i]));
    *(unsigned long long*)(orr + ob) = *(unsigned long long*)o8;
}

// ---------------------------------------------------------------------------
// WKV chunked scan. State (aa,bb,pp): num = aa*e^pp, den = bb*e^pp.
// Chunk combine: S_out = e^{w*WT} * S_in + S_local (associative).
// ---------------------------------------------------------------------------
__global__ __launch_bounds__(256) void wkv_loc_k(
    const float* __restrict__ kbuf, const float* __restrict__ vbuf,
    float* __restrict__ st, const float* __restrict__ decay)
{
    int idx = blockIdx.x * 256 + threadIdx.x;   // [c][b][d]
    int bd = idx & 4095;
    int c = idx >> 12;
    int d = bd & 511;
    int b = bd >> 9;
    float w = -__expf(decay[d]);
    float aa = 0.f, bb = 0.f, pp = -1e38f;
    size_t base = ((size_t)b * 1024 + c * WT) * 512 + d;
#pragma unroll
    for (int s = 0; s < WT; s++) {
        float kt = kbuf[base + (size_t)s * 512];
        float vt = vbuf[base + (size_t)s * 512];
        float ww2 = pp + w;
        float p2 = ww2 > kt ? ww2 : kt;
        float e1 = __expf(ww2 - p2), e2 = __expf(kt - p2);
        aa = e1 * aa + e2 * vt;
        bb = e1 * bb + e2;
        pp = p2;
    }
    st[idx] = aa;
    st[WPLANE + idx] = bb;
    st[2 * WPLANE + idx] = pp;
}

__global__ __launch_bounds__(256) void wkv_comb_k(
    const float* __restrict__ loc, float* __restrict__ inc,
    const float* __restrict__ decay)
{
    int bd = blockIdx.x * 256 + threadIdx.x;  // 4096
    int d = bd & 511;
    float wT = -__expf(decay[d]) * (float)WT;
    float aa = 0.f, bb = 0.f, pp = -1e38f;
    for (int c = 0; c < WC; c++) {
        int i = c * 4096 + bd;
        inc[i] = aa;
        inc[WPLANE + i] = bb;
        inc[2 * WPLANE + i] = pp;
        float la = loc[i], lb = loc[WPLANE + i], lp = loc[2 * WPLANE + i];
        float pd = pp + wT;
        float p2 = pd > lp ? pd : lp;
        float e1 = __expf(pd - p2), e2 = __expf(lp - p2);
        aa = e1 * aa + e2 * la;
        bb = e1 * bb + e2 * lb;
        pp = p2;
    }
}

__global__ __launch_bounds__(256) void wkv_out_k(
    const float* __restrict__ kbuf, const float* __restrict__ vbuf,
    const float* __restrict__ rbuf, unsigned char* __restrict__ outbuf,
    const float* __restrict__ inc,
    const float* __restrict__ decay, const float* __restrict__ first)
{
    int idx = blockIdx.x * 256 + threadIdx.x;
    int bd = idx & 4095;
    int c = idx >> 12;
    int d = bd & 511;
    int b = bd >> 9;
    float w = -__expf(decay[d]);
    float u = first[d];
    float aa = inc[idx], bb = inc[WPLANE + idx], pp = inc[2 * WPLANE + idx];
    size_t base = ((size_t)b * 1024 + c * WT) * 512 + d;
#pragma unroll
    for (int s = 0; s < WT; s++) {
        float kt = kbuf[base + (size_t)s * 512];
        float vt = vbuf[base + (size_t)s * 512];
        float rt = rbuf[base + (size_t)s * 512];
        float ww = u + kt;
        float p = pp > ww ? pp : ww;
        float e1 = __expf(pp - p), e2 = __expf(ww - p);
        float out = (e1 * aa + e2 * vt) / (e1 * bb + e2);
        outbuf[base + (size_t)s * 512] = f2e4(rt * out);
        float ww2 = pp + w;
        float p2 = ww2 > kt ? ww2 : kt;
        e1 = __expf(ww2 - p2);
        e2 = __expf(kt - p2);
        aa = e1 * aa + e2 * vt;
        bb = e1 * bb + e2;
        pp = p2;
    }
}

__global__ void olens_k(const int* __restrict__ x_len, float* __restrict__ out)
{
    int i = threadIdx.x;
    if (i < 8) {
        int l1 = (x_len[i] - 1) / 2 + 1;
        int ol = (l1 - 1) / 2 + 1;
        out[i] = (float)ol;
    }
}

// ---------------------------------------------------------------------------
extern "C" void kernel_launch(void* const* d_in, const int* in_sizes, int n_in,
                              void* d_out, int out_size, void* d_ws, size_t ws_size,
                              hipStream_t stream)
{
    (void)in_sizes; (void)n_in; (void)out_size; (void)ws_size;
    const float* x         = (const float*)d_in[0];
    const int*   x_len     = (const int*)d_in[1];
    const float* conv1_w   = (const float*)d_in[2];
    const float* conv1_b   = (const float*)d_in[3];
    const float* conv2_w   = (const float*)d_in[4];
    const float* conv2_b   = (const float*)d_in[5];
    const float* conv3_w   = (const float*)d_in[6];
    const float* conv3_b   = (const float*)d_in[7];
    const float* embed_w   = (const float*)d_in[8];
    const float* embed_b   = (const float*)d_in[9];
    const float* embed_ln_g= (const float*)d_in[10];
    const float* embed_ln_b= (const float*)d_in[11];
    const float* ln_att_g  = (const float*)d_in[12];
    const float* ln_att_b  = (const float*)d_in[13];
    const float* att_decay = (const float*)d_in[14];
    const float* att_first = (const float*)d_in[15];
    const float* att_mix_k = (const float*)d_in[16];
    const float* att_mix_v = (const float*)d_in[17];
    const float* att_mix_r = (const float*)d_in[18];
    const float* att_wk    = (const float*)d_in[19];
    const float* att_wv    = (const float*)d_in[20];
    const float* att_wr    = (const float*)d_in[21];
    const float* att_wo    = (const float*)d_in[22];
    const float* ln_ffn_g  = (const float*)d_in[23];
    const float* ln_ffn_b  = (const float*)d_in[24];
    const float* ffn_mix_k = (const float*)d_in[25];
    const float* ffn_mix_r = (const float*)d_in[26];
    const float* ffn_wk    = (const float*)d_in[27];
    const float* ffn_wv    = (const float*)d_in[28];
    const float* ffn_wr    = (const float*)d_in[29];
    const float* final_ln_g= (const float*)d_in[30];
    const float* final_ln_b= (const float*)d_in[31];

    // ---- workspace layout (MiB offsets) ----
    // 0..16 h | 16..32 xn / wkv states | 32..36 rwkv8 | 40..52 xkvr8 (xf8
    // aliases 40..48) | 64..112 kvrb f32 | 112..128 kkb8
    // conv overlay (fp8): c1b 40..60 | c2b(halo) 80..91.1 | zpg 103 | c3b 104..124
    // fp8 weights: attT8 144..147 | attTo8 150..151 | ffnT8 152..157 |
    //              ffnTv8 162..166 | embT8 170..175 | c2wb/c3wb 180..
    char* wsb = (char*)d_ws;
    float* h     = (float*)(wsb);
    float* xn    = (float*)(wsb + (16LL << 20));
    float* sloc  = (float*)(wsb + (16LL << 20));   // [3][WC][4096] f32 (3MB)
    float* sinc  = (float*)(wsb + (20LL << 20));   // [3][WC][4096] f32 (3MB)
    unsigned char* rwkv8 = (unsigned char*)(wsb + (32LL << 20)); // [8192][512] fp8
    unsigned char* xkvr8 = (unsigned char*)(wsb + (40LL << 20)); // [3][8192][512] fp8
    unsigned char* xf8   = xkvr8;                                // [2][8192][512] fp8
    float* kvrb  = (float*)(wsb + (64LL << 20));   // [3][8192][512] f32
    unsigned char* kkb8  = (unsigned char*)(wsb + (112LL << 20)); // [8192][2048] fp8
    unsigned char* c1b  = (unsigned char*)(wsb + (40LL << 20));  // (2,2048,40,128) fp8
    unsigned char* c2b  = (unsigned char*)(wsb + (80LL << 20));  // (2,1026,22,256) fp8
    unsigned char* zpg  = (unsigned char*)(wsb + (103LL << 20)); // 4KB zero page
    unsigned char* c3b  = (unsigned char*)(wsb + (104LL << 20)); // (2048,10240) fp8
    unsigned char* attT8  = (unsigned char*)(wsb + (144LL << 20)); // 4x[1536][512]
    unsigned char* attTo8 = (unsigned char*)(wsb + (150LL << 20)); // 4x[512][512]
    unsigned char* ffnT8  = (unsigned char*)(wsb + (152LL << 20)); // 4x[2560][512]
    unsigned char* ffnTv8 = (unsigned char*)(wsb + (162LL << 20)); // 4x[512][2048]
    unsigned char* embT8  = (unsigned char*)(wsb + (170LL << 20)); // [512][10240]
    unsigned char* c2wb = (unsigned char*)(wsb + (180LL << 20));   // 256 x 1152
    unsigned char* c3wb = (unsigned char*)(wsb + (180LL << 20) + 294912); // 512x2304

    const size_t MD  = 8192LL * 512;   // f32 plane stride (elements)
    const size_t MD8 = 8192LL * 512;   // fp8 plane stride (bytes)

    // ---- weight prep (all fp8, x16 scale; embed x64)
    transpose8_k<<<dim3(16, 16, 4), 256, 0, stream>>>(att_wk, attT8, 512, 512,
                                                      262144, 786432, 16.f);
    transpose8_k<<<dim3(16, 16, 4), 256, 0, stream>>>(att_wv, attT8 + 262144, 512, 512,
                                                      262144, 786432, 16.f);
    transpose8_k<<<dim3(16, 16, 4), 256, 0, stream>>>(att_wr, attT8 + 524288, 512, 512,
                                                      262144, 786432, 16.f);
    transpose8_k<<<dim3(16, 16, 4), 256, 0, stream>>>(att_wo, attTo8, 512, 512,
                                                      262144, 262144, 16.f);
    transpose8_k<<<dim3(64, 16, 4), 256, 0, stream>>>(ffn_wk, ffnT8, 512, 2048,
                                                      1048576, 1310720, 16.f);
    transpose8_k<<<dim3(16, 16, 4), 256, 0, stream>>>(ffn_wr, ffnT8 + 1048576, 512, 512,
                                                      262144, 1310720, 16.f);
    transpose8_k<<<dim3(16, 64, 4), 256, 0, stream>>>(ffn_wv, ffnTv8, 2048, 512,
                                                      1048576, 1048576, 16.f);
    transpose8_k<<<dim3(16, 320, 1), 256, 0, stream>>>(embed_w, embT8, 10240, 512,
                                                       0, 0, 64.f);
    reorder_w8_k<<<1152, 256, 0, stream>>>(conv2_w, c2wb, 256, 128);
    reorder_w8_k<<<4608, 256, 0, stream>>>(conv3_w, c3wb, 512, 256);
    hipMemsetAsync(xn, 0, 16LL << 20, stream);
    hipMemsetAsync(c2b, 0, 2LL * 1026 * 22 * 256, stream);
    hipMemsetAsync(zpg, 0, 4096, stream);

    // ---- conv frontend + embed (fp8, BK=64), 2 batches per chunk
    for (int chunk = 0; chunk < 4; chunk++) {
        int b0 = chunk * 2;
        conv1_k<<<640, 256, 0, stream>>>(x + (size_t)b0 * 327680, conv1_w, conv1_b, c1b);
        gemm_k<128, B_CONV, EP_CONV_CL, 0, 2048, 40, 2, 128, 0, 1><<<dim3(320, 2), 256, 0, stream>>>(
            c2wb, zpg, c1b, nullptr, c2b, conv2_b, nullptr,
            256, 40960, 1152, 1152, 0.0625f);
        gemm_k<128, B_CONV, EP_CONV_T, 0, 1024, 20, 1, 256, 1, 1><<<dim3(320, 4), 256, 0, stream>>>(
            c3wb, nullptr, c2b, nullptr, c3b, conv3_b, nullptr,
            512, 40960, 2304, 2304, 0.0625f);
        gemm_k<64, B_T, EP_ATOMIC, 0, 0, 0, 0, 0, 0, 1><<<dim3(4, 32, 4), 256, 0, stream>>>(
            c3b, embT8, nullptr, xn + (size_t)b0 * 1024 * 512, nullptr, embed_b, nullptr,
            2048, 512, 10240, 2560, 0.015625f);
    }
    ln_k<<<2048, 256, 0, stream>>>(xn, h, embed_ln_g, embed_ln_b, 8192);

    // ---- 4 RWKV blocks (fp8 GEMMs, x16 weights -> wsc=1/16)
    for (int i = 0; i < 4; i++) {
        lnmix_k<3><<<2048, 256, 0, stream>>>(h, ln_att_g + i * 512, ln_att_b + i * 512,
                                             att_mix_k + i * 512, att_mix_v + i * 512,
                                             att_mix_r + i * 512,
                                             xkvr8, xkvr8 + MD8, xkvr8 + 2 * MD8);
        gemm_k<64, B_T, EP_KVR, 9, 0, 0, 0, 0, 0, 1><<<dim3(12, 128), 256, 0, stream>>>(
            xkvr8, attT8 + (size_t)i * 786432, nullptr, kvrb, nullptr, nullptr, nullptr,
            8192, 1536, 512, 512, 0.0625f);
        wkv_loc_k<<<1024, 256, 0, stream>>>(kvrb, kvrb + MD, sloc, att_decay + i * 512);
        wkv_comb_k<<<16, 256, 0, stream>>>(sloc, sinc, att_decay + i * 512);
        wkv_out_k<<<1024, 256, 0, stream>>>(kvrb, kvrb + MD, kvrb + 2 * MD, rwkv8,
                                            sinc, att_decay + i * 512, att_first + i * 512);
        gemm_k<64, B_T, EP_ADD, 0, 0, 0, 0, 0, 0, 1><<<dim3(4, 128), 256, 0, stream>>>(
            rwkv8, attTo8 + (size_t)i * 262144, nullptr, h, nullptr, nullptr, nullptr,
            8192, 512, 512, 512, 0.0625f);
        lnmix_k<2><<<2048, 256, 0, stream>>>(h, ln_ffn_g + i * 512, ln_ffn_b + i * 512,
                                             ffn_mix_k + i * 512, nullptr,
                                             ffn_mix_r + i * 512,
                                             xf8, nullptr, xf8 + MD8);
        gemm_k<64, B_T, EP_FFN, 11, 0, 0, 0, 0, 0, 1><<<dim3(20, 128), 256, 0, stream>>>(
            xf8, ffnT8 + (size_t)i * 1310720, nullptr, kvrb + 2 * MD, kkb8, nullptr, nullptr,
            8192, 2560, 512, 512, 0.0625f);
        gemm_k<64, B_T, EP_ADDMUL, 0, 0, 0, 0, 0, 0, 1><<<dim3(4, 128), 256, 0, stream>>>(
            kkb8, ffnTv8 + (size_t)i * 1048576, nullptr, h, nullptr, nullptr, kvrb + 2 * MD,
            8192, 512, 2048, 2048, 0.0625f);
    }

    // ---- final LN straight into d_out, then olens
    ln_k<<<2048, 256, 0, stream>>>(h, (float*)d_out, final_ln_g, final_ln_b, 8192);
    olens_k<<<1, 64, 0, stream>>>(x_len, (float*)d_out + 4194304);
}

// Round 11
// 1456.243 us; speedup vs baseline: 1.9098x; 1.0429x over previous
//
#include <hip/hip_runtime.h>
#include <hip/hip_bf16.h>
#include <hip/hip_fp8.h>

typedef __hip_bfloat16 bf16;
typedef __bf16 v8bf __attribute__((ext_vector_type(8)));
typedef float v4f __attribute__((ext_vector_type(4)));
typedef unsigned short u16x8 __attribute__((ext_vector_type(8)));
typedef long v2l __attribute__((ext_vector_type(2)));

// ---------------------------------------------------------------------------
//   x: (8,4096,80) -> conv1(1->128,s2) -> (8,2048,40,128)   [channel-last fp8]
//   -> conv2(128->256,s2) -> halo (8,1026,22,256) fp8
//   -> conv3(256->512,s1) -> tokens (8,1024,10240) fp8
//   -> embed GEMM fp8 (split-K, atomic) -> 4 RWKV blocks (fp8 GEMMs) -> LN
// GEMM core: TM x 128 tile, 64 BYTES of K per phase (bf16 BK=32, fp8 BK=64),
// 3-buffer counted-vmcnt pipeline (T3+T4). Staging IDENTICAL both dtypes:
// 4 thr/row, 16B chunks, source-chunk XOR fT=(tid>>3)&3 (T2 both-sides).
// Fragment reads are ds_read_b128 at slot (lq ^ ((lr>>1)&3)) for BOTH dtypes
// (r7-verified 0-conflict). r11: fp8 b64 reads were a STRUCTURAL 4-way
// conflict (64 lanes x 8B = 128 bank-slots / 32 banks; no XOR can fix) ->
// read 16B instead and split: MFMA#0 gets the low 8B (k in {16g..16g+8}),
// MFMA#1 the high 8B. A and B use the same lane->k map, every k covered
// once -> exact (k-accumulation order differs only).
// Weights pre-scaled x16 (x64 embed); epilogue multiplies 1/scale.
// WKV: 3-pass chunked associative scan (C=64 chunks of T=16), f32.
// ---------------------------------------------------------------------------

constexpr int B_T = 0, B_CONV = 1;
constexpr int EP_CONV_CL = 0, EP_CONV_T = 1, EP_ATOMIC = 2, EP_KVR = 3,
              EP_ADD = 4, EP_FFN = 5, EP_ADDMUL = 6;

constexpr int WC = 64;          // wkv chunks per sequence
constexpr int WT = 1024 / WC;   // 16 steps per chunk
constexpr int WPLANE = WC * 4096;  // 262144 states per plane

static __device__ __forceinline__ unsigned short f2b(float f) {
    return __builtin_bit_cast(unsigned short, __float2bfloat16(f));
}
static __device__ __forceinline__ unsigned char f2e4(float f) {
    __hip_fp8_e4m3 q(f);
    return (unsigned char)q.__x;
}

// global -> LDS async copy, 16B per lane. LDS dest must be the wave-uniform
// base; HW writes lane i at base + i*16.
static __device__ __forceinline__ void gld16(const unsigned char* g,
                                             unsigned char* l) {
    __builtin_amdgcn_global_load_lds(
        (__attribute__((address_space(1))) void*)g,
        (__attribute__((address_space(3))) void*)l, 16, 0, 0);
}

// ---------------------------------------------------------------------------
// MFMA GEMM: C[M,N] = A[M,K] * B[K,N]. A [M][K]; B [N][K] (B_T) or
// channel-last im2col gather (B_CONV; HALO=1 -> zero-padded halo buffer;
// HALO=0 -> OOB lanes read zero page Bw). ASH>0: A += (n0>>ASH)*M*K.
// K-phase = 64 bytes/row both dtypes. Loads/wave/stage L = TM/64 + 2.
// Steady wait vmcnt(2L); tail peels vmcnt(L), vmcnt(0).
// ---------------------------------------------------------------------------
template <int TM, int BL, int EPM, int ASH, int TIN, int FIN, int STRIDE,
          int ICN, int HALO, int F8>
__global__ __launch_bounds__(256) void gemm_k(
    const void* __restrict__ Av, const void* __restrict__ Bwv,
    const void* __restrict__ Bactv,
    float* __restrict__ C, void* __restrict__ Cbv,
    const float* __restrict__ bias, const float* __restrict__ mul,
    int M, int N, int K, int KLEN, float wsc)
{
    constexpr int MI = TM / 32;
    constexpr int ESZ = F8 ? 1 : 2;
    constexpr int BKe = 64 / ESZ;          // K-elements per phase (64B/row)
    __shared__ __align__(16) unsigned char As[3][TM * 64];
    __shared__ __align__(16) unsigned char Bs[3][128 * 64];
    const unsigned char* A    = (const unsigned char*)Av;
    const unsigned char* Bw   = (const unsigned char*)Bwv;
    const unsigned char* Bact = (const unsigned char*)Bactv;
    const int tid = threadIdx.x;
    const int n0 = blockIdx.x * 128;
    const int m0 = blockIdx.y * TM;
    const int kbase = blockIdx.z * KLEN;
    const int wave = tid >> 6, lane = tid & 63;
    const int wr = wave >> 1, wc = wave & 1;
    const int lq = lane >> 4, lr = lane & 15;

    if constexpr (ASH > 0) A += (size_t)(n0 >> ASH) * M * K * ESZ;

    v4f acc[MI][4];
#pragma unroll
    for (int i = 0; i < MI; i++)
#pragma unroll
        for (int j = 0; j < 4; j++) acc[i][j] = v4f{0.f, 0.f, 0.f, 0.f};

    // staging geometry (both dtypes): 4 threads/row, row = c*64 + (tid>>2);
    // lane fetches global 16B-chunk (tid&3)^((tid>>3)&3) of its 64B row slice.
    const int sr = tid >> 2;
    const int swzB = ((tid & 3) ^ ((tid >> 3) & 3)) * 16;  // byte off in row

    const unsigned char* aP[TM / 64];
#pragma unroll
    for (int c = 0; c < TM / 64; c++)
        aP[c] = A + (size_t)(m0 + c * 64 + sr) * K * ESZ + swzB;

    const unsigned char* bP[2];
    int cb0 = 0, cb1 = 0, cto0 = 0, cto1 = 0, cfo0 = 0, cfo1 = 0;
    if constexpr (BL == B_T) {
#pragma unroll
        for (int c = 0; c < 2; c++)
            bP[c] = Bw + (size_t)(n0 + c * 64 + sr) * K * ESZ + swzB;
    } else {
        {
            int n = n0 + sr;
            cb0 = n / 20480;
            int s = n - cb0 * 20480;
            cto0 = s / 20;
            cfo0 = s - cto0 * 20;
        }
        {
            int n = n0 + 64 + sr;
            cb1 = n / 20480;
            int s = n - cb1 * 20480;
            cto1 = s / 20;
            cfo1 = s - cto1 * 20;
        }
        if constexpr (HALO) {
            bP[0] = Bact + ((((size_t)cb0 * 1026 + cto0) * 22 + cfo0) * 256) * ESZ + swzB;
            bP[1] = Bact + ((((size_t)cb1 * 1026 + cto1) * 22 + cfo1) * 256) * ESZ + swzB;
        }
    }

    auto stageA = [&](int k0, int sel) {
#pragma unroll
        for (int c = 0; c < TM / 64; c++)
            gld16(aP[c] + (size_t)k0 * ESZ, &As[sel][c * 4096 + wave * 1024]);
    };
    auto stageB = [&](int k0, int sel) {
        if constexpr (BL == B_T) {
#pragma unroll
            for (int c = 0; c < 2; c++)
                gld16(bP[c] + (size_t)k0 * ESZ, &Bs[sel][c * 4096 + wave * 1024]);
        } else {
            int kg = k0 / ICN;             // kt*3+kf (BKe never crosses a tap)
            int ic0 = k0 - kg * ICN;       // channel base of this K-slice
            int kt = kg / 3, kf = kg - kt * 3;
            if constexpr (HALO) {          // conv3: bP already carries swzB
                gld16(bP[0] + ((size_t)(kt * 22 + kf) * 256 + ic0) * ESZ,
                      &Bs[sel][wave * 1024]);
                gld16(bP[1] + ((size_t)(kt * 22 + kf) * 256 + ic0) * ESZ,
                      &Bs[sel][4096 + wave * 1024]);
            } else {                       // conv2: OOB -> zero page (Bw)
                int ti0 = cto0 * STRIDE - 1 + kt, fi0 = cfo0 * STRIDE - 1 + kf;
                const unsigned char* s0 =
                    ((unsigned)ti0 < (unsigned)TIN && (unsigned)fi0 < (unsigned)FIN)
                    ? Bact + ((((size_t)cb0 * TIN + ti0) * FIN + fi0) * ICN + ic0) * ESZ + swzB
                    : Bw;
                gld16(s0, &Bs[sel][wave * 1024]);
                int ti1 = cto1 * STRIDE - 1 + kt, fi1 = cfo1 * STRIDE - 1 + kf;
                const unsigned char* s1 =
                    ((unsigned)ti1 < (unsigned)TIN && (unsigned)fi1 < (unsigned)FIN)
                    ? Bact + ((((size_t)cb1 * TIN + ti1) * FIN + fi1) * ICN + ic0) * ESZ + swzB
                    : Bw;
                gld16(s1, &Bs[sel][4096 + wave * 1024]);
            }
        }
    };
    auto compute = [&](int sel) {
        const int lsw = (lr >> 1) & 3;
        if constexpr (F8) {
            // b128 read: 16B = global k[16*lq .. 16*lq+16). Low 8B -> MFMA#0,
            // high 8B -> MFMA#1 (same lane->k map on A and B -> exact).
            v2l fa16[MI], fb16[4];
#pragma unroll
            for (int mi = 0; mi < MI; mi++)
                fa16[mi] = *(const v2l*)&As[sel][(wr * (TM / 2) + mi * 16 + lr) * 64 +
                                                (lq ^ lsw) * 16];
#pragma unroll
            for (int ni = 0; ni < 4; ni++)
                fb16[ni] = *(const v2l*)&Bs[sel][(wc * 64 + ni * 16 + lr) * 64 +
                                                (lq ^ lsw) * 16];
#pragma unroll
            for (int mi = 0; mi < MI; mi++)
#pragma unroll
                for (int ni = 0; ni < 4; ni++) {
                    acc[mi][ni] = __builtin_amdgcn_mfma_f32_16x16x32_fp8_fp8(
                        fa16[mi][0], fb16[ni][0], acc[mi][ni], 0, 0, 0);
                    acc[mi][ni] = __builtin_amdgcn_mfma_f32_16x16x32_fp8_fp8(
                        fa16[mi][1], fb16[ni][1], acc[mi][ni], 0, 0, 0);
                }
        } else {
            v8bf fa[MI], fb[4];
#pragma unroll
            for (int mi = 0; mi < MI; mi++)
                fa[mi] = *(const v8bf*)&As[sel][(wr * (TM / 2) + mi * 16 + lr) * 64 +
                                               (lq ^ lsw) * 16];
#pragma unroll
            for (int ni = 0; ni < 4; ni++)
                fb[ni] = *(const v8bf*)&Bs[sel][(wc * 64 + ni * 16 + lr) * 64 +
                                               (lq ^ lsw) * 16];
#pragma unroll
            for (int mi = 0; mi < MI; mi++)
#pragma unroll
                for (int ni = 0; ni < 4; ni++)
                    acc[mi][ni] = __builtin_amdgcn_mfma_f32_16x16x32_bf16(
                        fa[mi], fb[ni], acc[mi][ni], 0, 0, 0);
        }
    };

    // ---- 3-buffer counted-vmcnt pipeline. NT >= 3 for all instances.
    const int NT = KLEN / BKe;
    stageA(kbase, 0);            stageB(kbase, 0);
    stageA(kbase + BKe, 1);      stageB(kbase + BKe, 1);
    stageA(kbase + 2 * BKe, 2);  stageB(kbase + 2 * BKe, 2);
    int sel = 0;
    for (int t = 0; t < NT - 2; ++t) {
        if constexpr (TM == 128)
            asm volatile("s_waitcnt vmcnt(8)" ::: "memory");
        else
            asm volatile("s_waitcnt vmcnt(6)" ::: "memory");
        __builtin_amdgcn_sched_barrier(0);
        __builtin_amdgcn_s_barrier();     // all waves' stage(t) landed
        compute(sel);
        __builtin_amdgcn_s_barrier();     // all reads of buf[sel] done
        if (t + 3 < NT) {
            int k0 = kbase + (t + 3) * BKe;
            stageA(k0, sel);
            stageB(k0, sel);
        }
        sel = sel == 2 ? 0 : sel + 1;
    }
    // t = NT-2: two stages outstanding -> wait for the older one
    if constexpr (TM == 128)
        asm volatile("s_waitcnt vmcnt(4)" ::: "memory");
    else
        asm volatile("s_waitcnt vmcnt(3)" ::: "memory");
    __builtin_amdgcn_sched_barrier(0);
    __builtin_amdgcn_s_barrier();
    compute(sel);
    sel = sel == 2 ? 0 : sel + 1;
    // t = NT-1: last stage
    asm volatile("s_waitcnt vmcnt(0)" ::: "memory");
    __builtin_amdgcn_sched_barrier(0);
    __builtin_amdgcn_s_barrier();
    compute(sel);

    // ---- epilogue
#pragma unroll
    for (int mi = 0; mi < MI; mi++) {
#pragma unroll
        for (int ni = 0; ni < 4; ni++) {
#pragma unroll
            for (int reg = 0; reg < 4; reg++) {
                int row = m0 + wr * (TM / 2) + mi * 16 + lq * 4 + reg;
                int col = n0 + wc * 64 + ni * 16 + lr;
                float v = acc[mi][ni][reg] * wsc;
                if constexpr (EPM == EP_CONV_CL) {
                    v += bias[row];
                    v = v > 0.f ? v : 0.f;
                    int b = col / 20480;
                    int s = col - b * 20480;
                    int t = s / 20, fo = s - t * 20;
                    ((unsigned char*)Cbv)[(((size_t)b * 1026 + t + 1) * 22 + fo + 1) * 256 + row] =
                        f2e4(v);
                } else if constexpr (EPM == EP_CONV_T) {
                    v += bias[row];
                    v = v > 0.f ? v : 0.f;
                    int b = col / 20480;
                    int s = col - b * 20480;
                    int t = s / 20, fo = s - t * 20;
                    ((unsigned char*)Cbv)[(size_t)(b * 1024 + t) * 10240 + row * 20 + fo] =
                        f2e4(v);
                } else if constexpr (EPM == EP_ATOMIC) {
                    float add = (blockIdx.z == 0) ? bias[col] : 0.f;
                    atomicAdd(&C[(size_t)row * N + col], v + add);
                } else if constexpr (EPM == EP_KVR) {
                    int seg = col >> 9;     // 0=k,1=v,2=r (uniform per block)
                    if (seg == 2) v = 1.f / (1.f + __expf(-v));
                    C[(size_t)seg * M * 512 + (size_t)row * 512 + (col & 511)] = v;
                } else if constexpr (EPM == EP_ADD) {
                    C[(size_t)row * N + col] += v;
                } else if constexpr (EPM == EP_FFN) {
                    if (col < 2048) {       // wk branch: sqrelu -> fp8 kkb
                        float t = v > 0.f ? v : 0.f;
                        ((unsigned char*)Cbv)[(size_t)row * 2048 + col] = f2e4(t * t);
                    } else {                // wr branch: sigmoid -> f32 rb
                        C[(size_t)row * 512 + (col - 2048)] = 1.f / (1.f + __expf(-v));
                    }
                } else if constexpr (EPM == EP_ADDMUL) {
                    size_t idx = (size_t)row * N + col;
                    C[idx] += mul[idx] * v;
                }
            }
        }
    }
}

// ---------------------------------------------------------------------------
// Prep: conv weight OIHW f32 -> fp8 e4m3 [oc][(kt*3+kf)*IC + ic], scaled x16
// ---------------------------------------------------------------------------
__global__ __launch_bounds__(256) void reorder_w8_k(const float* __restrict__ in,
                                                    unsigned char* __restrict__ out,
                                                    int OC, int IC)
{
    int idx = blockIdx.x * 256 + threadIdx.x;
    if (idx >= OC * IC * 9) return;
    int oc = idx / (IC * 9);
    int r = idx - oc * (IC * 9);
    int g = r / IC;
    int ic = r - g * IC;
    out[idx] = f2e4(in[((size_t)oc * IC + ic) * 9 + g] * 16.f);
}

// ---------------------------------------------------------------------------
// Prep: f32 [K][N] -> fp8 e4m3 [N][K] scaled; z: in stride izs, out stride ozs
// ---------------------------------------------------------------------------
__global__ __launch_bounds__(256) void transpose8_k(const float* __restrict__ in,
                                                    unsigned char* __restrict__ out,
                                                    int K, int N, size_t izs,
                                                    size_t ozs, float sc)
{
    __shared__ float t[32][33];
    const float* pin = in + (size_t)blockIdx.z * izs;
    unsigned char* pout = out + (size_t)blockIdx.z * ozs;
    int n0 = blockIdx.x * 32, k0 = blockIdx.y * 32;
    int tx = threadIdx.x & 31, ty = threadIdx.x >> 5;
#pragma unroll
    for (int i = 0; i < 32; i += 8)
        t[ty + i][tx] = pin[(size_t)(k0 + ty + i) * N + n0 + tx];
    __syncthreads();
#pragma unroll
    for (int i = 0; i < 32; i += 8)
        pout[(size_t)(n0 + ty + i) * K + k0 + tx] = f2e4(t[tx][ty + i] * sc);
}

// ---------------------------------------------------------------------------
// conv1 for a 2-batch chunk: 1 input channel, direct, channel-last fp8 out.
// ---------------------------------------------------------------------------
__global__ __launch_bounds__(256) void conv1_k(
    const float* __restrict__ x, const float* __restrict__ w,
    const float* __restrict__ bias, unsigned char* __restrict__ out)
{
    __shared__ float ws_[128 * 9];
    __shared__ float bs_[128];
    const int tid = threadIdx.x;
    for (int i = tid; i < 128 * 9; i += 256) ws_[i] = w[i];
    if (tid < 128) bs_[tid] = bias[tid];
    __syncthreads();

    int idx = blockIdx.x * 256 + tid;  // 2*2048*40
    int f = idx % 40;
    int t = (idx / 40) & 2047;
    int b = idx / 81920;

    float xin[9];
#pragma unroll
    for (int kt = 0; kt < 3; kt++)
#pragma unroll
        for (int kf = 0; kf < 3; kf++) {
            int ti = 2 * t - 1 + kt, fi = 2 * f - 1 + kf;
            float v = 0.f;
            if ((unsigned)ti < 4096u && (unsigned)fi < 80u)
                v = x[(size_t)b * 327680 + (size_t)ti * 80 + fi];
            xin[kt * 3 + kf] = v;
        }
    unsigned char* outu = out + (size_t)idx * 128;
#pragma unroll
    for (int oc8 = 0; oc8 < 16; oc8++) {
        unsigned char pk[8];
#pragma unroll
        for (int j = 0; j < 8; j++) {
            int oc = oc8 * 8 + j;
            float a = bs_[oc];
#pragma unroll
            for (int q = 0; q < 9; q++) a += ws_[oc * 9 + q] * xin[q];
            a = a > 0.f ? a : 0.f;
            pk[j] = f2e4(a);
        }
        *(unsigned long long*)&outu[oc8 * 8] = *(unsigned long long*)pk;
    }
}

// ---------------------------------------------------------------------------
// LayerNorm over D=512, one wave per row (4 rows / block)
// ---------------------------------------------------------------------------
__global__ __launch_bounds__(256) void ln_k(
    const float* __restrict__ in, float* __restrict__ out,
    const float* __restrict__ g, const float* __restrict__ b, int M)
{
    int wave = threadIdx.x >> 6;
    int lane = threadIdx.x & 63;
    int row = blockIdx.x * 4 + wave;
    if (row >= M) return;
    const float* p = in + (size_t)row * 512;
    float v[8], s = 0.f, sq = 0.f;
#pragma unroll
    for (int i = 0; i < 8; i++) {
        v[i] = p[lane + i * 64];
        s += v[i];
        sq += v[i] * v[i];
    }
#pragma unroll
    for (int o = 32; o > 0; o >>= 1) {
        s += __shfl_xor(s, o, 64);
        sq += __shfl_xor(sq, o, 64);
    }
    float mean = s * (1.f / 512.f);
    float var = sq * (1.f / 512.f) - mean * mean;
    float r = rsqrtf(var + 1e-5f);
    float* q = out + (size_t)row * 512;
#pragma unroll
    for (int i = 0; i < 8; i++) {
        int d = lane + i * 64;
        q[d] = (v[i] - mean) * r * g[d] + b[d];
    }
}

// ---------------------------------------------------------------------------
// Fused LN + token-shift mix -> fp8 operands. One wave per row; the wave
// also recomputes the predecessor row's LN (exact same f32 math). Lane owns
// 8 contiguous dims (8B fp8 stores). NOUT=3 (att) or 2 (ffn).
// ---------------------------------------------------------------------------
template <int NOUT>
__global__ __launch_bounds__(256) void lnmix_k(
    const float* __restrict__ hb, const float* __restrict__ g,
    const float* __restrict__ b, const float* __restrict__ mk,
    const float* __restrict__ mv, const float* __restrict__ mr,
    unsigned char* __restrict__ ok, unsigned char* __restrict__ ov,
    unsigned char* __restrict__ orr)
{
    int wave = threadIdx.x >> 6, lane = threadIdx.x & 63;
    int row = blockIdx.x * 4 + wave;     // 8192 rows
    int u = row & 1023;
    int d0 = lane * 8;
    const float* pc = hb + (size_t)row * 512 + d0;

    float vc[8], vp[8];
    *(float4*)&vc[0] = *(const float4*)pc;
    *(float4*)&vc[4] = *(const float4*)(pc + 4);
    float s = 0.f, sq = 0.f, sp = 0.f, sqp = 0.f;
#pragma unroll
    for (int i = 0; i < 8; i++) { s += vc[i]; sq += vc[i] * vc[i]; }
    if (u) {
        *(float4*)&vp[0] = *(const float4*)(pc - 512);
        *(float4*)&vp[4] = *(const float4*)(pc - 508);
#pragma unroll
        for (int i = 0; i < 8; i++) { sp += vp[i]; sqp += vp[i] * vp[i]; }
    } else {
#pragma unroll
        for (int i = 0; i < 8; i++) vp[i] = 0.f;
    }
#pragma unroll
    for (int o = 32; o > 0; o >>= 1) {
        s += __shfl_xor(s, o, 64);
        sq += __shfl_xor(sq, o, 64);
        sp += __shfl_xor(sp, o, 64);
        sqp += __shfl_xor(sqp, o, 64);
    }
    float mc = s * (1.f / 512.f);
    float rc = rsqrtf(sq * (1.f / 512.f) - mc * mc + 1e-5f);
    float mp = sp * (1.f / 512.f);
    float rp = rsqrtf(sqp * (1.f / 512.f) - mp * mp + 1e-5f);

    float gv[8], bv[8], xc[8], xp[8];
    *(float4*)&gv[0] = *(const float4*)(g + d0);
    *(float4*)&gv[4] = *(const float4*)(g + d0 + 4);
    *(float4*)&bv[0] = *(const float4*)(b + d0);
    *(float4*)&bv[4] = *(const float4*)(b + d0 + 4);
#pragma unroll
    for (int i = 0; i < 8; i++) {
        xc[i] = (vc[i] - mc) * rc * gv[i] + bv[i];
        xp[i] = u ? (vp[i] - mp) * rp * gv[i] + bv[i] : 0.f;
    }

    size_t ob = (size_t)row * 512 + d0;
    float a[8];
    unsigned char o8[8];
    *(float4*)&a[0] = *(const float4*)(mk + d0);
    *(float4*)&a[4] = *(const float4*)(mk + d0 + 4);
#pragma unroll
    for (int i = 0; i < 8; i++) o8[i] = f2e4(xc[i] * a[i] + xp[i] * (1.f - a[i]));
    *(unsigned long long*)(ok + ob) = *(unsigned long long*)o8;
    if constexpr (NOUT == 3) {
        *(float4*)&a[0] = *(const float4*)(mv + d0);
        *(float4*)&a[4] = *(const float4*)(mv + d0 + 4);
#pragma unroll
        for (int i = 0; i < 8; i++) o8[i] = f2e4(xc[i] * a[i] + xp[i] * (1.f - a[i]));
        *(unsigned long long*)(ov + ob) = *(unsigned long long*)o8;
    }
    *(float4*)&a[0] = *(const float4*)(mr + d0);
    *(float4*)&a[4] = *(const float4*)(mr + d0 + 4);
#pragma unroll
    for (int i = 0; i < 8; i++) o8[i] = f2e4(xc[i] * a[i] + xp[i] * (1.f - a[i]));
    *(unsigned long long*)(orr + ob) = *(unsigned long long*)o8;
}

// ---------------------------------------------------------------------------
// WKV chunked scan. State (aa,bb,pp): num = aa*e^pp, den = bb*e^pp.
// Chunk combine: S_out = e^{w*WT} * S_in + S_local (associative).
// ---------------------------------------------------------------------------
__global__ __launch_bounds__(256) void wkv_loc_k(
    const float* __restrict__ kbuf, const float* __restrict__ vbuf,
    float* __restrict__ st, const float* __restrict__ decay)
{
    int idx = blockIdx.x * 256 + threadIdx.x;   // [c][b][d]
    int bd = idx & 4095;
    int c = idx >> 12;
    int d = bd & 511;
    int b = bd >> 9;
    float w = -__expf(decay[d]);
    float aa = 0.f, bb = 0.f, pp = -1e38f;
    size_t base = ((size_t)b * 1024 + c * WT) * 512 + d;
#pragma unroll
    for (int s = 0; s < WT; s++) {
        float kt = kbuf[base + (size_t)s * 512];
        float vt = vbuf[base + (size_t)s * 512];
        float ww2 = pp + w;
        float p2 = ww2 > kt ? ww2 : kt;
        float e1 = __expf(ww2 - p2), e2 = __expf(kt - p2);
        aa = e1 * aa + e2 * vt;
        bb = e1 * bb + e2;
        pp = p2;
    }
    st[idx] = aa;
    st[WPLANE + idx] = bb;
    st[2 * WPLANE + idx] = pp;
}

__global__ __launch_bounds__(256) void wkv_comb_k(
    const float* __restrict__ loc, float* __restrict__ inc,
    const float* __restrict__ decay)
{
    int bd = blockIdx.x * 256 + threadIdx.x;  // 4096
    int d = bd & 511;
    float wT = -__expf(decay[d]) * (float)WT;
    float aa = 0.f, bb = 0.f, pp = -1e38f;
    for (int c = 0; c < WC; c++) {
        int i = c * 4096 + bd;
        inc[i] = aa;
        inc[WPLANE + i] = bb;
        inc[2 * WPLANE + i] = pp;
        float la = loc[i], lb = loc[WPLANE + i], lp = loc[2 * WPLANE + i];
        float pd = pp + wT;
        float p2 = pd > lp ? pd : lp;
        float e1 = __expf(pd - p2), e2 = __expf(lp - p2);
        aa = e1 * aa + e2 * la;
        bb = e1 * bb + e2 * lb;
        pp = p2;
    }
}

__global__ __launch_bounds__(256) void wkv_out_k(
    const float* __restrict__ kbuf, const float* __restrict__ vbuf,
    const float* __restrict__ rbuf, unsigned char* __restrict__ outbuf,
    const float* __restrict__ inc,
    const float* __restrict__ decay, const float* __restrict__ first)
{
    int idx = blockIdx.x * 256 + threadIdx.x;
    int bd = idx & 4095;
    int c = idx >> 12;
    int d = bd & 511;
    int b = bd >> 9;
    float w = -__expf(decay[d]);
    float u = first[d];
    float aa = inc[idx], bb = inc[WPLANE + idx], pp = inc[2 * WPLANE + idx];
    size_t base = ((size_t)b * 1024 + c * WT) * 512 + d;
#pragma unroll
    for (int s = 0; s < WT; s++) {
        float kt = kbuf[base + (size_t)s * 512];
        float vt = vbuf[base + (size_t)s * 512];
        float rt = rbuf[base + (size_t)s * 512];
        float ww = u + kt;
        float p = pp > ww ? pp : ww;
        float e1 = __expf(pp - p), e2 = __expf(ww - p);
        float out = (e1 * aa + e2 * vt) / (e1 * bb + e2);
        outbuf[base + (size_t)s * 512] = f2e4(rt * out);
        float ww2 = pp + w;
        float p2 = ww2 > kt ? ww2 : kt;
        e1 = __expf(ww2 - p2);
        e2 = __expf(kt - p2);
        aa = e1 * aa + e2 * vt;
        bb = e1 * bb + e2;
        pp = p2;
    }
}

__global__ void olens_k(const int* __restrict__ x_len, float* __restrict__ out)
{
    int i = threadIdx.x;
    if (i < 8) {
        int l1 = (x_len[i] - 1) / 2 + 1;
        int ol = (l1 - 1) / 2 + 1;
        out[i] = (float)ol;
    }
}

// ---------------------------------------------------------------------------
extern "C" void kernel_launch(void* const* d_in, const int* in_sizes, int n_in,
                              void* d_out, int out_size, void* d_ws, size_t ws_size,
                              hipStream_t stream)
{
    (void)in_sizes; (void)n_in; (void)out_size; (void)ws_size;
    const float* x         = (const float*)d_in[0];
    const int*   x_len     = (const int*)d_in[1];
    const float* conv1_w   = (const float*)d_in[2];
    const float* conv1_b   = (const float*)d_in[3];
    const float* conv2_w   = (const float*)d_in[4];
    const float* conv2_b   = (const float*)d_in[5];
    const float* conv3_w   = (const float*)d_in[6];
    const float* conv3_b   = (const float*)d_in[7];
    const float* embed_w   = (const float*)d_in[8];
    const float* embed_b   = (const float*)d_in[9];
    const float* embed_ln_g= (const float*)d_in[10];
    const float* embed_ln_b= (const float*)d_in[11];
    const float* ln_att_g  = (const float*)d_in[12];
    const float* ln_att_b  = (const float*)d_in[13];
    const float* att_decay = (const float*)d_in[14];
    const float* att_first = (const float*)d_in[15];
    const float* att_mix_k = (const float*)d_in[16];
    const float* att_mix_v = (const float*)d_in[17];
    const float* att_mix_r = (const float*)d_in[18];
    const float* att_wk    = (const float*)d_in[19];
    const float* att_wv    = (const float*)d_in[20];
    const float* att_wr    = (const float*)d_in[21];
    const float* att_wo    = (const float*)d_in[22];
    const float* ln_ffn_g  = (const float*)d_in[23];
    const float* ln_ffn_b  = (const float*)d_in[24];
    const float* ffn_mix_k = (const float*)d_in[25];
    const float* ffn_mix_r = (const float*)d_in[26];
    const float* ffn_wk    = (const float*)d_in[27];
    const float* ffn_wv    = (const float*)d_in[28];
    const float* ffn_wr    = (const float*)d_in[29];
    const float* final_ln_g= (const float*)d_in[30];
    const float* final_ln_b= (const float*)d_in[31];

    // ---- workspace layout (MiB offsets) ----
    // 0..16 h | 16..32 xn / wkv states | 32..36 rwkv8 | 40..52 xkvr8 (xf8
    // aliases 40..48) | 64..112 kvrb f32 | 112..128 kkb8
    // conv overlay (fp8): c1b 40..60 | c2b(halo) 80..91.1 | zpg 103 | c3b 104..124
    // fp8 weights: attT8 144..147 | attTo8 150..151 | ffnT8 152..157 |
    //              ffnTv8 162..166 | embT8 170..175 | c2wb/c3wb 180..
    char* wsb = (char*)d_ws;
    float* h     = (float*)(wsb);
    float* xn    = (float*)(wsb + (16LL << 20));
    float* sloc  = (float*)(wsb + (16LL << 20));   // [3][WC][4096] f32 (3MB)
    float* sinc  = (float*)(wsb + (20LL << 20));   // [3][WC][4096] f32 (3MB)
    unsigned char* rwkv8 = (unsigned char*)(wsb + (32LL << 20)); // [8192][512] fp8
    unsigned char* xkvr8 = (unsigned char*)(wsb + (40LL << 20)); // [3][8192][512] fp8
    unsigned char* xf8   = xkvr8;                                // [2][8192][512] fp8
    float* kvrb  = (float*)(wsb + (64LL << 20));   // [3][8192][512] f32
    unsigned char* kkb8  = (unsigned char*)(wsb + (112LL << 20)); // [8192][2048] fp8
    unsigned char* c1b  = (unsigned char*)(wsb + (40LL << 20));  // (2,2048,40,128) fp8
    unsigned char* c2b  = (unsigned char*)(wsb + (80LL << 20));  // (2,1026,22,256) fp8
    unsigned char* zpg  = (unsigned char*)(wsb + (103LL << 20)); // 4KB zero page
    unsigned char* c3b  = (unsigned char*)(wsb + (104LL << 20)); // (2048,10240) fp8
    unsigned char* attT8  = (unsigned char*)(wsb + (144LL << 20)); // 4x[1536][512]
    unsigned char* attTo8 = (unsigned char*)(wsb + (150LL << 20)); // 4x[512][512]
    unsigned char* ffnT8  = (unsigned char*)(wsb + (152LL << 20)); // 4x[2560][512]
    unsigned char* ffnTv8 = (unsigned char*)(wsb + (162LL << 20)); // 4x[512][2048]
    unsigned char* embT8  = (unsigned char*)(wsb + (170LL << 20)); // [512][10240]
    unsigned char* c2wb = (unsigned char*)(wsb + (180LL << 20));   // 256 x 1152
    unsigned char* c3wb = (unsigned char*)(wsb + (180LL << 20) + 294912); // 512x2304

    const size_t MD  = 8192LL * 512;   // f32 plane stride (elements)
    const size_t MD8 = 8192LL * 512;   // fp8 plane stride (bytes)

    // ---- weight prep (all fp8, x16 scale; embed x64)
    transpose8_k<<<dim3(16, 16, 4), 256, 0, stream>>>(att_wk, attT8, 512, 512,
                                                      262144, 786432, 16.f);
    transpose8_k<<<dim3(16, 16, 4), 256, 0, stream>>>(att_wv, attT8 + 262144, 512, 512,
                                                      262144, 786432, 16.f);
    transpose8_k<<<dim3(16, 16, 4), 256, 0, stream>>>(att_wr, attT8 + 524288, 512, 512,
                                                      262144, 786432, 16.f);
    transpose8_k<<<dim3(16, 16, 4), 256, 0, stream>>>(att_wo, attTo8, 512, 512,
                                                      262144, 262144, 16.f);
    transpose8_k<<<dim3(64, 16, 4), 256, 0, stream>>>(ffn_wk, ffnT8, 512, 2048,
                                                      1048576, 1310720, 16.f);
    transpose8_k<<<dim3(16, 16, 4), 256, 0, stream>>>(ffn_wr, ffnT8 + 1048576, 512, 512,
                                                      262144, 1310720, 16.f);
    transpose8_k<<<dim3(16, 64, 4), 256, 0, stream>>>(ffn_wv, ffnTv8, 2048, 512,
                                                      1048576, 1048576, 16.f);
    transpose8_k<<<dim3(16, 320, 1), 256, 0, stream>>>(embed_w, embT8, 10240, 512,
                                                       0, 0, 64.f);
    reorder_w8_k<<<1152, 256, 0, stream>>>(conv2_w, c2wb, 256, 128);
    reorder_w8_k<<<4608, 256, 0, stream>>>(conv3_w, c3wb, 512, 256);
    hipMemsetAsync(xn, 0, 16LL << 20, stream);
    hipMemsetAsync(c2b, 0, 2LL * 1026 * 22 * 256, stream);
    hipMemsetAsync(zpg, 0, 4096, stream);

    // ---- conv frontend + embed (fp8, BK=64), 2 batches per chunk
    for (int chunk = 0; chunk < 4; chunk++) {
        int b0 = chunk * 2;
        conv1_k<<<640, 256, 0, stream>>>(x + (size_t)b0 * 327680, conv1_w, conv1_b, c1b);
        gemm_k<128, B_CONV, EP_CONV_CL, 0, 2048, 40, 2, 128, 0, 1><<<dim3(320, 2), 256, 0, stream>>>(
            c2wb, zpg, c1b, nullptr, c2b, conv2_b, nullptr,
            256, 40960, 1152, 1152, 0.0625f);
        gemm_k<128, B_CONV, EP_CONV_T, 0, 1024, 20, 1, 256, 1, 1><<<dim3(320, 4), 256, 0, stream>>>(
            c3wb, nullptr, c2b, nullptr, c3b, conv3_b, nullptr,
            512, 40960, 2304, 2304, 0.0625f);
        gemm_k<64, B_T, EP_ATOMIC, 0, 0, 0, 0, 0, 0, 1><<<dim3(4, 32, 4), 256, 0, stream>>>(
            c3b, embT8, nullptr, xn + (size_t)b0 * 1024 * 512, nullptr, embed_b, nullptr,
            2048, 512, 10240, 2560, 0.015625f);
    }
    ln_k<<<2048, 256, 0, stream>>>(xn, h, embed_ln_g, embed_ln_b, 8192);

    // ---- 4 RWKV blocks (fp8 GEMMs, x16 weights -> wsc=1/16)
    for (int i = 0; i < 4; i++) {
        lnmix_k<3><<<2048, 256, 0, stream>>>(h, ln_att_g + i * 512, ln_att_b + i * 512,
                                             att_mix_k + i * 512, att_mix_v + i * 512,
                                             att_mix_r + i * 512,
                                             xkvr8, xkvr8 + MD8, xkvr8 + 2 * MD8);
        gemm_k<64, B_T, EP_KVR, 9, 0, 0, 0, 0, 0, 1><<<dim3(12, 128), 256, 0, stream>>>(
            xkvr8, attT8 + (size_t)i * 786432, nullptr, kvrb, nullptr, nullptr, nullptr,
            8192, 1536, 512, 512, 0.0625f);
        wkv_loc_k<<<1024, 256, 0, stream>>>(kvrb, kvrb + MD, sloc, att_decay + i * 512);
        wkv_comb_k<<<16, 256, 0, stream>>>(sloc, sinc, att_decay + i * 512);
        wkv_out_k<<<1024, 256, 0, stream>>>(kvrb, kvrb + MD, kvrb + 2 * MD, rwkv8,
                                            sinc, att_decay + i * 512, att_first + i * 512);
        gemm_k<64, B_T, EP_ADD, 0, 0, 0, 0, 0, 0, 1><<<dim3(4, 128), 256, 0, stream>>>(
            rwkv8, attTo8 + (size_t)i * 262144, nullptr, h, nullptr, nullptr, nullptr,
            8192, 512, 512, 512, 0.0625f);
        lnmix_k<2><<<2048, 256, 0, stream>>>(h, ln_ffn_g + i * 512, ln_ffn_b + i * 512,
                                             ffn_mix_k + i * 512, nullptr,
                                             ffn_mix_r + i * 512,
                                             xf8, nullptr, xf8 + MD8);
        gemm_k<64, B_T, EP_FFN, 11, 0, 0, 0, 0, 0, 1><<<dim3(20, 128), 256, 0, stream>>>(
            xf8, ffnT8 + (size_t)i * 1310720, nullptr, kvrb + 2 * MD, kkb8, nullptr, nullptr,
            8192, 2560, 512, 512, 0.0625f);
        gemm_k<64, B_T, EP_ADDMUL, 0, 0, 0, 0, 0, 0, 1><<<dim3(4, 128), 256, 0, stream>>>(
            kkb8, ffnTv8 + (size_t)i * 1048576, nullptr, h, nullptr, nullptr, kvrb + 2 * MD,
            8192, 512, 2048, 2048, 0.0625f);
    }

    // ---- final LN straight into d_out, then olens
    ln_k<<<2048, 256, 0, stream>>>(h, (float*)d_out, final_ln_g, final_ln_b, 8192);
    olens_k<<<1, 64, 0, stream>>>(x_len, (float*)d_out + 4194304);
}

// Round 12
// 1441.831 us; speedup vs baseline: 1.9289x; 1.0100x over previous
//
#include <hip/hip_runtime.h>
#include <hip/hip_bf16.h>
#include <hip/hip_fp8.h>

typedef __hip_bfloat16 bf16;
typedef __bf16 v8bf __attribute__((ext_vector_type(8)));
typedef float v4f __attribute__((ext_vector_type(4)));
typedef unsigned short u16x8 __attribute__((ext_vector_type(8)));
typedef long v2l __attribute__((ext_vector_type(2)));

// ---------------------------------------------------------------------------
//   x: (8,4096,80) -> conv1(1->128,s2) -> (8,2048,40,128)   [channel-last fp8]
//   -> conv2(128->256,s2) -> halo (8,1026,22,256) fp8
//   -> conv3(256->512,s1) -> tokens (8,1024,10240) fp8
//   -> embed GEMM fp8 (split-K, atomic) -> 4 RWKV blocks (fp8 GEMMs) -> LN
// GEMM core: TM x 128 tile, 64 BYTES of K per phase (bf16 BK=32, fp8 BK=64),
// DOUBLE-BUFFERED depth-2 counted-vmcnt pipeline (r12: was 3-buffer depth-3;
// occupancy was the limiter -- 48KB LDS capped 3 blocks/CU, measured ~2
// resident, MfmaUtil 50%. 32KB -> 5 blocks/CU (TM=128), 24KB -> 6 (TM=64);
// cross-block wave overlap (m114) fills the barrier stalls. Depth-2 steady
// wait vmcnt(L) never drains to 0; one compute phase covers L2-resident
// load latency).
// Staging IDENTICAL both dtypes: 4 thr/row, 16B chunks, source-chunk XOR
// fT=(tid>>3)&3 (T2 both-sides). Fragment reads are ds_read_b128 at slot
// (lq ^ ((lr>>1)&3)) for BOTH dtypes (r7/r11-verified 0-conflict). fp8:
// low 8B -> MFMA#0, high 8B -> MFMA#1 (same lane->k map on A and B -> exact).
// Weights pre-scaled x16 (x64 embed); epilogue multiplies 1/scale.
// WKV: 3-pass chunked associative scan (C=64 chunks of T=16), f32.
// ---------------------------------------------------------------------------

constexpr int B_T = 0, B_CONV = 1;
constexpr int EP_CONV_CL = 0, EP_CONV_T = 1, EP_ATOMIC = 2, EP_KVR = 3,
              EP_ADD = 4, EP_FFN = 5, EP_ADDMUL = 6;

constexpr int WC = 64;          // wkv chunks per sequence
constexpr int WT = 1024 / WC;   // 16 steps per chunk
constexpr int WPLANE = WC * 4096;  // 262144 states per plane

static __device__ __forceinline__ unsigned short f2b(float f) {
    return __builtin_bit_cast(unsigned short, __float2bfloat16(f));
}
static __device__ __forceinline__ unsigned char f2e4(float f) {
    __hip_fp8_e4m3 q(f);
    return (unsigned char)q.__x;
}

// global -> LDS async copy, 16B per lane. LDS dest must be the wave-uniform
// base; HW writes lane i at base + i*16.
static __device__ __forceinline__ void gld16(const unsigned char* g,
                                             unsigned char* l) {
    __builtin_amdgcn_global_load_lds(
        (__attribute__((address_space(1))) void*)g,
        (__attribute__((address_space(3))) void*)l, 16, 0, 0);
}

// ---------------------------------------------------------------------------
// MFMA GEMM: C[M,N] = A[M,K] * B[K,N]. A [M][K]; B [N][K] (B_T) or
// channel-last im2col gather (B_CONV; HALO=1 -> zero-padded halo buffer;
// HALO=0 -> OOB lanes read zero page Bw). ASH>0: A += (n0>>ASH)*M*K.
// K-phase = 64 bytes/row both dtypes. Loads/wave/stage L = TM/64 + 2.
// Depth-2: steady wait vmcnt(L) (stage t+1 in flight); tail vmcnt(0).
// ---------------------------------------------------------------------------
template <int TM, int BL, int EPM, int ASH, int TIN, int FIN, int STRIDE,
          int ICN, int HALO, int F8>
__global__ __launch_bounds__(256) void gemm_k(
    const void* __restrict__ Av, const void* __restrict__ Bwv,
    const void* __restrict__ Bactv,
    float* __restrict__ C, void* __restrict__ Cbv,
    const float* __restrict__ bias, const float* __restrict__ mul,
    int M, int N, int K, int KLEN, float wsc)
{
    constexpr int MI = TM / 32;
    constexpr int ESZ = F8 ? 1 : 2;
    constexpr int BKe = 64 / ESZ;          // K-elements per phase (64B/row)
    __shared__ __align__(16) unsigned char As[2][TM * 64];
    __shared__ __align__(16) unsigned char Bs[2][128 * 64];
    const unsigned char* A    = (const unsigned char*)Av;
    const unsigned char* Bw   = (const unsigned char*)Bwv;
    const unsigned char* Bact = (const unsigned char*)Bactv;
    const int tid = threadIdx.x;
    const int n0 = blockIdx.x * 128;
    const int m0 = blockIdx.y * TM;
    const int kbase = blockIdx.z * KLEN;
    const int wave = tid >> 6, lane = tid & 63;
    const int wr = wave >> 1, wc = wave & 1;
    const int lq = lane >> 4, lr = lane & 15;

    if constexpr (ASH > 0) A += (size_t)(n0 >> ASH) * M * K * ESZ;

    v4f acc[MI][4];
#pragma unroll
    for (int i = 0; i < MI; i++)
#pragma unroll
        for (int j = 0; j < 4; j++) acc[i][j] = v4f{0.f, 0.f, 0.f, 0.f};

    // staging geometry (both dtypes): 4 threads/row, row = c*64 + (tid>>2);
    // lane fetches global 16B-chunk (tid&3)^((tid>>3)&3) of its 64B row slice.
    const int sr = tid >> 2;
    const int swzB = ((tid & 3) ^ ((tid >> 3) & 3)) * 16;  // byte off in row

    const unsigned char* aP[TM / 64];
#pragma unroll
    for (int c = 0; c < TM / 64; c++)
        aP[c] = A + (size_t)(m0 + c * 64 + sr) * K * ESZ + swzB;

    const unsigned char* bP[2];
    int cb0 = 0, cb1 = 0, cto0 = 0, cto1 = 0, cfo0 = 0, cfo1 = 0;
    if constexpr (BL == B_T) {
#pragma unroll
        for (int c = 0; c < 2; c++)
            bP[c] = Bw + (size_t)(n0 + c * 64 + sr) * K * ESZ + swzB;
    } else {
        {
            int n = n0 + sr;
            cb0 = n / 20480;
            int s = n - cb0 * 20480;
            cto0 = s / 20;
            cfo0 = s - cto0 * 20;
        }
        {
            int n = n0 + 64 + sr;
            cb1 = n / 20480;
            int s = n - cb1 * 20480;
            cto1 = s / 20;
            cfo1 = s - cto1 * 20;
        }
        if constexpr (HALO) {
            bP[0] = Bact + ((((size_t)cb0 * 1026 + cto0) * 22 + cfo0) * 256) * ESZ + swzB;
            bP[1] = Bact + ((((size_t)cb1 * 1026 + cto1) * 22 + cfo1) * 256) * ESZ + swzB;
        }
    }

    auto stageA = [&](int k0, int sel) {
#pragma unroll
        for (int c = 0; c < TM / 64; c++)
            gld16(aP[c] + (size_t)k0 * ESZ, &As[sel][c * 4096 + wave * 1024]);
    };
    auto stageB = [&](int k0, int sel) {
        if constexpr (BL == B_T) {
#pragma unroll
            for (int c = 0; c < 2; c++)
                gld16(bP[c] + (size_t)k0 * ESZ, &Bs[sel][c * 4096 + wave * 1024]);
        } else {
            int kg = k0 / ICN;             // kt*3+kf (BKe never crosses a tap)
            int ic0 = k0 - kg * ICN;       // channel base of this K-slice
            int kt = kg / 3, kf = kg - kt * 3;
            if constexpr (HALO) {          // conv3: bP already carries swzB
                gld16(bP[0] + ((size_t)(kt * 22 + kf) * 256 + ic0) * ESZ,
                      &Bs[sel][wave * 1024]);
                gld16(bP[1] + ((size_t)(kt * 22 + kf) * 256 + ic0) * ESZ,
                      &Bs[sel][4096 + wave * 1024]);
            } else {                       // conv2: OOB -> zero page (Bw)
                int ti0 = cto0 * STRIDE - 1 + kt, fi0 = cfo0 * STRIDE - 1 + kf;
                const unsigned char* s0 =
                    ((unsigned)ti0 < (unsigned)TIN && (unsigned)fi0 < (unsigned)FIN)
                    ? Bact + ((((size_t)cb0 * TIN + ti0) * FIN + fi0) * ICN + ic0) * ESZ + swzB
                    : Bw;
                gld16(s0, &Bs[sel][wave * 1024]);
                int ti1 = cto1 * STRIDE - 1 + kt, fi1 = cfo1 * STRIDE - 1 + kf;
                const unsigned char* s1 =
                    ((unsigned)ti1 < (unsigned)TIN && (unsigned)fi1 < (unsigned)FIN)
                    ? Bact + ((((size_t)cb1 * TIN + ti1) * FIN + fi1) * ICN + ic0) * ESZ + swzB
                    : Bw;
                gld16(s1, &Bs[sel][4096 + wave * 1024]);
            }
        }
    };
    auto compute = [&](int sel) {
        const int lsw = (lr >> 1) & 3;
        if constexpr (F8) {
            // b128 read: 16B = global k[16*lq .. 16*lq+16). Low 8B -> MFMA#0,
            // high 8B -> MFMA#1 (same lane->k map on A and B -> exact).
            v2l fa16[MI], fb16[4];
#pragma unroll
            for (int mi = 0; mi < MI; mi++)
                fa16[mi] = *(const v2l*)&As[sel][(wr * (TM / 2) + mi * 16 + lr) * 64 +
                                                (lq ^ lsw) * 16];
#pragma unroll
            for (int ni = 0; ni < 4; ni++)
                fb16[ni] = *(const v2l*)&Bs[sel][(wc * 64 + ni * 16 + lr) * 64 +
                                                (lq ^ lsw) * 16];
#pragma unroll
            for (int mi = 0; mi < MI; mi++)
#pragma unroll
                for (int ni = 0; ni < 4; ni++) {
                    acc[mi][ni] = __builtin_amdgcn_mfma_f32_16x16x32_fp8_fp8(
                        fa16[mi][0], fb16[ni][0], acc[mi][ni], 0, 0, 0);
                    acc[mi][ni] = __builtin_amdgcn_mfma_f32_16x16x32_fp8_fp8(
                        fa16[mi][1], fb16[ni][1], acc[mi][ni], 0, 0, 0);
                }
        } else {
            v8bf fa[MI], fb[4];
#pragma unroll
            for (int mi = 0; mi < MI; mi++)
                fa[mi] = *(const v8bf*)&As[sel][(wr * (TM / 2) + mi * 16 + lr) * 64 +
                                               (lq ^ lsw) * 16];
#pragma unroll
            for (int ni = 0; ni < 4; ni++)
                fb[ni] = *(const v8bf*)&Bs[sel][(wc * 64 + ni * 16 + lr) * 64 +
                                               (lq ^ lsw) * 16];
#pragma unroll
            for (int mi = 0; mi < MI; mi++)
#pragma unroll
                for (int ni = 0; ni < 4; ni++)
                    acc[mi][ni] = __builtin_amdgcn_mfma_f32_16x16x32_bf16(
                        fa[mi], fb[ni], acc[mi][ni], 0, 0, 0);
        }
    };

    // ---- 2-buffer depth-2 counted-vmcnt pipeline. NT >= 2 all instances.
    const int NT = KLEN / BKe;
    stageA(kbase, 0);        stageB(kbase, 0);
    stageA(kbase + BKe, 1);  stageB(kbase + BKe, 1);
    for (int t = 0; t < NT; ++t) {
        const int cur = t & 1;
        if (t < NT - 1) {
            if constexpr (TM == 128)
                asm volatile("s_waitcnt vmcnt(4)" ::: "memory");
            else
                asm volatile("s_waitcnt vmcnt(3)" ::: "memory");
        } else {
            asm volatile("s_waitcnt vmcnt(0)" ::: "memory");
        }
        __builtin_amdgcn_sched_barrier(0);
        __builtin_amdgcn_s_barrier();     // all waves' stage(t) landed
        compute(cur);
        __builtin_amdgcn_s_barrier();     // all reads of buf[cur] done
        if (t + 2 < NT) {
            int k0 = kbase + (t + 2) * BKe;
            stageA(k0, cur);
            stageB(k0, cur);
        }
    }

    // ---- epilogue
#pragma unroll
    for (int mi = 0; mi < MI; mi++) {
#pragma unroll
        for (int ni = 0; ni < 4; ni++) {
#pragma unroll
            for (int reg = 0; reg < 4; reg++) {
                int row = m0 + wr * (TM / 2) + mi * 16 + lq * 4 + reg;
                int col = n0 + wc * 64 + ni * 16 + lr;
                float v = acc[mi][ni][reg] * wsc;
                if constexpr (EPM == EP_CONV_CL) {
                    v += bias[row];
                    v = v > 0.f ? v : 0.f;
                    int b = col / 20480;
                    int s = col - b * 20480;
                    int t = s / 20, fo = s - t * 20;
                    ((unsigned char*)Cbv)[(((size_t)b * 1026 + t + 1) * 22 + fo + 1) * 256 + row] =
                        f2e4(v);
                } else if constexpr (EPM == EP_CONV_T) {
                    v += bias[row];
                    v = v > 0.f ? v : 0.f;
                    int b = col / 20480;
                    int s = col - b * 20480;
                    int t = s / 20, fo = s - t * 20;
                    ((unsigned char*)Cbv)[(size_t)(b * 1024 + t) * 10240 + row * 20 + fo] =
                        f2e4(v);
                } else if constexpr (EPM == EP_ATOMIC) {
                    float add = (blockIdx.z == 0) ? bias[col] : 0.f;
                    atomicAdd(&C[(size_t)row * N + col], v + add);
                } else if constexpr (EPM == EP_KVR) {
                    int seg = col >> 9;     // 0=k,1=v,2=r (uniform per block)
                    if (seg == 2) v = 1.f / (1.f + __expf(-v));
                    C[(size_t)seg * M * 512 + (size_t)row * 512 + (col & 511)] = v;
                } else if constexpr (EPM == EP_ADD) {
                    C[(size_t)row * N + col] += v;
                } else if constexpr (EPM == EP_FFN) {
                    if (col < 2048) {       // wk branch: sqrelu -> fp8 kkb
                        float t = v > 0.f ? v : 0.f;
                        ((unsigned char*)Cbv)[(size_t)row * 2048 + col] = f2e4(t * t);
                    } else {                // wr branch: sigmoid -> f32 rb
                        C[(size_t)row * 512 + (col - 2048)] = 1.f / (1.f + __expf(-v));
                    }
                } else if constexpr (EPM == EP_ADDMUL) {
                    size_t idx = (size_t)row * N + col;
                    C[idx] += mul[idx] * v;
                }
            }
        }
    }
}

// ---------------------------------------------------------------------------
// Prep: conv weight OIHW f32 -> fp8 e4m3 [oc][(kt*3+kf)*IC + ic], scaled x16
// ---------------------------------------------------------------------------
__global__ __launch_bounds__(256) void reorder_w8_k(const float* __restrict__ in,
                                                    unsigned char* __restrict__ out,
                                                    int OC, int IC)
{
    int idx = blockIdx.x * 256 + threadIdx.x;
    if (idx >= OC * IC * 9) return;
    int oc = idx / (IC * 9);
    int r = idx - oc * (IC * 9);
    int g = r / IC;
    int ic = r - g * IC;
    out[idx] = f2e4(in[((size_t)oc * IC + ic) * 9 + g] * 16.f);
}

// ---------------------------------------------------------------------------
// Prep: f32 [K][N] -> fp8 e4m3 [N][K] scaled; z: in stride izs, out stride ozs
// ---------------------------------------------------------------------------
__global__ __launch_bounds__(256) void transpose8_k(const float* __restrict__ in,
                                                    unsigned char* __restrict__ out,
                                                    int K, int N, size_t izs,
                                                    size_t ozs, float sc)
{
    __shared__ float t[32][33];
    const float* pin = in + (size_t)blockIdx.z * izs;
    unsigned char* pout = out + (size_t)blockIdx.z * ozs;
    int n0 = blockIdx.x * 32, k0 = blockIdx.y * 32;
    int tx = threadIdx.x & 31, ty = threadIdx.x >> 5;
#pragma unroll
    for (int i = 0; i < 32; i += 8)
        t[ty + i][tx] = pin[(size_t)(k0 + ty + i) * N + n0 + tx];
    __syncthreads();
#pragma unroll
    for (int i = 0; i < 32; i += 8)
        pout[(size_t)(n0 + ty + i) * K + k0 + tx] = f2e4(t[tx][ty + i] * sc);
}

// ---------------------------------------------------------------------------
// conv1 for a 2-batch chunk: 1 input channel, direct, channel-last fp8 out.
// ---------------------------------------------------------------------------
__global__ __launch_bounds__(256) void conv1_k(
    const float* __restrict__ x, const float* __restrict__ w,
    const float* __restrict__ bias, unsigned char* __restrict__ out)
{
    __shared__ float ws_[128 * 9];
    __shared__ float bs_[128];
    const int tid = threadIdx.x;
    for (int i = tid; i < 128 * 9; i += 256) ws_[i] = w[i];
    if (tid < 128) bs_[tid] = bias[tid];
    __syncthreads();

    int idx = blockIdx.x * 256 + tid;  // 2*2048*40
    int f = idx % 40;
    int t = (idx / 40) & 2047;
    int b = idx / 81920;

    float xin[9];
#pragma unroll
    for (int kt = 0; kt < 3; kt++)
#pragma unroll
        for (int kf = 0; kf < 3; kf++) {
            int ti = 2 * t - 1 + kt, fi = 2 * f - 1 + kf;
            float v = 0.f;
            if ((unsigned)ti < 4096u && (unsigned)fi < 80u)
                v = x[(size_t)b * 327680 + (size_t)ti * 80 + fi];
            xin[kt * 3 + kf] = v;
        }
    unsigned char* outu = out + (size_t)idx * 128;
#pragma unroll
    for (int oc8 = 0; oc8 < 16; oc8++) {
        unsigned char pk[8];
#pragma unroll
        for (int j = 0; j < 8; j++) {
            int oc = oc8 * 8 + j;
            float a = bs_[oc];
#pragma unroll
            for (int q = 0; q < 9; q++) a += ws_[oc * 9 + q] * xin[q];
            a = a > 0.f ? a : 0.f;
            pk[j] = f2e4(a);
        }
        *(unsigned long long*)&outu[oc8 * 8] = *(unsigned long long*)pk;
    }
}

// ---------------------------------------------------------------------------
// LayerNorm over D=512, one wave per row (4 rows / block)
// ---------------------------------------------------------------------------
__global__ __launch_bounds__(256) void ln_k(
    const float* __restrict__ in, float* __restrict__ out,
    const float* __restrict__ g, const float* __restrict__ b, int M)
{
    int wave = threadIdx.x >> 6;
    int lane = threadIdx.x & 63;
    int row = blockIdx.x * 4 + wave;
    if (row >= M) return;
    const float* p = in + (size_t)row * 512;
    float v[8], s = 0.f, sq = 0.f;
#pragma unroll
    for (int i = 0; i < 8; i++) {
        v[i] = p[lane + i * 64];
        s += v[i];
        sq += v[i] * v[i];
    }
#pragma unroll
    for (int o = 32; o > 0; o >>= 1) {
        s += __shfl_xor(s, o, 64);
        sq += __shfl_xor(sq, o, 64);
    }
    float mean = s * (1.f / 512.f);
    float var = sq * (1.f / 512.f) - mean * mean;
    float r = rsqrtf(var + 1e-5f);
    float* q = out + (size_t)row * 512;
#pragma unroll
    for (int i = 0; i < 8; i++) {
        int d = lane + i * 64;
        q[d] = (v[i] - mean) * r * g[d] + b[d];
    }
}

// ---------------------------------------------------------------------------
// Fused LN + token-shift mix -> fp8 operands. One wave per row; the wave
// also recomputes the predecessor row's LN (exact same f32 math). Lane owns
// 8 contiguous dims (8B fp8 stores). NOUT=3 (att) or 2 (ffn).
// ---------------------------------------------------------------------------
template <int NOUT>
__global__ __launch_bounds__(256) void lnmix_k(
    const float* __restrict__ hb, const float* __restrict__ g,
    const float* __restrict__ b, const float* __restrict__ mk,
    const float* __restrict__ mv, const float* __restrict__ mr,
    unsigned char* __restrict__ ok, unsigned char* __restrict__ ov,
    unsigned char* __restrict__ orr)
{
    int wave = threadIdx.x >> 6, lane = threadIdx.x & 63;
    int row = blockIdx.x * 4 + wave;     // 8192 rows
    int u = row & 1023;
    int d0 = lane * 8;
    const float* pc = hb + (size_t)row * 512 + d0;

    float vc[8], vp[8];
    *(float4*)&vc[0] = *(const float4*)pc;
    *(float4*)&vc[4] = *(const float4*)(pc + 4);
    float s = 0.f, sq = 0.f, sp = 0.f, sqp = 0.f;
#pragma unroll
    for (int i = 0; i < 8; i++) { s += vc[i]; sq += vc[i] * vc[i]; }
    if (u) {
        *(float4*)&vp[0] = *(const float4*)(pc - 512);
        *(float4*)&vp[4] = *(const float4*)(pc - 508);
#pragma unroll
        for (int i = 0; i < 8; i++) { sp += vp[i]; sqp += vp[i] * vp[i]; }
    } else {
#pragma unroll
        for (int i = 0; i < 8; i++) vp[i] = 0.f;
    }
#pragma unroll
    for (int o = 32; o > 0; o >>= 1) {
        s += __shfl_xor(s, o, 64);
        sq += __shfl_xor(sq, o, 64);
        sp += __shfl_xor(sp, o, 64);
        sqp += __shfl_xor(sqp, o, 64);
    }
    float mc = s * (1.f / 512.f);
    float rc = rsqrtf(sq * (1.f / 512.f) - mc * mc + 1e-5f);
    float mp = sp * (1.f / 512.f);
    float rp = rsqrtf(sqp * (1.f / 512.f) - mp * mp + 1e-5f);

    float gv[8], bv[8], xc[8], xp[8];
    *(float4*)&gv[0] = *(const float4*)(g + d0);
    *(float4*)&gv[4] = *(const float4*)(g + d0 + 4);
    *(float4*)&bv[0] = *(const float4*)(b + d0);
    *(float4*)&bv[4] = *(const float4*)(b + d0 + 4);
#pragma unroll
    for (int i = 0; i < 8; i++) {
        xc[i] = (vc[i] - mc) * rc * gv[i] + bv[i];
        xp[i] = u ? (vp[i] - mp) * rp * gv[i] + bv[i] : 0.f;
    }

    size_t ob = (size_t)row * 512 + d0;
    float a[8];
    unsigned char o8[8];
    *(float4*)&a[0] = *(const float4*)(mk + d0);
    *(float4*)&a[4] = *(const float4*)(mk + d0 + 4);
#pragma unroll
    for (int i = 0; i < 8; i++) o8[i] = f2e4(xc[i] * a[i] + xp[i] * (1.f - a[i]));
    *(unsigned long long*)(ok + ob) = *(unsigned long long*)o8;
    if constexpr (NOUT == 3) {
        *(float4*)&a[0] = *(const float4*)(mv + d0);
        *(float4*)&a[4] = *(const float4*)(mv + d0 + 4);
#pragma unroll
        for (int i = 0; i < 8; i++) o8[i] = f2e4(xc[i] * a[i] + xp[i] * (1.f - a[i]));
        *(unsigned long long*)(ov + ob) = *(unsigned long long*)o8;
    }
    *(float4*)&a[0] = *(const float4*)(mr + d0);
    *(float4*)&a[4] = *(const float4*)(mr + d0 + 4);
#pragma unroll
    for (int i = 0; i < 8; i++) o8[i] = f2e4(xc[i] * a[i] + xp[i] * (1.f - a[i]));
    *(unsigned long long*)(orr + ob) = *(unsigned long long*)o8;
}

// ---------------------------------------------------------------------------
// WKV chunked scan. State (aa,bb,pp): num = aa*e^pp, den = bb*e^pp.
// Chunk combine: S_out = e^{w*WT} * S_in + S_local (associative).
// ---------------------------------------------------------------------------
__global__ __launch_bounds__(256) void wkv_loc_k(
    const float* __restrict__ kbuf, const float* __restrict__ vbuf,
    float* __restrict__ st, const float* __restrict__ decay)
{
    int idx = blockIdx.x * 256 + threadIdx.x;   // [c][b][d]
    int bd = idx & 4095;
    int c = idx >> 12;
    int d = bd & 511;
    int b = bd >> 9;
    float w = -__expf(decay[d]);
    float aa = 0.f, bb = 0.f, pp = -1e38f;
    size_t base = ((size_t)b * 1024 + c * WT) * 512 + d;
#pragma unroll
    for (int s = 0; s < WT; s++) {
        float kt = kbuf[base + (size_t)s * 512];
        float vt = vbuf[base + (size_t)s * 512];
        float ww2 = pp + w;
        float p2 = ww2 > kt ? ww2 : kt;
        float e1 = __expf(ww2 - p2), e2 = __expf(kt - p2);
        aa = e1 * aa + e2 * vt;
        bb = e1 * bb + e2;
        pp = p2;
    }
    st[idx] = aa;
    st[WPLANE + idx] = bb;
    st[2 * WPLANE + idx] = pp;
}

__global__ __launch_bounds__(256) void wkv_comb_k(
    const float* __restrict__ loc, float* __restrict__ inc,
    const float* __restrict__ decay)
{
    int bd = blockIdx.x * 256 + threadIdx.x;  // 4096
    int d = bd & 511;
    float wT = -__expf(decay[d]) * (float)WT;
    float aa = 0.f, bb = 0.f, pp = -1e38f;
    for (int c = 0; c < WC; c++) {
        int i = c * 4096 + bd;
        inc[i] = aa;
        inc[WPLANE + i] = bb;
        inc[2 * WPLANE + i] = pp;
        float la = loc[i], lb = loc[WPLANE + i], lp = loc[2 * WPLANE + i];
        float pd = pp + wT;
        float p2 = pd > lp ? pd : lp;
        float e1 = __expf(pd - p2), e2 = __expf(lp - p2);
        aa = e1 * aa + e2 * la;
        bb = e1 * bb + e2 * lb;
        pp = p2;
    }
}

__global__ __launch_bounds__(256) void wkv_out_k(
    const float* __restrict__ kbuf, const float* __restrict__ vbuf,
    const float* __restrict__ rbuf, unsigned char* __restrict__ outbuf,
    const float* __restrict__ inc,
    const float* __restrict__ decay, const float* __restrict__ first)
{
    int idx = blockIdx.x * 256 + threadIdx.x;
    int bd = idx & 4095;
    int c = idx >> 12;
    int d = bd & 511;
    int b = bd >> 9;
    float w = -__expf(decay[d]);
    float u = first[d];
    float aa = inc[idx], bb = inc[WPLANE + idx], pp = inc[2 * WPLANE + idx];
    size_t base = ((size_t)b * 1024 + c * WT) * 512 + d;
#pragma unroll
    for (int s = 0; s < WT; s++) {
        float kt = kbuf[base + (size_t)s * 512];
        float vt = vbuf[base + (size_t)s * 512];
        float rt = rbuf[base + (size_t)s * 512];
        float ww = u + kt;
        float p = pp > ww ? pp : ww;
        float e1 = __expf(pp - p), e2 = __expf(ww - p);
        float out = (e1 * aa + e2 * vt) / (e1 * bb + e2);
        outbuf[base + (size_t)s * 512] = f2e4(rt * out);
        float ww2 = pp + w;
        float p2 = ww2 > kt ? ww2 : kt;
        e1 = __expf(ww2 - p2);
        e2 = __expf(kt - p2);
        aa = e1 * aa + e2 * vt;
        bb = e1 * bb + e2;
        pp = p2;
    }
}

__global__ void olens_k(const int* __restrict__ x_len, float* __restrict__ out)
{
    int i = threadIdx.x;
    if (i < 8) {
        int l1 = (x_len[i] - 1) / 2 + 1;
        int ol = (l1 - 1) / 2 + 1;
        out[i] = (float)ol;
    }
}

// ---------------------------------------------------------------------------
extern "C" void kernel_launch(void* const* d_in, const int* in_sizes, int n_in,
                              void* d_out, int out_size, void* d_ws, size_t ws_size,
                              hipStream_t stream)
{
    (void)in_sizes; (void)n_in; (void)out_size; (void)ws_size;
    const float* x         = (const float*)d_in[0];
    const int*   x_len     = (const int*)d_in[1];
    const float* conv1_w   = (const float*)d_in[2];
    const float* conv1_b   = (const float*)d_in[3];
    const float* conv2_w   = (const float*)d_in[4];
    const float* conv2_b   = (const float*)d_in[5];
    const float* conv3_w   = (const float*)d_in[6];
    const float* conv3_b   = (const float*)d_in[7];
    const float* embed_w   = (const float*)d_in[8];
    const float* embed_b   = (const float*)d_in[9];
    const float* embed_ln_g= (const float*)d_in[10];
    const float* embed_ln_b= (const float*)d_in[11];
    const float* ln_att_g  = (const float*)d_in[12];
    const float* ln_att_b  = (const float*)d_in[13];
    const float* att_decay = (const float*)d_in[14];
    const float* att_first = (const float*)d_in[15];
    const float* att_mix_k = (const float*)d_in[16];
    const float* att_mix_v = (const float*)d_in[17];
    const float* att_mix_r = (const float*)d_in[18];
    const float* att_wk    = (const float*)d_in[19];
    const float* att_wv    = (const float*)d_in[20];
    const float* att_wr    = (const float*)d_in[21];
    const float* att_wo    = (const float*)d_in[22];
    const float* ln_ffn_g  = (const float*)d_in[23];
    const float* ln_ffn_b  = (const float*)d_in[24];
    const float* ffn_mix_k = (const float*)d_in[25];
    const float* ffn_mix_r = (const float*)d_in[26];
    const float* ffn_wk    = (const float*)d_in[27];
    const float* ffn_wv    = (const float*)d_in[28];
    const float* ffn_wr    = (const float*)d_in[29];
    const float* final_ln_g= (const float*)d_in[30];
    const float* final_ln_b= (const float*)d_in[31];

    // ---- workspace layout (MiB offsets) ----
    // 0..16 h | 16..32 xn / wkv states | 32..36 rwkv8 | 40..52 xkvr8 (xf8
    // aliases 40..48) | 64..112 kvrb f32 | 112..128 kkb8
    // conv overlay (fp8): c1b 40..60 | c2b(halo) 80..91.1 | zpg 103 | c3b 104..124
    // fp8 weights: attT8 144..147 | attTo8 150..151 | ffnT8 152..157 |
    //              ffnTv8 162..166 | embT8 170..175 | c2wb/c3wb 180..
    char* wsb = (char*)d_ws;
    float* h     = (float*)(wsb);
    float* xn    = (float*)(wsb + (16LL << 20));
    float* sloc  = (float*)(wsb + (16LL << 20));   // [3][WC][4096] f32 (3MB)
    float* sinc  = (float*)(wsb + (20LL << 20));   // [3][WC][4096] f32 (3MB)
    unsigned char* rwkv8 = (unsigned char*)(wsb + (32LL << 20)); // [8192][512] fp8
    unsigned char* xkvr8 = (unsigned char*)(wsb + (40LL << 20)); // [3][8192][512] fp8
    unsigned char* xf8   = xkvr8;                                // [2][8192][512] fp8
    float* kvrb  = (float*)(wsb + (64LL << 20));   // [3][8192][512] f32
    unsigned char* kkb8  = (unsigned char*)(wsb + (112LL << 20)); // [8192][2048] fp8
    unsigned char* c1b  = (unsigned char*)(wsb + (40LL << 20));  // (2,2048,40,128) fp8
    unsigned char* c2b  = (unsigned char*)(wsb + (80LL << 20));  // (2,1026,22,256) fp8
    unsigned char* zpg  = (unsigned char*)(wsb + (103LL << 20)); // 4KB zero page
    unsigned char* c3b  = (unsigned char*)(wsb + (104LL << 20)); // (2048,10240) fp8
    unsigned char* attT8  = (unsigned char*)(wsb + (144LL << 20)); // 4x[1536][512]
    unsigned char* attTo8 = (unsigned char*)(wsb + (150LL << 20)); // 4x[512][512]
    unsigned char* ffnT8  = (unsigned char*)(wsb + (152LL << 20)); // 4x[2560][512]
    unsigned char* ffnTv8 = (unsigned char*)(wsb + (162LL << 20)); // 4x[512][2048]
    unsigned char* embT8  = (unsigned char*)(wsb + (170LL << 20)); // [512][10240]
    unsigned char* c2wb = (unsigned char*)(wsb + (180LL << 20));   // 256 x 1152
    unsigned char* c3wb = (unsigned char*)(wsb + (180LL << 20) + 294912); // 512x2304

    const size_t MD  = 8192LL * 512;   // f32 plane stride (elements)
    const size_t MD8 = 8192LL * 512;   // fp8 plane stride (bytes)

    // ---- weight prep (all fp8, x16 scale; embed x64)
    transpose8_k<<<dim3(16, 16, 4), 256, 0, stream>>>(att_wk, attT8, 512, 512,
                                                      262144, 786432, 16.f);
    transpose8_k<<<dim3(16, 16, 4), 256, 0, stream>>>(att_wv, attT8 + 262144, 512, 512,
                                                      262144, 786432, 16.f);
    transpose8_k<<<dim3(16, 16, 4), 256, 0, stream>>>(att_wr, attT8 + 524288, 512, 512,
                                                      262144, 786432, 16.f);
    transpose8_k<<<dim3(16, 16, 4), 256, 0, stream>>>(att_wo, attTo8, 512, 512,
                                                      262144, 262144, 16.f);
    transpose8_k<<<dim3(64, 16, 4), 256, 0, stream>>>(ffn_wk, ffnT8, 512, 2048,
                                                      1048576, 1310720, 16.f);
    transpose8_k<<<dim3(16, 16, 4), 256, 0, stream>>>(ffn_wr, ffnT8 + 1048576, 512, 512,
                                                      262144, 1310720, 16.f);
    transpose8_k<<<dim3(16, 64, 4), 256, 0, stream>>>(ffn_wv, ffnTv8, 2048, 512,
                                                      1048576, 1048576, 16.f);
    transpose8_k<<<dim3(16, 320, 1), 256, 0, stream>>>(embed_w, embT8, 10240, 512,
                                                       0, 0, 64.f);
    reorder_w8_k<<<1152, 256, 0, stream>>>(conv2_w, c2wb, 256, 128);
    reorder_w8_k<<<4608, 256, 0, stream>>>(conv3_w, c3wb, 512, 256);
    hipMemsetAsync(xn, 0, 16LL << 20, stream);
    hipMemsetAsync(c2b, 0, 2LL * 1026 * 22 * 256, stream);
    hipMemsetAsync(zpg, 0, 4096, stream);

    // ---- conv frontend + embed (fp8, BK=64), 2 batches per chunk
    for (int chunk = 0; chunk < 4; chunk++) {
        int b0 = chunk * 2;
        conv1_k<<<640, 256, 0, stream>>>(x + (size_t)b0 * 327680, conv1_w, conv1_b, c1b);
        gemm_k<128, B_CONV, EP_CONV_CL, 0, 2048, 40, 2, 128, 0, 1><<<dim3(320, 2), 256, 0, stream>>>(
            c2wb, zpg, c1b, nullptr, c2b, conv2_b, nullptr,
            256, 40960, 1152, 1152, 0.0625f);
        gemm_k<128, B_CONV, EP_CONV_T, 0, 1024, 20, 1, 256, 1, 1><<<dim3(320, 4), 256, 0, stream>>>(
            c3wb, nullptr, c2b, nullptr, c3b, conv3_b, nullptr,
            512, 40960, 2304, 2304, 0.0625f);
        gemm_k<64, B_T, EP_ATOMIC, 0, 0, 0, 0, 0, 0, 1><<<dim3(4, 32, 4), 256, 0, stream>>>(
            c3b, embT8, nullptr, xn + (size_t)b0 * 1024 * 512, nullptr, embed_b, nullptr,
            2048, 512, 10240, 2560, 0.015625f);
    }
    ln_k<<<2048, 256, 0, stream>>>(xn, h, embed_ln_g, embed_ln_b, 8192);

    // ---- 4 RWKV blocks (fp8 GEMMs, x16 weights -> wsc=1/16)
    for (int i = 0; i < 4; i++) {
        lnmix_k<3><<<2048, 256, 0, stream>>>(h, ln_att_g + i * 512, ln_att_b + i * 512,
                                             att_mix_k + i * 512, att_mix_v + i * 512,
                                             att_mix_r + i * 512,
                                             xkvr8, xkvr8 + MD8, xkvr8 + 2 * MD8);
        gemm_k<64, B_T, EP_KVR, 9, 0, 0, 0, 0, 0, 1><<<dim3(12, 128), 256, 0, stream>>>(
            xkvr8, attT8 + (size_t)i * 786432, nullptr, kvrb, nullptr, nullptr, nullptr,
            8192, 1536, 512, 512, 0.0625f);
        wkv_loc_k<<<1024, 256, 0, stream>>>(kvrb, kvrb + MD, sloc, att_decay + i * 512);
        wkv_comb_k<<<16, 256, 0, stream>>>(sloc, sinc, att_decay + i * 512);
        wkv_out_k<<<1024, 256, 0, stream>>>(kvrb, kvrb + MD, kvrb + 2 * MD, rwkv8,
                                            sinc, att_decay + i * 512, att_first + i * 512);
        gemm_k<64, B_T, EP_ADD, 0, 0, 0, 0, 0, 0, 1><<<dim3(4, 128), 256, 0, stream>>>(
            rwkv8, attTo8 + (size_t)i * 262144, nullptr, h, nullptr, nullptr, nullptr,
            8192, 512, 512, 512, 0.0625f);
        lnmix_k<2><<<2048, 256, 0, stream>>>(h, ln_ffn_g + i * 512, ln_ffn_b + i * 512,
                                             ffn_mix_k + i * 512, nullptr,
                                             ffn_mix_r + i * 512,
                                             xf8, nullptr, xf8 + MD8);
        gemm_k<64, B_T, EP_FFN, 11, 0, 0, 0, 0, 0, 1><<<dim3(20, 128), 256, 0, stream>>>(
            xf8, ffnT8 + (size_t)i * 1310720, nullptr, kvrb + 2 * MD, kkb8, nullptr, nullptr,
            8192, 2560, 512, 512, 0.0625f);
        gemm_k<64, B_T, EP_ADDMUL, 0, 0, 0, 0, 0, 0, 1><<<dim3(4, 128), 256, 0, stream>>>(
            kkb8, ffnTv8 + (size_t)i * 1048576, nullptr, h, nullptr, nullptr, kvrb + 2 * MD,
            8192, 512, 2048, 2048, 0.0625f);
    }

    // ---- final LN straight into d_out, then olens
    ln_k<<<2048, 256, 0, stream>>>(h, (float*)d_out, final_ln_g, final_ln_b, 8192);
    olens_k<<<1, 64, 0, stream>>>(x_len, (float*)d_out + 4194304);
}